// Round 17
// baseline (366.486 us; speedup 1.0000x reference)
//
#include <hip/hip_runtime.h>
#include <hip/hip_bf16.h>
#include <cstddef>

#define BB 4
#define LL 2048
#define DM 256
#define DN 512
#define EE 1024
#define NS 16
#define RK 16
#define NC2 128         // scan chunks
#define CL2 (LL / NC2)  // chunk length = 16
#define NLT (LL / 16)   // l-tiles for xdbl/delta = 128

typedef __attribute__((ext_vector_type(8))) short bf16x8;
typedef __attribute__((ext_vector_type(8))) unsigned short ushort8;
typedef __attribute__((ext_vector_type(4))) unsigned short ushort4v;
typedef __attribute__((ext_vector_type(2))) unsigned short ushort2v;
typedef __attribute__((ext_vector_type(4))) float f32x4;

__device__ __forceinline__ float fsilu(float x) { return x / (1.0f + __expf(-x)); }
__device__ __forceinline__ float fsoftplus(float x) { return x > 20.0f ? x : log1pf(__expf(x)); }
__device__ __forceinline__ unsigned short f2bf(float x) {  // RNE float->bf16
  union { float f; unsigned int u; } v; v.f = x;
  unsigned int r = v.u + 0x7fffu + ((v.u >> 16) & 1u);
  return (unsigned short)(r >> 16);
}
__device__ __forceinline__ float bf2f(unsigned short x) {
  union { unsigned int u; float f; } v; v.u = ((unsigned int)x) << 16;
  return v.f;
}

// ---------------------------------------------------------------------------
// in_proj via bf16 MFMA. x-blocks (e<DN): C[e][l] -> xz[b][e][l] fp32.
// z-blocks: swap A/B so C[l][d] -> z_t[b][l][d] = silu, stored BF16.
// ---------------------------------------------------------------------------
__global__ __launch_bounds__(256) void in_proj_mfma(
    const float* __restrict__ h, const float* __restrict__ w,
    float* __restrict__ xz, unsigned short* __restrict__ z_t) {
  __shared__ unsigned short ht[128][40];  // [l][k] bf16
  __shared__ unsigned short wt[128][40];  // [e][k]
  const int b = blockIdx.z;
  const int e0 = blockIdx.y * 128;
  const int l0 = blockIdx.x * 128;
  const int tid = threadIdx.x;
  const int lane = tid & 63;
  const int wid = tid >> 6;
  const int wm = wid >> 1, wn = wid & 1;
  const bool zblk = (e0 >= DN);
  const int krow = (lane >> 4) * 8;
  const int rlo = lane & 15;

  f32x4 acc[4][4];
#pragma unroll
  for (int i = 0; i < 4; i++)
#pragma unroll
    for (int j = 0; j < 4; j++) acc[i][j] = (f32x4){0.f, 0.f, 0.f, 0.f};

  for (int dk = 0; dk < DM; dk += 32) {
#pragma unroll
    for (int it = 0; it < 2; it++) {
      int idx = it * 256 + tid;
      int row = idx >> 2;
      int seg = (idx & 3) * 8;
      const float* hp = h + ((size_t)b * LL + l0 + row) * DM + dk + seg;
      float4 ha = *(const float4*)hp, hb = *(const float4*)(hp + 4);
      ushort8 hv;
      hv[0] = f2bf(ha.x); hv[1] = f2bf(ha.y); hv[2] = f2bf(ha.z); hv[3] = f2bf(ha.w);
      hv[4] = f2bf(hb.x); hv[5] = f2bf(hb.y); hv[6] = f2bf(hb.z); hv[7] = f2bf(hb.w);
      *(ushort8*)&ht[row][seg] = hv;
      const float* wp = w + (size_t)(e0 + row) * DM + dk + seg;
      float4 wa = *(const float4*)wp, wb = *(const float4*)(wp + 4);
      ushort8 wv;
      wv[0] = f2bf(wa.x); wv[1] = f2bf(wa.y); wv[2] = f2bf(wa.z); wv[3] = f2bf(wa.w);
      wv[4] = f2bf(wb.x); wv[5] = f2bf(wb.y); wv[6] = f2bf(wb.z); wv[7] = f2bf(wb.w);
      *(ushort8*)&wt[row][seg] = wv;
    }
    __syncthreads();
    unsigned short (*Ab)[40] = zblk ? ht : wt;
    unsigned short (*Bb)[40] = zblk ? wt : ht;
    bf16x8 af[4], bfr[4];
#pragma unroll
    for (int mt = 0; mt < 4; mt++)
      af[mt] = *(bf16x8*)&Ab[wm * 64 + mt * 16 + rlo][krow];
#pragma unroll
    for (int nt = 0; nt < 4; nt++)
      bfr[nt] = *(bf16x8*)&Bb[wn * 64 + nt * 16 + rlo][krow];
#pragma unroll
    for (int mt = 0; mt < 4; mt++)
#pragma unroll
      for (int nt = 0; nt < 4; nt++)
        acc[mt][nt] = __builtin_amdgcn_mfma_f32_16x16x32_bf16(
            af[mt], bfr[nt], acc[mt][nt], 0, 0, 0);
    __syncthreads();
  }
  if (!zblk) {
#pragma unroll
    for (int mt = 0; mt < 4; mt++)
#pragma unroll
      for (int nt = 0; nt < 4; nt++)
#pragma unroll
        for (int r = 0; r < 4; r++) {
          int e = e0 + wm * 64 + mt * 16 + (lane >> 4) * 4 + r;
          int l = l0 + wn * 64 + nt * 16 + rlo;
          xz[((size_t)b * DN + e) * LL + l] = acc[mt][nt][r];
        }
  } else {
#pragma unroll
    for (int mt = 0; mt < 4; mt++)
#pragma unroll
      for (int nt = 0; nt < 4; nt++)
#pragma unroll
        for (int r = 0; r < 4; r++) {
          int l = l0 + wm * 64 + mt * 16 + (lane >> 4) * 4 + r;
          int d = (e0 - DN) + wn * 64 + nt * 16 + rlo;
          z_t[((size_t)b * LL + l) * DN + d] = f2bf(fsilu(acc[mt][nt][r]));
        }
  }
}

// ---------------------------------------------------------------------------
// conv_kernel: streaming conv+silu+transpose. Writes u[b][l][d] as BF16.
// ---------------------------------------------------------------------------
__global__ __launch_bounds__(256) void conv_kernel(
    const float* __restrict__ xz,
    const float* __restrict__ cw_f, const float* __restrict__ cb_f,
    const float* __restrict__ cw_r, const float* __restrict__ cb_r,
    unsigned short* __restrict__ u_f, unsigned short* __restrict__ u_r) {
  __shared__ float xt[128][33];
  const int rev = blockIdx.z;
  const int b = blockIdx.y;
  const int dc0 = (blockIdx.x & 3) * 128;
  const int l0 = (blockIdx.x >> 2) * 32;
  const int tid = threadIdx.x;
  const int lc = tid & 31;
  const int dg = tid >> 5;  // 0..7
  const int l = l0 + lc;
  const float* conv_w = rev ? cw_r : cw_f;
  const float* conv_b = rev ? cb_r : cb_f;
  unsigned short* u_out = rev ? u_r : u_f;

#pragma unroll
  for (int i = 0; i < 16; i++) {
    int dloc = dg * 16 + i;
    int dd = dc0 + dloc;
    const float* base = xz + ((size_t)b * DN + dd) * LL;
    float4 cw4 = *(const float4*)(conv_w + dd * 4);
    float a0 = conv_b[dd];
    if (rev) {
      a0 = fmaf(cw4.w, base[l], a0);
      if (l + 1 < LL) a0 = fmaf(cw4.z, base[l + 1], a0);
      if (l + 2 < LL) a0 = fmaf(cw4.y, base[l + 2], a0);
      if (l + 3 < LL) a0 = fmaf(cw4.x, base[l + 3], a0);
    } else {
      a0 = fmaf(cw4.w, base[l], a0);
      if (l - 1 >= 0) a0 = fmaf(cw4.z, base[l - 1], a0);
      if (l - 2 >= 0) a0 = fmaf(cw4.y, base[l - 2], a0);
      if (l - 3 >= 0) a0 = fmaf(cw4.x, base[l - 3], a0);
    }
    xt[dloc][lc] = fsilu(a0);
  }
  __syncthreads();
#pragma unroll
  for (int j = 0; j < 8; j++) {
    int idx = j * 256 + tid;  // 0..2047 ushort2 units
    int d2 = idx & 63;        // ushort2 column (d = 2*d2)
    int l2 = idx >> 6;        // 0..31
    ushort2v v;
    v[0] = f2bf(xt[2 * d2][l2]);
    v[1] = f2bf(xt[2 * d2 + 1][l2]);
    *(ushort2v*)&u_out[((size_t)b * LL + l0 + l2) * DN + dc0 + 2 * d2] = v;
  }
}

// ---------------------------------------------------------------------------
// prep: convert x_w (48x512 fp32) of both branches to bf16 global.
// ---------------------------------------------------------------------------
__global__ __launch_bounds__(256) void xw_prep_kernel(
    const float* __restrict__ xw_f, const float* __restrict__ xw_r,
    unsigned short* __restrict__ o_f, unsigned short* __restrict__ o_r) {
  int i = blockIdx.x * 256 + threadIdx.x;
  if (i < 48 * 512) {
    o_f[i] = f2bf(xw_f[i]);
    o_r[i] = f2bf(xw_r[i]);
  }
}

// ---------------------------------------------------------------------------
// xdbl_kernel: x_dbl GEMM (48 x 16l x 512). Stage u tile, 12 MFMA per wave,
// LDS reduce, scatter: dt rows -> dtv_g (global), B/C rows -> B/C buffers.
// Delta moved to its own kernel (was 2/3 of this kernel's VALU serialized
// behind barriers at 4 blocks/CU).
// ---------------------------------------------------------------------------
__global__ __launch_bounds__(256) void xdbl_kernel(
    const unsigned short* __restrict__ u_f, const unsigned short* __restrict__ u_r,
    const unsigned short* __restrict__ xwb_f,
    const unsigned short* __restrict__ xwb_r,
    float* __restrict__ dtv_g,
    float* __restrict__ B_f, float* __restrict__ C_f,
    float* __restrict__ B_r, float* __restrict__ C_r) {
  __shared__ __align__(16) unsigned short ub[4][16][136];  // u tile, per k-chunk
  __shared__ float red[4][48][17];                         // per-wave partials
  const int rev = blockIdx.z;
  const int b = blockIdx.y;
  const int lt = blockIdx.x;  // l-tile index
  const int l0 = lt * 16;
  const int tid = threadIdx.x;
  const int lane = tid & 63;
  const int w = tid >> 6;  // wave = k-chunk 0..3
  const int rlo = lane & 15;
  const int hi4 = lane >> 4;  // 0..3
  const int kseg = hi4 * 8;

  const unsigned short* up = (rev ? u_r : u_f) + ((size_t)b * LL + l0) * DN;
  const unsigned short* xwb = rev ? xwb_r : xwb_f;
  float* B_out = rev ? B_r : B_f;
  float* C_out = rev ? C_r : C_f;

#pragma unroll
  for (int j = 0; j < 4; j++) {
    int idx = j * 256 + tid;  // 0..1023 ushort8 units
    int l2 = idx >> 6;        // 0..15
    int c8 = idx & 63;        // ushort8 col
    ushort8 v = *(const ushort8*)(up + (size_t)l2 * DN + c8 * 8);
    *(ushort8*)&ub[c8 >> 4][l2][(c8 & 15) * 8] = v;
  }
  __syncthreads();

  f32x4 am0 = (f32x4){0.f, 0.f, 0.f, 0.f};
  f32x4 am1 = (f32x4){0.f, 0.f, 0.f, 0.f};
  f32x4 am2 = (f32x4){0.f, 0.f, 0.f, 0.f};
#pragma unroll
  for (int ks = 0; ks < 4; ks++) {
    bf16x8 bfrag = *(bf16x8*)&ub[w][rlo][ks * 32 + kseg];
    const unsigned short* xp = xwb + (size_t)(w * 128 + ks * 32 + kseg);
    bf16x8 a0 = *(const bf16x8*)(xp + (size_t)(0 + rlo) * 512);
    bf16x8 a1 = *(const bf16x8*)(xp + (size_t)(16 + rlo) * 512);
    bf16x8 a2 = *(const bf16x8*)(xp + (size_t)(32 + rlo) * 512);
    am0 = __builtin_amdgcn_mfma_f32_16x16x32_bf16(a0, bfrag, am0, 0, 0, 0);
    am1 = __builtin_amdgcn_mfma_f32_16x16x32_bf16(a1, bfrag, am1, 0, 0, 0);
    am2 = __builtin_amdgcn_mfma_f32_16x16x32_bf16(a2, bfrag, am2, 0, 0, 0);
  }
  {
    const int rbase = hi4 * 4;
#pragma unroll
    for (int r = 0; r < 4; r++) red[w][0 + rbase + r][rlo] = am0[r];
#pragma unroll
    for (int r = 0; r < 4; r++) red[w][16 + rbase + r][rlo] = am1[r];
#pragma unroll
    for (int r = 0; r < 4; r++) red[w][32 + rbase + r][rlo] = am2[r];
  }
  __syncthreads();
  // reduce across waves + scatter (dt rows -> global dtv_g)
  float* dtvp = dtv_g + (((size_t)(rev * BB + b) * NLT + lt) * 16) * 16;
#pragma unroll
  for (int i = 0; i < 3; i++) {
    int o = i * 256 + tid;  // 0..767
    int row = o >> 4, col = o & 15;
    float s = (red[0][row][col] + red[1][row][col]) +
              (red[2][row][col] + red[3][row][col]);
    if (row < 16)
      dtvp[(size_t)row * 16 + col] = s;  // contiguous 1 KB block, coalesced
    else if (row < 32)
      B_out[((size_t)b * LL + l0 + col) * NS + (row - 16)] = s;
    else
      C_out[((size_t)b * LL + l0 + col) * NS + (row - 32)] = s;
  }
}

// ---------------------------------------------------------------------------
// delta_kernel: dl[b][l][d] = softplus(dt_w @ dtv + dt_b). Streaming, 1 KB
// LDS, high occupancy; the former xdbl tail with no MFMA phases in front.
// Grid (NLT, BB, 2).
// ---------------------------------------------------------------------------
__global__ __launch_bounds__(256) void delta_kernel(
    const float* __restrict__ dtv_g,
    const float* __restrict__ dtw_f, const float* __restrict__ dtb_f,
    const float* __restrict__ dtw_r, const float* __restrict__ dtb_r,
    float* __restrict__ dl_f, float* __restrict__ dl_r) {
  __shared__ float dtv[16][17];
  const int rev = blockIdx.z;
  const int b = blockIdx.y;
  const int lt = blockIdx.x;
  const int l0 = lt * 16;
  const int tid = threadIdx.x;
  const float* dt_w = rev ? dtw_r : dtw_f;
  const float* dt_b = rev ? dtb_r : dtb_f;
  float* dl_out = rev ? dl_r : dl_f;

  {
    const float* dtvp = dtv_g + (((size_t)(rev * BB + b) * NLT + lt) * 16) * 16;
    dtv[tid >> 4][tid & 15] = dtvp[tid];
  }
  __syncthreads();

#pragma unroll
  for (int half = 0; half < 2; half++) {
    int dd = half * 256 + tid;
    const float4* wr = (const float4*)(dt_w + (size_t)dd * RK);
    float4 w0 = wr[0], w1 = wr[1], w2 = wr[2], w3 = wr[3];
    float bias = dt_b[dd];
#pragma unroll
    for (int l2 = 0; l2 < 16; l2++) {
      float a0 = bias;
      a0 = fmaf(w0.x, dtv[0][l2], a0);  a0 = fmaf(w0.y, dtv[1][l2], a0);
      a0 = fmaf(w0.z, dtv[2][l2], a0);  a0 = fmaf(w0.w, dtv[3][l2], a0);
      a0 = fmaf(w1.x, dtv[4][l2], a0);  a0 = fmaf(w1.y, dtv[5][l2], a0);
      a0 = fmaf(w1.z, dtv[6][l2], a0);  a0 = fmaf(w1.w, dtv[7][l2], a0);
      a0 = fmaf(w2.x, dtv[8][l2], a0);  a0 = fmaf(w2.y, dtv[9][l2], a0);
      a0 = fmaf(w2.z, dtv[10][l2], a0); a0 = fmaf(w2.w, dtv[11][l2], a0);
      a0 = fmaf(w3.x, dtv[12][l2], a0); a0 = fmaf(w3.y, dtv[13][l2], a0);
      a0 = fmaf(w3.z, dtv[14][l2], a0); a0 = fmaf(w3.w, dtv[15][l2], a0);
      dl_out[((size_t)b * LL + l0 + l2) * DN + dd] = fsoftplus(a0);
    }
  }
}

// ---------------------------------------------------------------------------
// Scan (LDS-staged): block = 256 channels x 1 chunk (uniform b/rev). Stage
// the ENTIRE chunk tile with independent coalesced loads, then run the
// 16-step recurrence from LDS. u/z/y BF16, dl fp32. y in place over u.
// ---------------------------------------------------------------------------
#define HSTEP(n, Bcomp, Ccomp)                      \
  {                                                 \
    float e_ = __expf(dc * Av[n]);                  \
    h[n] = fmaf(e_, h[n], dlu * (Bcomp));           \
    if (PHASE == 3) acc = fmaf(h[n], (Ccomp), acc); \
  }

template <int PHASE>
__global__ __launch_bounds__(256) void scan_kernel(
    unsigned short* __restrict__ uy_f, unsigned short* __restrict__ uy_r,
    const float* __restrict__ dl_f, const float* __restrict__ dl_r,
    const unsigned short* __restrict__ z_t, const float* __restrict__ B_f,
    const float* __restrict__ C_f, const float* __restrict__ B_r,
    const float* __restrict__ C_r, const float* __restrict__ A_log,
    const float* __restrict__ Ab_log, const float* __restrict__ D_f,
    const float* __restrict__ D_r, float* __restrict__ hend,
    float* __restrict__ sumdl) {
  __shared__ unsigned short us[CL2][256];  // 8 KB
  __shared__ unsigned short zs[CL2][256];  // 8 KB
  __shared__ float dls[CL2][256];          // 16 KB
  __shared__ float Bs[CL2][16];            // 1 KB
  __shared__ float Cs[CL2][16];            // 1 KB
  const int G2 = 2 * BB * DN;              // 4096
  const int tid = threadIdx.x;
  const int ch0 = (blockIdx.x & 15) * 256;
  const int chunk = blockIdx.x >> 4;  // 0..NC2-1
  const int ch = ch0 + tid;
  const bool rev = ch0 >= BB * DN;  // uniform per block
  const int cid0 = rev ? ch0 - BB * DN : ch0;
  const int b = cid0 >> 9;
  const int d0 = cid0 & (DN - 1);  // thread's d = d0 + tid
  const int d = d0 + tid;

  const float* Arow = (rev ? Ab_log : A_log) + d * NS;
  float Av[NS];
#pragma unroll
  for (int n = 0; n < NS; n++) Av[n] = -__expf(Arow[n]);
  const float Dd = (rev ? D_r : D_f)[d];

  const int tlo = rev ? (LL - CL2 * (chunk + 1)) : (CL2 * chunk);
  unsigned short* uyb = (rev ? uy_r : uy_f) + ((size_t)b * LL + tlo) * DN + d0;
  const float* dlb = (rev ? dl_r : dl_f) + ((size_t)b * LL + tlo) * DN + d0;
  const unsigned short* zb = z_t + ((size_t)b * LL + tlo) * DN + d0;
  const float* Bp = (rev ? B_r : B_f) + ((size_t)b * LL + tlo) * NS;
  const float* Cp = (rev ? C_r : C_f) + ((size_t)b * LL + tlo) * NS;

  // ---- stage the whole chunk tile ----
  {
    const int lane = tid & 63;
    const int w = tid >> 6;  // wave stages rows w*4..w*4+3
#pragma unroll
    for (int j4 = 0; j4 < 4; j4++) {
      int row = w * 4 + j4;
      ushort4v uu = *(const ushort4v*)(uyb + (size_t)row * DN + lane * 4);
      *(ushort4v*)&us[row][lane * 4] = uu;
      float4 dd4 = *(const float4*)(dlb + (size_t)row * DN + lane * 4);
      *(float4*)&dls[row][lane * 4] = dd4;
      if (PHASE == 3) {
        ushort4v zz = *(const ushort4v*)(zb + (size_t)row * DN + lane * 4);
        *(ushort4v*)&zs[row][lane * 4] = zz;
      }
    }
    Bs[tid >> 4][tid & 15] = Bp[(size_t)(tid >> 4) * NS + (tid & 15)];
    if (PHASE == 3) Cs[tid >> 4][tid & 15] = Cp[(size_t)(tid >> 4) * NS + (tid & 15)];
  }

  float h[NS];
  if (PHASE == 3) {
    const float* hp = hend + ((size_t)chunk * G2 + ch) * NS;
#pragma unroll
    for (int n = 0; n < NS; n++) h[n] = hp[n];
  } else {
#pragma unroll
    for (int n = 0; n < NS; n++) h[n] = 0.f;
  }
  __syncthreads();

  float sdl = 0.f;
#pragma unroll
  for (int jj = 0; jj < CL2; jj++) {
    const int j = rev ? (CL2 - 1 - jj) : jj;
    const float uc = bf2f(us[j][tid]);
    const float dc = dls[j][tid];
    const float4 Bq0 = *(const float4*)&Bs[j][0];
    const float4 Bq1 = *(const float4*)&Bs[j][4];
    const float4 Bq2 = *(const float4*)&Bs[j][8];
    const float4 Bq3 = *(const float4*)&Bs[j][12];
    float4 Cq0 = {0, 0, 0, 0}, Cq1 = {0, 0, 0, 0}, Cq2 = {0, 0, 0, 0},
           Cq3 = {0, 0, 0, 0};
    if (PHASE == 3) {
      Cq0 = *(const float4*)&Cs[j][0];
      Cq1 = *(const float4*)&Cs[j][4];
      Cq2 = *(const float4*)&Cs[j][8];
      Cq3 = *(const float4*)&Cs[j][12];
    }
    const float dlu = dc * uc;
    float acc = 0.f;
    HSTEP(0, Bq0.x, Cq0.x)  HSTEP(1, Bq0.y, Cq0.y)
    HSTEP(2, Bq0.z, Cq0.z)  HSTEP(3, Bq0.w, Cq0.w)
    HSTEP(4, Bq1.x, Cq1.x)  HSTEP(5, Bq1.y, Cq1.y)
    HSTEP(6, Bq1.z, Cq1.z)  HSTEP(7, Bq1.w, Cq1.w)
    HSTEP(8, Bq2.x, Cq2.x)  HSTEP(9, Bq2.y, Cq2.y)
    HSTEP(10, Bq2.z, Cq2.z) HSTEP(11, Bq2.w, Cq2.w)
    HSTEP(12, Bq3.x, Cq3.x) HSTEP(13, Bq3.y, Cq3.y)
    HSTEP(14, Bq3.z, Cq3.z) HSTEP(15, Bq3.w, Cq3.w)
    if (PHASE == 1) sdl += dc;
    if (PHASE == 3) {
      const float zc = bf2f(zs[j][tid]);
      float y = fmaf(uc, Dd, acc) * zc;
      uyb[(size_t)j * DN + tid] = f2bf(y);
    }
  }
  if (PHASE == 1) {
    float* hp = hend + ((size_t)chunk * G2 + ch) * NS;
#pragma unroll
    for (int n = 0; n < NS; n++) hp[n] = h[n];
    sumdl[(size_t)chunk * G2 + ch] = sdl;
  }
}
#undef HSTEP

// ---------------------------------------------------------------------------
// Phase 2 (in-place, LDS-tiled): batch-loaded slabs keep global loads off the
// dependent chain.
// ---------------------------------------------------------------------------
__global__ __launch_bounds__(256) void scan_combine_kernel(
    const float* __restrict__ A_log, const float* __restrict__ Ab_log,
    float* __restrict__ hend, const float* __restrict__ sumdl) {
  const int G2 = 2 * BB * DN;
  __shared__ float tile[8][256];
  __shared__ float sd[8][16];
  const int tid = threadIdx.x;
  const int ch0 = blockIdx.x * 16;
  const int chl = tid >> 4;  // local channel 0..15
  const int n = tid & 15;
  const int ch = ch0 + chl;
  const bool rev = ch >= BB * DN;
  const int d = ch & (DN - 1);
  const float Av = -__expf((rev ? Ab_log : A_log)[d * NS + n]);
  float H = 0.f;
  for (int cb = 0; cb < NC2 / 8; cb++) {
#pragma unroll
    for (int j = 0; j < 8; j++)
      tile[j][tid] = hend[((size_t)(cb * 8 + j) * G2 + ch0) * NS + tid];
    if (tid < 128) {
      int j = tid >> 4, k = tid & 15;
      sd[j][k] = sumdl[(size_t)(cb * 8 + j) * G2 + ch0 + k];
    }
    __syncthreads();
#pragma unroll
    for (int j = 0; j < 8; j++) {
      float tmp = tile[j][tid];
      tile[j][tid] = H;
      H = fmaf(__expf(Av * sd[j][chl]), H, tmp);
    }
    __syncthreads();
#pragma unroll
    for (int j = 0; j < 8; j++)
      hend[((size_t)(cb * 8 + j) * G2 + ch0) * NS + tid] = tile[j][tid];
    __syncthreads();
  }
}

// ---------------------------------------------------------------------------
// out_proj via bf16 MFMA: y BF16 [b][l][d] -> direct ushort8 loads.
// ---------------------------------------------------------------------------
__global__ __launch_bounds__(256) void out_proj_mfma(
    const unsigned short* __restrict__ yf, const unsigned short* __restrict__ yr,
    const float* __restrict__ ow, float* __restrict__ outp) {
  __shared__ unsigned short yt[64][40];
  __shared__ unsigned short wo[64][40];
  const int b = blockIdx.z;
  const int m0 = blockIdx.y * 64;
  const int l0 = blockIdx.x * 64;
  const int tid = threadIdx.x;
  const int lane = tid & 63;
  const int wid = tid >> 6;
  const int wm = wid >> 1, wn = wid & 1;
  const int krow = (lane >> 4) * 8;
  const int rlo = lane & 15;

  f32x4 acc[2][2];
#pragma unroll
  for (int i = 0; i < 2; i++)
#pragma unroll
    for (int j = 0; j < 2; j++) acc[i][j] = (f32x4){0.f, 0.f, 0.f, 0.f};

  for (int dk = 0; dk < DN; dk += 32) {
    {
      int row = tid >> 2;
      int seg = (tid & 3) * 8;
      ushort8 a = *(const ushort8*)(yf + ((size_t)b * LL + l0 + row) * DN + dk + seg);
      ushort8 c = *(const ushort8*)(yr + ((size_t)b * LL + l0 + row) * DN + dk + seg);
      ushort8 yv;
#pragma unroll
      for (int k = 0; k < 8; k++) yv[k] = f2bf(0.5f * (bf2f(a[k]) + bf2f(c[k])));
      *(ushort8*)&yt[row][seg] = yv;
      const float* wp = ow + (size_t)(m0 + row) * DN + dk + seg;
      float4 w0 = *(const float4*)wp, w1 = *(const float4*)(wp + 4);
      ushort8 wv;
      wv[0] = f2bf(w0.x); wv[1] = f2bf(w0.y); wv[2] = f2bf(w0.z); wv[3] = f2bf(w0.w);
      wv[4] = f2bf(w1.x); wv[5] = f2bf(w1.y); wv[6] = f2bf(w1.z); wv[7] = f2bf(w1.w);
      *(ushort8*)&wo[row][seg] = wv;
    }
    __syncthreads();
    bf16x8 a0 = *(bf16x8*)&yt[wm * 32 + rlo][krow];
    bf16x8 a1 = *(bf16x8*)&yt[wm * 32 + 16 + rlo][krow];
    bf16x8 b0 = *(bf16x8*)&wo[wn * 32 + rlo][krow];
    bf16x8 b1 = *(bf16x8*)&wo[wn * 32 + 16 + rlo][krow];
    acc[0][0] = __builtin_amdgcn_mfma_f32_16x16x32_bf16(a0, b0, acc[0][0], 0, 0, 0);
    acc[0][1] = __builtin_amdgcn_mfma_f32_16x16x32_bf16(a0, b1, acc[0][1], 0, 0, 0);
    acc[1][0] = __builtin_amdgcn_mfma_f32_16x16x32_bf16(a1, b0, acc[1][0], 0, 0, 0);
    acc[1][1] = __builtin_amdgcn_mfma_f32_16x16x32_bf16(a1, b1, acc[1][1], 0, 0, 0);
    __syncthreads();
  }
#pragma unroll
  for (int mt = 0; mt < 2; mt++)
#pragma unroll
    for (int nt = 0; nt < 2; nt++)
#pragma unroll
      for (int r = 0; r < 4; r++) {
        int l = l0 + wm * 32 + mt * 16 + (lane >> 4) * 4 + r;
        int m = m0 + wn * 32 + nt * 16 + rlo;
        outp[((size_t)b * LL + l) * DM + m] = acc[mt][nt][r];
      }
}

// ---------------------------------------------------------------------------
extern "C" void kernel_launch(void* const* d_in, const int* in_sizes, int n_in,
                              void* d_out, int out_size, void* d_ws, size_t ws_size,
                              hipStream_t stream) {
  (void)in_sizes; (void)n_in; (void)out_size; (void)ws_size;
  const float* A_log = (const float*)d_in[2];
  const float* Ab_log = (const float*)d_in[3];

  const size_t SZ = (size_t)BB * LL * DN;      // 4,194,304 elements
  const size_t NSZ = (size_t)BB * LL * NS;     // 131,072
  float* ws = (float*)d_ws;
  float* dl_f = ws;                            // SZ fp32
  float* dl_r = dl_f + SZ;                     // SZ fp32
  float* B_f = dl_r + SZ;                      // NSZ
  float* C_f = B_f + NSZ;
  float* B_r = C_f + NSZ;
  float* C_r = B_r + NSZ;
  float* sumdl = C_r + NSZ;                    // NC2*G2 = 524,288
  float* dtv_g = sumdl + (size_t)NC2 * 2 * BB * DN;  // 2*BB*NLT*256 = 262,144
  unsigned short* xwbf_f = (unsigned short*)(dtv_g + (size_t)2 * BB * NLT * 256);
  unsigned short* xwbf_r = xwbf_f + 48 * 512;
  unsigned short* z_t = xwbf_r + 48 * 512;     // SZ bf16
  unsigned short* u_f = z_t + SZ;              // SZ bf16 (u -> y in place)
  unsigned short* u_r = u_f + SZ;              // SZ bf16
  float* xz = (float*)(u_r + SZ);              // SZ fp32 (dead after conv)
  float* hend = xz;  // ALIAS: NC2*G2*NS floats (xz region + tail extension)

  for (int s = 0; s < 2; s++) {
    const int p = 4 + s * 14;
    const float* hin = (const float*)d_in[s];
    const float* in_w = (const float*)d_in[p + 0];
    const float* conv_w = (const float*)d_in[p + 1];
    const float* conv_b = (const float*)d_in[p + 2];
    const float* x_w = (const float*)d_in[p + 3];
    const float* dt_w = (const float*)d_in[p + 4];
    const float* dt_b = (const float*)d_in[p + 5];
    const float* Dp = (const float*)d_in[p + 6];
    const float* conv_w_b = (const float*)d_in[p + 7];
    const float* conv_b_b = (const float*)d_in[p + 8];
    const float* x_w_b = (const float*)d_in[p + 9];
    const float* dt_w_b = (const float*)d_in[p + 10];
    const float* dt_b_b = (const float*)d_in[p + 11];
    const float* Dp_b = (const float*)d_in[p + 12];
    const float* out_w = (const float*)d_in[p + 13];
    float* outp = (float*)d_out + (size_t)s * BB * LL * DM;

    hipLaunchKernelGGL(in_proj_mfma, dim3(LL / 128, EE / 128, BB), dim3(256), 0,
                       stream, hin, in_w, xz, z_t);
    hipLaunchKernelGGL(xw_prep_kernel, dim3(96), dim3(256), 0, stream,
                       x_w, x_w_b, xwbf_f, xwbf_r);
    hipLaunchKernelGGL(conv_kernel, dim3((LL / 32) * 4, BB, 2), dim3(256), 0,
                       stream, xz, conv_w, conv_b, conv_w_b, conv_b_b, u_f, u_r);
    hipLaunchKernelGGL(xdbl_kernel, dim3(NLT, BB, 2), dim3(256), 0, stream,
                       u_f, u_r, xwbf_f, xwbf_r, dtv_g, B_f, C_f, B_r, C_r);
    hipLaunchKernelGGL(delta_kernel, dim3(NLT, BB, 2), dim3(256), 0, stream,
                       dtv_g, dt_w, dt_b, dt_w_b, dt_b_b, dl_f, dl_r);
    hipLaunchKernelGGL(HIP_KERNEL_NAME(scan_kernel<1>), dim3(NC2 * 16), dim3(256), 0,
                       stream, u_f, u_r, dl_f, dl_r, z_t, B_f, C_f, B_r, C_r, A_log,
                       Ab_log, Dp, Dp_b, hend, sumdl);
    hipLaunchKernelGGL(scan_combine_kernel, dim3(2 * BB * DN / 16), dim3(256),
                       0, stream, A_log, Ab_log, hend, sumdl);
    hipLaunchKernelGGL(HIP_KERNEL_NAME(scan_kernel<3>), dim3(NC2 * 16), dim3(256), 0,
                       stream, u_f, u_r, dl_f, dl_r, z_t, B_f, C_f, B_r, C_r, A_log,
                       Ab_log, Dp, Dp_b, hend, sumdl);
    hipLaunchKernelGGL(out_proj_mfma, dim3(LL / 64, DM / 64, BB), dim3(256), 0,
                       stream, u_f, u_r, out_w, outp);
  }
}

// Round 18
// 360.999 us; speedup vs baseline: 1.0152x; 1.0152x over previous
//
#include <hip/hip_runtime.h>
#include <hip/hip_bf16.h>
#include <cstddef>

#define BB 4
#define LL 2048
#define DM 256
#define DN 512
#define EE 1024
#define NS 16
#define RK 16
#define NC2 128         // scan chunks
#define CL2 (LL / NC2)  // chunk length = 16
#define NLT (LL / 16)   // l-tiles for xdbl/delta = 128

typedef __attribute__((ext_vector_type(8))) short bf16x8;
typedef __attribute__((ext_vector_type(8))) unsigned short ushort8;
typedef __attribute__((ext_vector_type(4))) unsigned short ushort4v;
typedef __attribute__((ext_vector_type(2))) unsigned short ushort2v;
typedef __attribute__((ext_vector_type(4))) float f32x4;

__device__ __forceinline__ float fsilu(float x) { return x / (1.0f + __expf(-x)); }
__device__ __forceinline__ float fsoftplus(float x) { return x > 20.0f ? x : log1pf(__expf(x)); }
__device__ __forceinline__ unsigned short f2bf(float x) {  // RNE float->bf16
  union { float f; unsigned int u; } v; v.f = x;
  unsigned int r = v.u + 0x7fffu + ((v.u >> 16) & 1u);
  return (unsigned short)(r >> 16);
}
__device__ __forceinline__ float bf2f(unsigned short x) {
  union { unsigned int u; float f; } v; v.u = ((unsigned int)x) << 16;
  return v.f;
}

// ---------------------------------------------------------------------------
// in_proj via bf16 MFMA. Tile 128e x 64l, 4 waves (wave = 32 e-rows),
// grid 1024 blocks (4/CU). x-blocks: C[e][l] -> xz BF16 [b][e][l].
// z-blocks: swap A/B so C[l][d] -> z_t[b][l][d] = silu, BF16.
// ---------------------------------------------------------------------------
__global__ __launch_bounds__(256) void in_proj_mfma(
    const float* __restrict__ h, const float* __restrict__ w,
    unsigned short* __restrict__ xz, unsigned short* __restrict__ z_t) {
  __shared__ unsigned short ht[64][40];   // [l][k] bf16
  __shared__ unsigned short wt[128][40];  // [e][k]
  const int b = blockIdx.z;
  const int e0 = blockIdx.y * 128;
  const int l0 = blockIdx.x * 64;
  const int tid = threadIdx.x;
  const int lane = tid & 63;
  const int wv = tid >> 6;  // wave 0..3 -> e rows [wv*32, wv*32+32)
  const bool zblk = (e0 >= DN);
  const int krow = (lane >> 4) * 8;
  const int rlo = lane & 15;
  const int rbase = (lane >> 4) * 4;

  f32x4 acc[8];
#pragma unroll
  for (int i = 0; i < 8; i++) acc[i] = (f32x4){0.f, 0.f, 0.f, 0.f};

  for (int dk = 0; dk < DM; dk += 32) {
    {  // stage h tile [64 l][32 k]: 1 ushort8 per thread
      int row = tid >> 2;
      int seg = (tid & 3) * 8;
      const float* hp = h + ((size_t)b * LL + l0 + row) * DM + dk + seg;
      float4 ha = *(const float4*)hp, hb = *(const float4*)(hp + 4);
      ushort8 hv;
      hv[0] = f2bf(ha.x); hv[1] = f2bf(ha.y); hv[2] = f2bf(ha.z); hv[3] = f2bf(ha.w);
      hv[4] = f2bf(hb.x); hv[5] = f2bf(hb.y); hv[6] = f2bf(hb.z); hv[7] = f2bf(hb.w);
      *(ushort8*)&ht[row][seg] = hv;
    }
#pragma unroll
    for (int it = 0; it < 2; it++) {  // stage w tile [128 e][32 k]
      int idx = it * 256 + tid;
      int row = idx >> 2;
      int seg = (idx & 3) * 8;
      const float* wp = w + (size_t)(e0 + row) * DM + dk + seg;
      float4 wa = *(const float4*)wp, wb = *(const float4*)(wp + 4);
      ushort8 wv8;
      wv8[0] = f2bf(wa.x); wv8[1] = f2bf(wa.y); wv8[2] = f2bf(wa.z); wv8[3] = f2bf(wa.w);
      wv8[4] = f2bf(wb.x); wv8[5] = f2bf(wb.y); wv8[6] = f2bf(wb.z); wv8[7] = f2bf(wb.w);
      *(ushort8*)&wt[row][seg] = wv8;
    }
    __syncthreads();
    if (!zblk) {
      // A = e rows (wave's 2x16), B = l rows (4x16); acc[m*4+n]
      bf16x8 af0 = *(bf16x8*)&wt[wv * 32 + 0 * 16 + rlo][krow];
      bf16x8 af1 = *(bf16x8*)&wt[wv * 32 + 1 * 16 + rlo][krow];
      bf16x8 bf0 = *(bf16x8*)&ht[0 * 16 + rlo][krow];
      bf16x8 bf1 = *(bf16x8*)&ht[1 * 16 + rlo][krow];
      bf16x8 bf2 = *(bf16x8*)&ht[2 * 16 + rlo][krow];
      bf16x8 bf3 = *(bf16x8*)&ht[3 * 16 + rlo][krow];
      acc[0] = __builtin_amdgcn_mfma_f32_16x16x32_bf16(af0, bf0, acc[0], 0, 0, 0);
      acc[1] = __builtin_amdgcn_mfma_f32_16x16x32_bf16(af0, bf1, acc[1], 0, 0, 0);
      acc[2] = __builtin_amdgcn_mfma_f32_16x16x32_bf16(af0, bf2, acc[2], 0, 0, 0);
      acc[3] = __builtin_amdgcn_mfma_f32_16x16x32_bf16(af0, bf3, acc[3], 0, 0, 0);
      acc[4] = __builtin_amdgcn_mfma_f32_16x16x32_bf16(af1, bf0, acc[4], 0, 0, 0);
      acc[5] = __builtin_amdgcn_mfma_f32_16x16x32_bf16(af1, bf1, acc[5], 0, 0, 0);
      acc[6] = __builtin_amdgcn_mfma_f32_16x16x32_bf16(af1, bf2, acc[6], 0, 0, 0);
      acc[7] = __builtin_amdgcn_mfma_f32_16x16x32_bf16(af1, bf3, acc[7], 0, 0, 0);
    } else {
      // A = l rows (4x16), B = d rows (wave's 2x16); acc[m*2+n]
      bf16x8 af0 = *(bf16x8*)&ht[0 * 16 + rlo][krow];
      bf16x8 af1 = *(bf16x8*)&ht[1 * 16 + rlo][krow];
      bf16x8 af2 = *(bf16x8*)&ht[2 * 16 + rlo][krow];
      bf16x8 af3 = *(bf16x8*)&ht[3 * 16 + rlo][krow];
      bf16x8 bf0 = *(bf16x8*)&wt[wv * 32 + 0 * 16 + rlo][krow];
      bf16x8 bf1 = *(bf16x8*)&wt[wv * 32 + 1 * 16 + rlo][krow];
      acc[0] = __builtin_amdgcn_mfma_f32_16x16x32_bf16(af0, bf0, acc[0], 0, 0, 0);
      acc[1] = __builtin_amdgcn_mfma_f32_16x16x32_bf16(af0, bf1, acc[1], 0, 0, 0);
      acc[2] = __builtin_amdgcn_mfma_f32_16x16x32_bf16(af1, bf0, acc[2], 0, 0, 0);
      acc[3] = __builtin_amdgcn_mfma_f32_16x16x32_bf16(af1, bf1, acc[3], 0, 0, 0);
      acc[4] = __builtin_amdgcn_mfma_f32_16x16x32_bf16(af2, bf0, acc[4], 0, 0, 0);
      acc[5] = __builtin_amdgcn_mfma_f32_16x16x32_bf16(af2, bf1, acc[5], 0, 0, 0);
      acc[6] = __builtin_amdgcn_mfma_f32_16x16x32_bf16(af3, bf0, acc[6], 0, 0, 0);
      acc[7] = __builtin_amdgcn_mfma_f32_16x16x32_bf16(af3, bf1, acc[7], 0, 0, 0);
    }
    __syncthreads();
  }
  if (!zblk) {
#pragma unroll
    for (int m = 0; m < 2; m++)
#pragma unroll
      for (int n = 0; n < 4; n++)
#pragma unroll
        for (int r = 0; r < 4; r++) {
          int e = e0 + wv * 32 + m * 16 + rbase + r;
          int l = l0 + n * 16 + rlo;
          xz[((size_t)b * DN + e) * LL + l] = f2bf(acc[m * 4 + n][r]);
        }
  } else {
#pragma unroll
    for (int m = 0; m < 4; m++)
#pragma unroll
      for (int n = 0; n < 2; n++)
#pragma unroll
        for (int r = 0; r < 4; r++) {
          int l = l0 + m * 16 + rbase + r;
          int d = (e0 - DN) + wv * 32 + n * 16 + rlo;
          z_t[((size_t)b * LL + l) * DN + d] = f2bf(fsilu(acc[m * 2 + n][r]));
        }
  }
}

// ---------------------------------------------------------------------------
// conv_kernel: streaming conv+silu+transpose. xz now BF16. Writes u BF16.
// ---------------------------------------------------------------------------
__global__ __launch_bounds__(256) void conv_kernel(
    const unsigned short* __restrict__ xz,
    const float* __restrict__ cw_f, const float* __restrict__ cb_f,
    const float* __restrict__ cw_r, const float* __restrict__ cb_r,
    unsigned short* __restrict__ u_f, unsigned short* __restrict__ u_r) {
  __shared__ float xt[128][33];
  const int rev = blockIdx.z;
  const int b = blockIdx.y;
  const int dc0 = (blockIdx.x & 3) * 128;
  const int l0 = (blockIdx.x >> 2) * 32;
  const int tid = threadIdx.x;
  const int lc = tid & 31;
  const int dg = tid >> 5;  // 0..7
  const int l = l0 + lc;
  const float* conv_w = rev ? cw_r : cw_f;
  const float* conv_b = rev ? cb_r : cb_f;
  unsigned short* u_out = rev ? u_r : u_f;

#pragma unroll
  for (int i = 0; i < 16; i++) {
    int dloc = dg * 16 + i;
    int dd = dc0 + dloc;
    const unsigned short* base = xz + ((size_t)b * DN + dd) * LL;
    float4 cw4 = *(const float4*)(conv_w + dd * 4);
    float a0 = conv_b[dd];
    if (rev) {
      a0 = fmaf(cw4.w, bf2f(base[l]), a0);
      if (l + 1 < LL) a0 = fmaf(cw4.z, bf2f(base[l + 1]), a0);
      if (l + 2 < LL) a0 = fmaf(cw4.y, bf2f(base[l + 2]), a0);
      if (l + 3 < LL) a0 = fmaf(cw4.x, bf2f(base[l + 3]), a0);
    } else {
      a0 = fmaf(cw4.w, bf2f(base[l]), a0);
      if (l - 1 >= 0) a0 = fmaf(cw4.z, bf2f(base[l - 1]), a0);
      if (l - 2 >= 0) a0 = fmaf(cw4.y, bf2f(base[l - 2]), a0);
      if (l - 3 >= 0) a0 = fmaf(cw4.x, bf2f(base[l - 3]), a0);
    }
    xt[dloc][lc] = fsilu(a0);
  }
  __syncthreads();
#pragma unroll
  for (int j = 0; j < 8; j++) {
    int idx = j * 256 + tid;  // 0..2047 ushort2 units
    int d2 = idx & 63;        // ushort2 column (d = 2*d2)
    int l2 = idx >> 6;        // 0..31
    ushort2v v;
    v[0] = f2bf(xt[2 * d2][l2]);
    v[1] = f2bf(xt[2 * d2 + 1][l2]);
    *(ushort2v*)&u_out[((size_t)b * LL + l0 + l2) * DN + dc0 + 2 * d2] = v;
  }
}

// ---------------------------------------------------------------------------
// prep: convert x_w (48x512 fp32) of both branches to bf16 global.
// ---------------------------------------------------------------------------
__global__ __launch_bounds__(256) void xw_prep_kernel(
    const float* __restrict__ xw_f, const float* __restrict__ xw_r,
    unsigned short* __restrict__ o_f, unsigned short* __restrict__ o_r) {
  int i = blockIdx.x * 256 + threadIdx.x;
  if (i < 48 * 512) {
    o_f[i] = f2bf(xw_f[i]);
    o_r[i] = f2bf(xw_r[i]);
  }
}

// ---------------------------------------------------------------------------
// xdbl_kernel: x_dbl GEMM (48 x 16l x 512). Stage u tile, 12 MFMA per wave,
// LDS reduce, scatter: dt rows -> dtv_g (global), B/C rows -> B/C buffers.
// ---------------------------------------------------------------------------
__global__ __launch_bounds__(256) void xdbl_kernel(
    const unsigned short* __restrict__ u_f, const unsigned short* __restrict__ u_r,
    const unsigned short* __restrict__ xwb_f,
    const unsigned short* __restrict__ xwb_r,
    float* __restrict__ dtv_g,
    float* __restrict__ B_f, float* __restrict__ C_f,
    float* __restrict__ B_r, float* __restrict__ C_r) {
  __shared__ __align__(16) unsigned short ub[4][16][136];  // u tile, per k-chunk
  __shared__ float red[4][48][17];                         // per-wave partials
  const int rev = blockIdx.z;
  const int b = blockIdx.y;
  const int lt = blockIdx.x;  // l-tile index
  const int l0 = lt * 16;
  const int tid = threadIdx.x;
  const int lane = tid & 63;
  const int w = tid >> 6;  // wave = k-chunk 0..3
  const int rlo = lane & 15;
  const int hi4 = lane >> 4;  // 0..3
  const int kseg = hi4 * 8;

  const unsigned short* up = (rev ? u_r : u_f) + ((size_t)b * LL + l0) * DN;
  const unsigned short* xwb = rev ? xwb_r : xwb_f;
  float* B_out = rev ? B_r : B_f;
  float* C_out = rev ? C_r : C_f;

#pragma unroll
  for (int j = 0; j < 4; j++) {
    int idx = j * 256 + tid;  // 0..1023 ushort8 units
    int l2 = idx >> 6;        // 0..15
    int c8 = idx & 63;        // ushort8 col
    ushort8 v = *(const ushort8*)(up + (size_t)l2 * DN + c8 * 8);
    *(ushort8*)&ub[c8 >> 4][l2][(c8 & 15) * 8] = v;
  }
  __syncthreads();

  f32x4 am0 = (f32x4){0.f, 0.f, 0.f, 0.f};
  f32x4 am1 = (f32x4){0.f, 0.f, 0.f, 0.f};
  f32x4 am2 = (f32x4){0.f, 0.f, 0.f, 0.f};
#pragma unroll
  for (int ks = 0; ks < 4; ks++) {
    bf16x8 bfrag = *(bf16x8*)&ub[w][rlo][ks * 32 + kseg];
    const unsigned short* xp = xwb + (size_t)(w * 128 + ks * 32 + kseg);
    bf16x8 a0 = *(const bf16x8*)(xp + (size_t)(0 + rlo) * 512);
    bf16x8 a1 = *(const bf16x8*)(xp + (size_t)(16 + rlo) * 512);
    bf16x8 a2 = *(const bf16x8*)(xp + (size_t)(32 + rlo) * 512);
    am0 = __builtin_amdgcn_mfma_f32_16x16x32_bf16(a0, bfrag, am0, 0, 0, 0);
    am1 = __builtin_amdgcn_mfma_f32_16x16x32_bf16(a1, bfrag, am1, 0, 0, 0);
    am2 = __builtin_amdgcn_mfma_f32_16x16x32_bf16(a2, bfrag, am2, 0, 0, 0);
  }
  {
    const int rbase = hi4 * 4;
#pragma unroll
    for (int r = 0; r < 4; r++) red[w][0 + rbase + r][rlo] = am0[r];
#pragma unroll
    for (int r = 0; r < 4; r++) red[w][16 + rbase + r][rlo] = am1[r];
#pragma unroll
    for (int r = 0; r < 4; r++) red[w][32 + rbase + r][rlo] = am2[r];
  }
  __syncthreads();
  float* dtvp = dtv_g + (((size_t)(rev * BB + b) * NLT + lt) * 16) * 16;
#pragma unroll
  for (int i = 0; i < 3; i++) {
    int o = i * 256 + tid;  // 0..767
    int row = o >> 4, col = o & 15;
    float s = (red[0][row][col] + red[1][row][col]) +
              (red[2][row][col] + red[3][row][col]);
    if (row < 16)
      dtvp[(size_t)row * 16 + col] = s;
    else if (row < 32)
      B_out[((size_t)b * LL + l0 + col) * NS + (row - 16)] = s;
    else
      C_out[((size_t)b * LL + l0 + col) * NS + (row - 32)] = s;
  }
}

// ---------------------------------------------------------------------------
// delta_kernel: dl[b][l][d] = softplus(dt_w @ dtv + dt_b). Streaming.
// ---------------------------------------------------------------------------
__global__ __launch_bounds__(256) void delta_kernel(
    const float* __restrict__ dtv_g,
    const float* __restrict__ dtw_f, const float* __restrict__ dtb_f,
    const float* __restrict__ dtw_r, const float* __restrict__ dtb_r,
    float* __restrict__ dl_f, float* __restrict__ dl_r) {
  __shared__ float dtv[16][17];
  const int rev = blockIdx.z;
  const int b = blockIdx.y;
  const int lt = blockIdx.x;
  const int l0 = lt * 16;
  const int tid = threadIdx.x;
  const float* dt_w = rev ? dtw_r : dtw_f;
  const float* dt_b = rev ? dtb_r : dtb_f;
  float* dl_out = rev ? dl_r : dl_f;

  {
    const float* dtvp = dtv_g + (((size_t)(rev * BB + b) * NLT + lt) * 16) * 16;
    dtv[tid >> 4][tid & 15] = dtvp[tid];
  }
  __syncthreads();

#pragma unroll
  for (int half = 0; half < 2; half++) {
    int dd = half * 256 + tid;
    const float4* wr = (const float4*)(dt_w + (size_t)dd * RK);
    float4 w0 = wr[0], w1 = wr[1], w2 = wr[2], w3 = wr[3];
    float bias = dt_b[dd];
#pragma unroll
    for (int l2 = 0; l2 < 16; l2++) {
      float a0 = bias;
      a0 = fmaf(w0.x, dtv[0][l2], a0);  a0 = fmaf(w0.y, dtv[1][l2], a0);
      a0 = fmaf(w0.z, dtv[2][l2], a0);  a0 = fmaf(w0.w, dtv[3][l2], a0);
      a0 = fmaf(w1.x, dtv[4][l2], a0);  a0 = fmaf(w1.y, dtv[5][l2], a0);
      a0 = fmaf(w1.z, dtv[6][l2], a0);  a0 = fmaf(w1.w, dtv[7][l2], a0);
      a0 = fmaf(w2.x, dtv[8][l2], a0);  a0 = fmaf(w2.y, dtv[9][l2], a0);
      a0 = fmaf(w2.z, dtv[10][l2], a0); a0 = fmaf(w2.w, dtv[11][l2], a0);
      a0 = fmaf(w3.x, dtv[12][l2], a0); a0 = fmaf(w3.y, dtv[13][l2], a0);
      a0 = fmaf(w3.z, dtv[14][l2], a0); a0 = fmaf(w3.w, dtv[15][l2], a0);
      dl_out[((size_t)b * LL + l0 + l2) * DN + dd] = fsoftplus(a0);
    }
  }
}

// ---------------------------------------------------------------------------
// Scan (LDS-staged): block = 256 channels x 1 chunk (uniform b/rev). Stage
// the ENTIRE chunk tile, then run the 16-step recurrence from LDS.
// u/z/y/hend BF16, dl fp32. y in place over u.
// ---------------------------------------------------------------------------
#define HSTEP(n, Bcomp, Ccomp)                      \
  {                                                 \
    float e_ = __expf(dc * Av[n]);                  \
    h[n] = fmaf(e_, h[n], dlu * (Bcomp));           \
    if (PHASE == 3) acc = fmaf(h[n], (Ccomp), acc); \
  }

template <int PHASE>
__global__ __launch_bounds__(256) void scan_kernel(
    unsigned short* __restrict__ uy_f, unsigned short* __restrict__ uy_r,
    const float* __restrict__ dl_f, const float* __restrict__ dl_r,
    const unsigned short* __restrict__ z_t, const float* __restrict__ B_f,
    const float* __restrict__ C_f, const float* __restrict__ B_r,
    const float* __restrict__ C_r, const float* __restrict__ A_log,
    const float* __restrict__ Ab_log, const float* __restrict__ D_f,
    const float* __restrict__ D_r, unsigned short* __restrict__ hend,
    float* __restrict__ sumdl) {
  __shared__ unsigned short us[CL2][256];  // 8 KB
  __shared__ unsigned short zs[CL2][256];  // 8 KB
  __shared__ float dls[CL2][256];          // 16 KB
  __shared__ float Bs[CL2][16];            // 1 KB
  __shared__ float Cs[CL2][16];            // 1 KB
  const int G2 = 2 * BB * DN;              // 4096
  const int tid = threadIdx.x;
  const int ch0 = (blockIdx.x & 15) * 256;
  const int chunk = blockIdx.x >> 4;  // 0..NC2-1
  const int ch = ch0 + tid;
  const bool rev = ch0 >= BB * DN;  // uniform per block
  const int cid0 = rev ? ch0 - BB * DN : ch0;
  const int b = cid0 >> 9;
  const int d0 = cid0 & (DN - 1);  // thread's d = d0 + tid
  const int d = d0 + tid;

  const float* Arow = (rev ? Ab_log : A_log) + d * NS;
  float Av[NS];
#pragma unroll
  for (int n = 0; n < NS; n++) Av[n] = -__expf(Arow[n]);
  const float Dd = (rev ? D_r : D_f)[d];

  const int tlo = rev ? (LL - CL2 * (chunk + 1)) : (CL2 * chunk);
  unsigned short* uyb = (rev ? uy_r : uy_f) + ((size_t)b * LL + tlo) * DN + d0;
  const float* dlb = (rev ? dl_r : dl_f) + ((size_t)b * LL + tlo) * DN + d0;
  const unsigned short* zb = z_t + ((size_t)b * LL + tlo) * DN + d0;
  const float* Bp = (rev ? B_r : B_f) + ((size_t)b * LL + tlo) * NS;
  const float* Cp = (rev ? C_r : C_f) + ((size_t)b * LL + tlo) * NS;

  // ---- stage the whole chunk tile ----
  {
    const int lane = tid & 63;
    const int w = tid >> 6;  // wave stages rows w*4..w*4+3
#pragma unroll
    for (int j4 = 0; j4 < 4; j4++) {
      int row = w * 4 + j4;
      ushort4v uu = *(const ushort4v*)(uyb + (size_t)row * DN + lane * 4);
      *(ushort4v*)&us[row][lane * 4] = uu;
      float4 dd4 = *(const float4*)(dlb + (size_t)row * DN + lane * 4);
      *(float4*)&dls[row][lane * 4] = dd4;
      if (PHASE == 3) {
        ushort4v zz = *(const ushort4v*)(zb + (size_t)row * DN + lane * 4);
        *(ushort4v*)&zs[row][lane * 4] = zz;
      }
    }
    Bs[tid >> 4][tid & 15] = Bp[(size_t)(tid >> 4) * NS + (tid & 15)];
    if (PHASE == 3) Cs[tid >> 4][tid & 15] = Cp[(size_t)(tid >> 4) * NS + (tid & 15)];
  }

  float h[NS];
  if (PHASE == 3) {
    const unsigned short* hp = hend + ((size_t)chunk * G2 + ch) * NS;
#pragma unroll
    for (int n = 0; n < NS; n++) h[n] = bf2f(hp[n]);
  } else {
#pragma unroll
    for (int n = 0; n < NS; n++) h[n] = 0.f;
  }
  __syncthreads();

  float sdl = 0.f;
#pragma unroll
  for (int jj = 0; jj < CL2; jj++) {
    const int j = rev ? (CL2 - 1 - jj) : jj;
    const float uc = bf2f(us[j][tid]);
    const float dc = dls[j][tid];
    const float4 Bq0 = *(const float4*)&Bs[j][0];
    const float4 Bq1 = *(const float4*)&Bs[j][4];
    const float4 Bq2 = *(const float4*)&Bs[j][8];
    const float4 Bq3 = *(const float4*)&Bs[j][12];
    float4 Cq0 = {0, 0, 0, 0}, Cq1 = {0, 0, 0, 0}, Cq2 = {0, 0, 0, 0},
           Cq3 = {0, 0, 0, 0};
    if (PHASE == 3) {
      Cq0 = *(const float4*)&Cs[j][0];
      Cq1 = *(const float4*)&Cs[j][4];
      Cq2 = *(const float4*)&Cs[j][8];
      Cq3 = *(const float4*)&Cs[j][12];
    }
    const float dlu = dc * uc;
    float acc = 0.f;
    HSTEP(0, Bq0.x, Cq0.x)  HSTEP(1, Bq0.y, Cq0.y)
    HSTEP(2, Bq0.z, Cq0.z)  HSTEP(3, Bq0.w, Cq0.w)
    HSTEP(4, Bq1.x, Cq1.x)  HSTEP(5, Bq1.y, Cq1.y)
    HSTEP(6, Bq1.z, Cq1.z)  HSTEP(7, Bq1.w, Cq1.w)
    HSTEP(8, Bq2.x, Cq2.x)  HSTEP(9, Bq2.y, Cq2.y)
    HSTEP(10, Bq2.z, Cq2.z) HSTEP(11, Bq2.w, Cq2.w)
    HSTEP(12, Bq3.x, Cq3.x) HSTEP(13, Bq3.y, Cq3.y)
    HSTEP(14, Bq3.z, Cq3.z) HSTEP(15, Bq3.w, Cq3.w)
    if (PHASE == 1) sdl += dc;
    if (PHASE == 3) {
      const float zc = bf2f(zs[j][tid]);
      float y = fmaf(uc, Dd, acc) * zc;
      uyb[(size_t)j * DN + tid] = f2bf(y);
    }
  }
  if (PHASE == 1) {
    unsigned short* hp = hend + ((size_t)chunk * G2 + ch) * NS;
#pragma unroll
    for (int n = 0; n < NS; n++) hp[n] = f2bf(h[n]);
    sumdl[(size_t)chunk * G2 + ch] = sdl;
  }
}
#undef HSTEP

// ---------------------------------------------------------------------------
// Phase 2 (in-place, LDS-tiled): hend BF16. Batch-loaded slabs keep global
// loads off the dependent chain; recurrence internal state stays fp32.
// ---------------------------------------------------------------------------
__global__ __launch_bounds__(256) void scan_combine_kernel(
    const float* __restrict__ A_log, const float* __restrict__ Ab_log,
    unsigned short* __restrict__ hend, const float* __restrict__ sumdl) {
  const int G2 = 2 * BB * DN;
  __shared__ float tile[8][256];
  __shared__ float sd[8][16];
  const int tid = threadIdx.x;
  const int ch0 = blockIdx.x * 16;
  const int chl = tid >> 4;  // local channel 0..15
  const int n = tid & 15;
  const int ch = ch0 + chl;
  const bool rev = ch >= BB * DN;
  const int d = ch & (DN - 1);
  const float Av = -__expf((rev ? Ab_log : A_log)[d * NS + n]);
  float H = 0.f;
  for (int cb = 0; cb < NC2 / 8; cb++) {
#pragma unroll
    for (int j = 0; j < 8; j++)
      tile[j][tid] = bf2f(hend[((size_t)(cb * 8 + j) * G2 + ch0) * NS + tid]);
    if (tid < 128) {
      int j = tid >> 4, k = tid & 15;
      sd[j][k] = sumdl[(size_t)(cb * 8 + j) * G2 + ch0 + k];
    }
    __syncthreads();
#pragma unroll
    for (int j = 0; j < 8; j++) {
      float tmp = tile[j][tid];
      tile[j][tid] = H;
      H = fmaf(__expf(Av * sd[j][chl]), H, tmp);
    }
    __syncthreads();
#pragma unroll
    for (int j = 0; j < 8; j++)
      hend[((size_t)(cb * 8 + j) * G2 + ch0) * NS + tid] = f2bf(tile[j][tid]);
    __syncthreads();
  }
}

// ---------------------------------------------------------------------------
// out_proj via bf16 MFMA: y BF16 [b][l][d] -> direct ushort8 loads.
// ---------------------------------------------------------------------------
__global__ __launch_bounds__(256) void out_proj_mfma(
    const unsigned short* __restrict__ yf, const unsigned short* __restrict__ yr,
    const float* __restrict__ ow, float* __restrict__ outp) {
  __shared__ unsigned short yt[64][40];
  __shared__ unsigned short wo[64][40];
  const int b = blockIdx.z;
  const int m0 = blockIdx.y * 64;
  const int l0 = blockIdx.x * 64;
  const int tid = threadIdx.x;
  const int lane = tid & 63;
  const int wid = tid >> 6;
  const int wm = wid >> 1, wn = wid & 1;
  const int krow = (lane >> 4) * 8;
  const int rlo = lane & 15;

  f32x4 acc[2][2];
#pragma unroll
  for (int i = 0; i < 2; i++)
#pragma unroll
    for (int j = 0; j < 2; j++) acc[i][j] = (f32x4){0.f, 0.f, 0.f, 0.f};

  for (int dk = 0; dk < DN; dk += 32) {
    {
      int row = tid >> 2;
      int seg = (tid & 3) * 8;
      ushort8 a = *(const ushort8*)(yf + ((size_t)b * LL + l0 + row) * DN + dk + seg);
      ushort8 c = *(const ushort8*)(yr + ((size_t)b * LL + l0 + row) * DN + dk + seg);
      ushort8 yv;
#pragma unroll
      for (int k = 0; k < 8; k++) yv[k] = f2bf(0.5f * (bf2f(a[k]) + bf2f(c[k])));
      *(ushort8*)&yt[row][seg] = yv;
      const float* wp = ow + (size_t)(m0 + row) * DN + dk + seg;
      float4 w0 = *(const float4*)wp, w1 = *(const float4*)(wp + 4);
      ushort8 wv;
      wv[0] = f2bf(w0.x); wv[1] = f2bf(w0.y); wv[2] = f2bf(w0.z); wv[3] = f2bf(w0.w);
      wv[4] = f2bf(w1.x); wv[5] = f2bf(w1.y); wv[6] = f2bf(w1.z); wv[7] = f2bf(w1.w);
      *(ushort8*)&wo[row][seg] = wv;
    }
    __syncthreads();
    bf16x8 a0 = *(bf16x8*)&yt[wm * 32 + rlo][krow];
    bf16x8 a1 = *(bf16x8*)&yt[wm * 32 + 16 + rlo][krow];
    bf16x8 b0 = *(bf16x8*)&wo[wn * 32 + rlo][krow];
    bf16x8 b1 = *(bf16x8*)&wo[wn * 32 + 16 + rlo][krow];
    acc[0][0] = __builtin_amdgcn_mfma_f32_16x16x32_bf16(a0, b0, acc[0][0], 0, 0, 0);
    acc[0][1] = __builtin_amdgcn_mfma_f32_16x16x32_bf16(a0, b1, acc[0][1], 0, 0, 0);
    acc[1][0] = __builtin_amdgcn_mfma_f32_16x16x32_bf16(a1, b0, acc[1][0], 0, 0, 0);
    acc[1][1] = __builtin_amdgcn_mfma_f32_16x16x32_bf16(a1, b1, acc[1][1], 0, 0, 0);
    __syncthreads();
  }
#pragma unroll
  for (int mt = 0; mt < 2; mt++)
#pragma unroll
    for (int nt = 0; nt < 2; nt++)
#pragma unroll
      for (int r = 0; r < 4; r++) {
        int l = l0 + wm * 32 + mt * 16 + (lane >> 4) * 4 + r;
        int m = m0 + wn * 32 + nt * 16 + rlo;
        outp[((size_t)b * LL + l) * DM + m] = acc[mt][nt][r];
      }
}

// ---------------------------------------------------------------------------
extern "C" void kernel_launch(void* const* d_in, const int* in_sizes, int n_in,
                              void* d_out, int out_size, void* d_ws, size_t ws_size,
                              hipStream_t stream) {
  (void)in_sizes; (void)n_in; (void)out_size; (void)ws_size;
  const float* A_log = (const float*)d_in[2];
  const float* Ab_log = (const float*)d_in[3];

  const size_t SZ = (size_t)BB * LL * DN;      // 4,194,304 elements
  const size_t NSZ = (size_t)BB * LL * NS;     // 131,072
  float* ws = (float*)d_ws;
  float* dl_f = ws;                            // SZ fp32
  float* dl_r = dl_f + SZ;                     // SZ fp32
  float* B_f = dl_r + SZ;                      // NSZ
  float* C_f = B_f + NSZ;
  float* B_r = C_f + NSZ;
  float* C_r = B_r + NSZ;
  float* sumdl = C_r + NSZ;                    // NC2*G2 = 524,288
  float* dtv_g = sumdl + (size_t)NC2 * 2 * BB * DN;  // 2*BB*NLT*256 = 262,144
  unsigned short* xwbf_f = (unsigned short*)(dtv_g + (size_t)2 * BB * NLT * 256);
  unsigned short* xwbf_r = xwbf_f + 48 * 512;
  unsigned short* z_t = xwbf_r + 48 * 512;     // SZ bf16
  unsigned short* u_f = z_t + SZ;              // SZ bf16 (u -> y in place)
  unsigned short* u_r = u_f + SZ;              // SZ bf16
  unsigned short* xz = u_r + SZ;               // SZ bf16 (dead after conv)
  unsigned short* hend = xz;  // ALIAS: NC2*G2*NS bf16 (xz region + tail)

  for (int s = 0; s < 2; s++) {
    const int p = 4 + s * 14;
    const float* hin = (const float*)d_in[s];
    const float* in_w = (const float*)d_in[p + 0];
    const float* conv_w = (const float*)d_in[p + 1];
    const float* conv_b = (const float*)d_in[p + 2];
    const float* x_w = (const float*)d_in[p + 3];
    const float* dt_w = (const float*)d_in[p + 4];
    const float* dt_b = (const float*)d_in[p + 5];
    const float* Dp = (const float*)d_in[p + 6];
    const float* conv_w_b = (const float*)d_in[p + 7];
    const float* conv_b_b = (const float*)d_in[p + 8];
    const float* x_w_b = (const float*)d_in[p + 9];
    const float* dt_w_b = (const float*)d_in[p + 10];
    const float* dt_b_b = (const float*)d_in[p + 11];
    const float* Dp_b = (const float*)d_in[p + 12];
    const float* out_w = (const float*)d_in[p + 13];
    float* outp = (float*)d_out + (size_t)s * BB * LL * DM;

    hipLaunchKernelGGL(in_proj_mfma, dim3(LL / 64, EE / 128, BB), dim3(256), 0,
                       stream, hin, in_w, xz, z_t);
    hipLaunchKernelGGL(xw_prep_kernel, dim3(96), dim3(256), 0, stream,
                       x_w, x_w_b, xwbf_f, xwbf_r);
    hipLaunchKernelGGL(conv_kernel, dim3((LL / 32) * 4, BB, 2), dim3(256), 0,
                       stream, xz, conv_w, conv_b, conv_w_b, conv_b_b, u_f, u_r);
    hipLaunchKernelGGL(xdbl_kernel, dim3(NLT, BB, 2), dim3(256), 0, stream,
                       u_f, u_r, xwbf_f, xwbf_r, dtv_g, B_f, C_f, B_r, C_r);
    hipLaunchKernelGGL(delta_kernel, dim3(NLT, BB, 2), dim3(256), 0, stream,
                       dtv_g, dt_w, dt_b, dt_w_b, dt_b_b, dl_f, dl_r);
    hipLaunchKernelGGL(HIP_KERNEL_NAME(scan_kernel<1>), dim3(NC2 * 16), dim3(256), 0,
                       stream, u_f, u_r, dl_f, dl_r, z_t, B_f, C_f, B_r, C_r, A_log,
                       Ab_log, Dp, Dp_b, hend, sumdl);
    hipLaunchKernelGGL(scan_combine_kernel, dim3(2 * BB * DN / 16), dim3(256),
                       0, stream, A_log, Ab_log, hend, sumdl);
    hipLaunchKernelGGL(HIP_KERNEL_NAME(scan_kernel<3>), dim3(NC2 * 16), dim3(256), 0,
                       stream, u_f, u_r, dl_f, dl_r, z_t, B_f, C_f, B_r, C_r, A_log,
                       Ab_log, Dp, Dp_b, hend, sumdl);
    hipLaunchKernelGGL(out_proj_mfma, dim3(LL / 64, DM / 64, BB), dim3(256), 0,
                       stream, u_f, u_r, out_w, outp);
  }
}

// Round 19
// 286.760 us; speedup vs baseline: 1.2780x; 1.2589x over previous
//
#include <hip/hip_runtime.h>
#include <hip/hip_bf16.h>
#include <cstddef>

#define BB 4
#define LL 2048
#define DM 256
#define DN 512
#define EE 1024
#define NS 16
#define RK 16
#define NC2 128         // scan chunks
#define CL2 (LL / NC2)  // chunk length = 16
#define NLT (LL / 16)   // l-tiles for xdbl/delta = 128
#define G2C (2 * BB * DN)                       // 4096
#define SZC ((size_t)BB * LL * DN)              // 4,194,304
#define NSZC ((size_t)BB * LL * NS)             // 131,072
#define HSZC ((size_t)NC2 * G2C * NS)           // 8,388,608 (bf16 elems)
#define XWSL (48 * 512)                         // 24,576

typedef __attribute__((ext_vector_type(8))) short bf16x8;
typedef __attribute__((ext_vector_type(8))) unsigned short ushort8;
typedef __attribute__((ext_vector_type(4))) unsigned short ushort4v;
typedef __attribute__((ext_vector_type(2))) unsigned short ushort2v;
typedef __attribute__((ext_vector_type(4))) float f32x4;

__device__ __forceinline__ float fsilu(float x) { return x / (1.0f + __expf(-x)); }
__device__ __forceinline__ float fsoftplus(float x) { return x > 20.0f ? x : log1pf(__expf(x)); }
__device__ __forceinline__ unsigned short f2bf(float x) {  // RNE float->bf16
  union { float f; unsigned int u; } v; v.f = x;
  unsigned int r = v.u + 0x7fffu + ((v.u >> 16) & 1u);
  return (unsigned short)(r >> 16);
}
__device__ __forceinline__ float bf2f(unsigned short x) {
  union { unsigned int u; float f; } v; v.u = ((unsigned int)x) << 16;
  return v.f;
}

// ---------------------------------------------------------------------------
// in_proj (both streams). Tile 128e x 64l, grid (32, 8, BB*2).
// x-blocks: C[e][l] -> xz BF16 [str][b][e][l]. z-blocks: silu -> z_t [str][b][l][d].
// ---------------------------------------------------------------------------
__global__ __launch_bounds__(256) void in_proj_mfma(
    const float* __restrict__ h_a, const float* __restrict__ h_v,
    const float* __restrict__ w_a, const float* __restrict__ w_v,
    unsigned short* __restrict__ xz, unsigned short* __restrict__ z_t) {
  __shared__ unsigned short ht[64][40];   // [l][k] bf16
  __shared__ unsigned short wt[128][40];  // [e][k]
  const int bz = blockIdx.z;
  const int b = bz & 3;
  const int str = bz >> 2;
  const float* h = str ? h_v : h_a;
  const float* w = str ? w_v : w_a;
  unsigned short* xzs = xz + (size_t)str * SZC;
  unsigned short* zts = z_t + (size_t)str * SZC;
  const int e0 = blockIdx.y * 128;
  const int l0 = blockIdx.x * 64;
  const int tid = threadIdx.x;
  const int lane = tid & 63;
  const int wv = tid >> 6;
  const bool zblk = (e0 >= DN);
  const int krow = (lane >> 4) * 8;
  const int rlo = lane & 15;
  const int rbase = (lane >> 4) * 4;

  f32x4 acc[8];
#pragma unroll
  for (int i = 0; i < 8; i++) acc[i] = (f32x4){0.f, 0.f, 0.f, 0.f};

  for (int dk = 0; dk < DM; dk += 32) {
    {
      int row = tid >> 2;
      int seg = (tid & 3) * 8;
      const float* hp = h + ((size_t)b * LL + l0 + row) * DM + dk + seg;
      float4 ha = *(const float4*)hp, hb = *(const float4*)(hp + 4);
      ushort8 hv;
      hv[0] = f2bf(ha.x); hv[1] = f2bf(ha.y); hv[2] = f2bf(ha.z); hv[3] = f2bf(ha.w);
      hv[4] = f2bf(hb.x); hv[5] = f2bf(hb.y); hv[6] = f2bf(hb.z); hv[7] = f2bf(hb.w);
      *(ushort8*)&ht[row][seg] = hv;
    }
#pragma unroll
    for (int it = 0; it < 2; it++) {
      int idx = it * 256 + tid;
      int row = idx >> 2;
      int seg = (idx & 3) * 8;
      const float* wp = w + (size_t)(e0 + row) * DM + dk + seg;
      float4 wa = *(const float4*)wp, wb = *(const float4*)(wp + 4);
      ushort8 wv8;
      wv8[0] = f2bf(wa.x); wv8[1] = f2bf(wa.y); wv8[2] = f2bf(wa.z); wv8[3] = f2bf(wa.w);
      wv8[4] = f2bf(wb.x); wv8[5] = f2bf(wb.y); wv8[6] = f2bf(wb.z); wv8[7] = f2bf(wb.w);
      *(ushort8*)&wt[row][seg] = wv8;
    }
    __syncthreads();
    if (!zblk) {
      bf16x8 af0 = *(bf16x8*)&wt[wv * 32 + 0 * 16 + rlo][krow];
      bf16x8 af1 = *(bf16x8*)&wt[wv * 32 + 1 * 16 + rlo][krow];
      bf16x8 bf0 = *(bf16x8*)&ht[0 * 16 + rlo][krow];
      bf16x8 bf1 = *(bf16x8*)&ht[1 * 16 + rlo][krow];
      bf16x8 bf2 = *(bf16x8*)&ht[2 * 16 + rlo][krow];
      bf16x8 bf3 = *(bf16x8*)&ht[3 * 16 + rlo][krow];
      acc[0] = __builtin_amdgcn_mfma_f32_16x16x32_bf16(af0, bf0, acc[0], 0, 0, 0);
      acc[1] = __builtin_amdgcn_mfma_f32_16x16x32_bf16(af0, bf1, acc[1], 0, 0, 0);
      acc[2] = __builtin_amdgcn_mfma_f32_16x16x32_bf16(af0, bf2, acc[2], 0, 0, 0);
      acc[3] = __builtin_amdgcn_mfma_f32_16x16x32_bf16(af0, bf3, acc[3], 0, 0, 0);
      acc[4] = __builtin_amdgcn_mfma_f32_16x16x32_bf16(af1, bf0, acc[4], 0, 0, 0);
      acc[5] = __builtin_amdgcn_mfma_f32_16x16x32_bf16(af1, bf1, acc[5], 0, 0, 0);
      acc[6] = __builtin_amdgcn_mfma_f32_16x16x32_bf16(af1, bf2, acc[6], 0, 0, 0);
      acc[7] = __builtin_amdgcn_mfma_f32_16x16x32_bf16(af1, bf3, acc[7], 0, 0, 0);
    } else {
      bf16x8 af0 = *(bf16x8*)&ht[0 * 16 + rlo][krow];
      bf16x8 af1 = *(bf16x8*)&ht[1 * 16 + rlo][krow];
      bf16x8 af2 = *(bf16x8*)&ht[2 * 16 + rlo][krow];
      bf16x8 af3 = *(bf16x8*)&ht[3 * 16 + rlo][krow];
      bf16x8 bf0 = *(bf16x8*)&wt[wv * 32 + 0 * 16 + rlo][krow];
      bf16x8 bf1 = *(bf16x8*)&wt[wv * 32 + 1 * 16 + rlo][krow];
      acc[0] = __builtin_amdgcn_mfma_f32_16x16x32_bf16(af0, bf0, acc[0], 0, 0, 0);
      acc[1] = __builtin_amdgcn_mfma_f32_16x16x32_bf16(af0, bf1, acc[1], 0, 0, 0);
      acc[2] = __builtin_amdgcn_mfma_f32_16x16x32_bf16(af1, bf0, acc[2], 0, 0, 0);
      acc[3] = __builtin_amdgcn_mfma_f32_16x16x32_bf16(af1, bf1, acc[3], 0, 0, 0);
      acc[4] = __builtin_amdgcn_mfma_f32_16x16x32_bf16(af2, bf0, acc[4], 0, 0, 0);
      acc[5] = __builtin_amdgcn_mfma_f32_16x16x32_bf16(af2, bf1, acc[5], 0, 0, 0);
      acc[6] = __builtin_amdgcn_mfma_f32_16x16x32_bf16(af3, bf0, acc[6], 0, 0, 0);
      acc[7] = __builtin_amdgcn_mfma_f32_16x16x32_bf16(af3, bf1, acc[7], 0, 0, 0);
    }
    __syncthreads();
  }
  if (!zblk) {
#pragma unroll
    for (int m = 0; m < 2; m++)
#pragma unroll
      for (int n = 0; n < 4; n++)
#pragma unroll
        for (int r = 0; r < 4; r++) {
          int e = e0 + wv * 32 + m * 16 + rbase + r;
          int l = l0 + n * 16 + rlo;
          xzs[((size_t)b * DN + e) * LL + l] = f2bf(acc[m * 4 + n][r]);
        }
  } else {
#pragma unroll
    for (int m = 0; m < 4; m++)
#pragma unroll
      for (int n = 0; n < 2; n++)
#pragma unroll
        for (int r = 0; r < 4; r++) {
          int l = l0 + m * 16 + rbase + r;
          int d = (e0 - DN) + wv * 32 + n * 16 + rlo;
          zts[((size_t)b * LL + l) * DN + d] = f2bf(fsilu(acc[m * 2 + n][r]));
        }
  }
}

// ---------------------------------------------------------------------------
// conv (both streams): grid ((LL/32)*4, BB, 4): z = str*2 + rev.
// ---------------------------------------------------------------------------
__global__ __launch_bounds__(256) void conv_kernel(
    const unsigned short* __restrict__ xz,
    const float* __restrict__ cw_af, const float* __restrict__ cb_af,
    const float* __restrict__ cw_ar, const float* __restrict__ cb_ar,
    const float* __restrict__ cw_vf, const float* __restrict__ cb_vf,
    const float* __restrict__ cw_vr, const float* __restrict__ cb_vr,
    unsigned short* __restrict__ u) {
  __shared__ float xt[128][33];
  const int slab = blockIdx.z;      // str*2 + rev
  const int rev = slab & 1;
  const int str = slab >> 1;
  const int b = blockIdx.y;
  const int dc0 = (blockIdx.x & 3) * 128;
  const int l0 = (blockIdx.x >> 2) * 32;
  const int tid = threadIdx.x;
  const int lc = tid & 31;
  const int dg = tid >> 5;
  const int l = l0 + lc;
  const float* conv_w = str ? (rev ? cw_vr : cw_vf) : (rev ? cw_ar : cw_af);
  const float* conv_b = str ? (rev ? cb_vr : cb_vf) : (rev ? cb_ar : cb_af);
  const unsigned short* xzs = xz + (size_t)str * SZC;
  unsigned short* u_out = u + (size_t)slab * SZC;

#pragma unroll
  for (int i = 0; i < 16; i++) {
    int dloc = dg * 16 + i;
    int dd = dc0 + dloc;
    const unsigned short* base = xzs + ((size_t)b * DN + dd) * LL;
    float4 cw4 = *(const float4*)(conv_w + dd * 4);
    float a0 = conv_b[dd];
    if (rev) {
      a0 = fmaf(cw4.w, bf2f(base[l]), a0);
      if (l + 1 < LL) a0 = fmaf(cw4.z, bf2f(base[l + 1]), a0);
      if (l + 2 < LL) a0 = fmaf(cw4.y, bf2f(base[l + 2]), a0);
      if (l + 3 < LL) a0 = fmaf(cw4.x, bf2f(base[l + 3]), a0);
    } else {
      a0 = fmaf(cw4.w, bf2f(base[l]), a0);
      if (l - 1 >= 0) a0 = fmaf(cw4.z, bf2f(base[l - 1]), a0);
      if (l - 2 >= 0) a0 = fmaf(cw4.y, bf2f(base[l - 2]), a0);
      if (l - 3 >= 0) a0 = fmaf(cw4.x, bf2f(base[l - 3]), a0);
    }
    xt[dloc][lc] = fsilu(a0);
  }
  __syncthreads();
#pragma unroll
  for (int j = 0; j < 8; j++) {
    int idx = j * 256 + tid;
    int d2 = idx & 63;
    int l2 = idx >> 6;
    ushort2v v;
    v[0] = f2bf(xt[2 * d2][l2]);
    v[1] = f2bf(xt[2 * d2 + 1][l2]);
    *(ushort2v*)&u_out[((size_t)b * LL + l0 + l2) * DN + dc0 + 2 * d2] = v;
  }
}

// ---------------------------------------------------------------------------
// prep: convert all 4 x_w matrices to bf16 slabs.
// ---------------------------------------------------------------------------
__global__ __launch_bounds__(256) void xw_prep_kernel(
    const float* __restrict__ a_f, const float* __restrict__ a_r,
    const float* __restrict__ v_f, const float* __restrict__ v_r,
    unsigned short* __restrict__ o) {
  int i = blockIdx.x * 256 + threadIdx.x;
  if (i < XWSL) {
    o[i] = f2bf(a_f[i]);
    o[i + XWSL] = f2bf(a_r[i]);
    o[i + 2 * XWSL] = f2bf(v_f[i]);
    o[i + 3 * XWSL] = f2bf(v_r[i]);
  }
}

// ---------------------------------------------------------------------------
// xdbl (both streams): grid (NLT, BB, 4): z = str*2 + rev.
// ---------------------------------------------------------------------------
__global__ __launch_bounds__(256) void xdbl_kernel(
    const unsigned short* __restrict__ u, const unsigned short* __restrict__ xwbf,
    float* __restrict__ dtv_g, float* __restrict__ Bb, float* __restrict__ Cb) {
  __shared__ __align__(16) unsigned short ub[4][16][136];
  __shared__ float red[4][48][17];
  const int slab = blockIdx.z;
  const int b = blockIdx.y;
  const int lt = blockIdx.x;
  const int l0 = lt * 16;
  const int tid = threadIdx.x;
  const int lane = tid & 63;
  const int w = tid >> 6;
  const int rlo = lane & 15;
  const int hi4 = lane >> 4;
  const int kseg = hi4 * 8;

  const unsigned short* up = u + (size_t)slab * SZC + ((size_t)b * LL + l0) * DN;
  const unsigned short* xwb = xwbf + (size_t)slab * XWSL;
  float* B_out = Bb + (size_t)slab * NSZC;
  float* C_out = Cb + (size_t)slab * NSZC;

#pragma unroll
  for (int j = 0; j < 4; j++) {
    int idx = j * 256 + tid;
    int l2 = idx >> 6;
    int c8 = idx & 63;
    ushort8 v = *(const ushort8*)(up + (size_t)l2 * DN + c8 * 8);
    *(ushort8*)&ub[c8 >> 4][l2][(c8 & 15) * 8] = v;
  }
  __syncthreads();

  f32x4 am0 = (f32x4){0.f, 0.f, 0.f, 0.f};
  f32x4 am1 = (f32x4){0.f, 0.f, 0.f, 0.f};
  f32x4 am2 = (f32x4){0.f, 0.f, 0.f, 0.f};
#pragma unroll
  for (int ks = 0; ks < 4; ks++) {
    bf16x8 bfrag = *(bf16x8*)&ub[w][rlo][ks * 32 + kseg];
    const unsigned short* xp = xwb + (size_t)(w * 128 + ks * 32 + kseg);
    bf16x8 a0 = *(const bf16x8*)(xp + (size_t)(0 + rlo) * 512);
    bf16x8 a1 = *(const bf16x8*)(xp + (size_t)(16 + rlo) * 512);
    bf16x8 a2 = *(const bf16x8*)(xp + (size_t)(32 + rlo) * 512);
    am0 = __builtin_amdgcn_mfma_f32_16x16x32_bf16(a0, bfrag, am0, 0, 0, 0);
    am1 = __builtin_amdgcn_mfma_f32_16x16x32_bf16(a1, bfrag, am1, 0, 0, 0);
    am2 = __builtin_amdgcn_mfma_f32_16x16x32_bf16(a2, bfrag, am2, 0, 0, 0);
  }
  {
    const int rbase = hi4 * 4;
#pragma unroll
    for (int r = 0; r < 4; r++) red[w][0 + rbase + r][rlo] = am0[r];
#pragma unroll
    for (int r = 0; r < 4; r++) red[w][16 + rbase + r][rlo] = am1[r];
#pragma unroll
    for (int r = 0; r < 4; r++) red[w][32 + rbase + r][rlo] = am2[r];
  }
  __syncthreads();
  float* dtvp = dtv_g + (((size_t)slab * BB + b) * NLT + lt) * 256;
#pragma unroll
  for (int i = 0; i < 3; i++) {
    int o = i * 256 + tid;
    int row = o >> 4, col = o & 15;
    float s = (red[0][row][col] + red[1][row][col]) +
              (red[2][row][col] + red[3][row][col]);
    if (row < 16)
      dtvp[(size_t)row * 16 + col] = s;
    else if (row < 32)
      B_out[((size_t)b * LL + l0 + col) * NS + (row - 16)] = s;
    else
      C_out[((size_t)b * LL + l0 + col) * NS + (row - 32)] = s;
  }
}

// ---------------------------------------------------------------------------
// delta (both streams): grid (NLT, BB, 4).
// ---------------------------------------------------------------------------
__global__ __launch_bounds__(256) void delta_kernel(
    const float* __restrict__ dtv_g,
    const float* __restrict__ dtw_af, const float* __restrict__ dtb_af,
    const float* __restrict__ dtw_ar, const float* __restrict__ dtb_ar,
    const float* __restrict__ dtw_vf, const float* __restrict__ dtb_vf,
    const float* __restrict__ dtw_vr, const float* __restrict__ dtb_vr,
    float* __restrict__ dl) {
  __shared__ float dtv[16][17];
  const int slab = blockIdx.z;
  const int rev = slab & 1;
  const int str = slab >> 1;
  const int b = blockIdx.y;
  const int lt = blockIdx.x;
  const int l0 = lt * 16;
  const int tid = threadIdx.x;
  const float* dt_w = str ? (rev ? dtw_vr : dtw_vf) : (rev ? dtw_ar : dtw_af);
  const float* dt_b = str ? (rev ? dtb_vr : dtb_vf) : (rev ? dtb_ar : dtb_af);
  float* dl_out = dl + (size_t)slab * SZC;

  {
    const float* dtvp = dtv_g + (((size_t)slab * BB + b) * NLT + lt) * 256;
    dtv[tid >> 4][tid & 15] = dtvp[tid];
  }
  __syncthreads();

#pragma unroll
  for (int half = 0; half < 2; half++) {
    int dd = half * 256 + tid;
    const float4* wr = (const float4*)(dt_w + (size_t)dd * RK);
    float4 w0 = wr[0], w1 = wr[1], w2 = wr[2], w3 = wr[3];
    float bias = dt_b[dd];
#pragma unroll
    for (int l2 = 0; l2 < 16; l2++) {
      float a0 = bias;
      a0 = fmaf(w0.x, dtv[0][l2], a0);  a0 = fmaf(w0.y, dtv[1][l2], a0);
      a0 = fmaf(w0.z, dtv[2][l2], a0);  a0 = fmaf(w0.w, dtv[3][l2], a0);
      a0 = fmaf(w1.x, dtv[4][l2], a0);  a0 = fmaf(w1.y, dtv[5][l2], a0);
      a0 = fmaf(w1.z, dtv[6][l2], a0);  a0 = fmaf(w1.w, dtv[7][l2], a0);
      a0 = fmaf(w2.x, dtv[8][l2], a0);  a0 = fmaf(w2.y, dtv[9][l2], a0);
      a0 = fmaf(w2.z, dtv[10][l2], a0); a0 = fmaf(w2.w, dtv[11][l2], a0);
      a0 = fmaf(w3.x, dtv[12][l2], a0); a0 = fmaf(w3.y, dtv[13][l2], a0);
      a0 = fmaf(w3.z, dtv[14][l2], a0); a0 = fmaf(w3.w, dtv[15][l2], a0);
      dl_out[((size_t)b * LL + l0 + l2) * DN + dd] = fsoftplus(a0);
    }
  }
}

// ---------------------------------------------------------------------------
// Scan (both streams, LDS-staged): grid (NC2*16, 2).
// ---------------------------------------------------------------------------
#define HSTEP(n, Bcomp, Ccomp)                      \
  {                                                 \
    float e_ = __expf(dc * Av[n]);                  \
    h[n] = fmaf(e_, h[n], dlu * (Bcomp));           \
    if (PHASE == 3) acc = fmaf(h[n], (Ccomp), acc); \
  }

template <int PHASE>
__global__ __launch_bounds__(256) void scan_kernel(
    unsigned short* __restrict__ u, const float* __restrict__ dl,
    const unsigned short* __restrict__ z_t, const float* __restrict__ Bb,
    const float* __restrict__ Cb, const float* __restrict__ A_log,
    const float* __restrict__ Ab_log,
    const float* __restrict__ D_af, const float* __restrict__ D_ar,
    const float* __restrict__ D_vf, const float* __restrict__ D_vr,
    unsigned short* __restrict__ hend, float* __restrict__ sumdl) {
  __shared__ unsigned short us[CL2][256];
  __shared__ unsigned short zs[CL2][256];
  __shared__ float dls[CL2][256];
  __shared__ float Bs[CL2][16];
  __shared__ float Cs[CL2][16];
  const int tid = threadIdx.x;
  const int str = blockIdx.y;
  const int ch0 = (blockIdx.x & 15) * 256;
  const int chunk = blockIdx.x >> 4;
  const int ch = ch0 + tid;
  const bool rev = ch0 >= BB * DN;
  const int slab = str * 2 + (rev ? 1 : 0);
  const int cid0 = rev ? ch0 - BB * DN : ch0;
  const int b = cid0 >> 9;
  const int d0 = cid0 & (DN - 1);
  const int d = d0 + tid;

  const float* Arow = (rev ? Ab_log : A_log) + d * NS;
  float Av[NS];
#pragma unroll
  for (int n = 0; n < NS; n++) Av[n] = -__expf(Arow[n]);
  const float* Dsel = str ? (rev ? D_vr : D_vf) : (rev ? D_ar : D_af);
  const float Dd = Dsel[d];

  const int tlo = rev ? (LL - CL2 * (chunk + 1)) : (CL2 * chunk);
  unsigned short* uyb = u + (size_t)slab * SZC + ((size_t)b * LL + tlo) * DN + d0;
  const float* dlb = dl + (size_t)slab * SZC + ((size_t)b * LL + tlo) * DN + d0;
  const unsigned short* zb = z_t + (size_t)str * SZC + ((size_t)b * LL + tlo) * DN + d0;
  const float* Bp = Bb + (size_t)slab * NSZC + ((size_t)b * LL + tlo) * NS;
  const float* Cp = Cb + (size_t)slab * NSZC + ((size_t)b * LL + tlo) * NS;
  unsigned short* hendp = hend + (size_t)str * HSZC;
  float* sumdlp = sumdl + (size_t)str * NC2 * G2C;

  // ---- stage the whole chunk tile ----
  {
    const int lane = tid & 63;
    const int w = tid >> 6;
#pragma unroll
    for (int j4 = 0; j4 < 4; j4++) {
      int row = w * 4 + j4;
      ushort4v uu = *(const ushort4v*)(uyb + (size_t)row * DN + lane * 4);
      *(ushort4v*)&us[row][lane * 4] = uu;
      float4 dd4 = *(const float4*)(dlb + (size_t)row * DN + lane * 4);
      *(float4*)&dls[row][lane * 4] = dd4;
      if (PHASE == 3) {
        ushort4v zz = *(const ushort4v*)(zb + (size_t)row * DN + lane * 4);
        *(ushort4v*)&zs[row][lane * 4] = zz;
      }
    }
    Bs[tid >> 4][tid & 15] = Bp[(size_t)(tid >> 4) * NS + (tid & 15)];
    if (PHASE == 3) Cs[tid >> 4][tid & 15] = Cp[(size_t)(tid >> 4) * NS + (tid & 15)];
  }

  float h[NS];
  if (PHASE == 3) {
    const unsigned short* hp = hendp + ((size_t)chunk * G2C + ch) * NS;
#pragma unroll
    for (int n = 0; n < NS; n++) h[n] = bf2f(hp[n]);
  } else {
#pragma unroll
    for (int n = 0; n < NS; n++) h[n] = 0.f;
  }
  __syncthreads();

  float sdl = 0.f;
#pragma unroll
  for (int jj = 0; jj < CL2; jj++) {
    const int j = rev ? (CL2 - 1 - jj) : jj;
    const float uc = bf2f(us[j][tid]);
    const float dc = dls[j][tid];
    const float4 Bq0 = *(const float4*)&Bs[j][0];
    const float4 Bq1 = *(const float4*)&Bs[j][4];
    const float4 Bq2 = *(const float4*)&Bs[j][8];
    const float4 Bq3 = *(const float4*)&Bs[j][12];
    float4 Cq0 = {0, 0, 0, 0}, Cq1 = {0, 0, 0, 0}, Cq2 = {0, 0, 0, 0},
           Cq3 = {0, 0, 0, 0};
    if (PHASE == 3) {
      Cq0 = *(const float4*)&Cs[j][0];
      Cq1 = *(const float4*)&Cs[j][4];
      Cq2 = *(const float4*)&Cs[j][8];
      Cq3 = *(const float4*)&Cs[j][12];
    }
    const float dlu = dc * uc;
    float acc = 0.f;
    HSTEP(0, Bq0.x, Cq0.x)  HSTEP(1, Bq0.y, Cq0.y)
    HSTEP(2, Bq0.z, Cq0.z)  HSTEP(3, Bq0.w, Cq0.w)
    HSTEP(4, Bq1.x, Cq1.x)  HSTEP(5, Bq1.y, Cq1.y)
    HSTEP(6, Bq1.z, Cq1.z)  HSTEP(7, Bq1.w, Cq1.w)
    HSTEP(8, Bq2.x, Cq2.x)  HSTEP(9, Bq2.y, Cq2.y)
    HSTEP(10, Bq2.z, Cq2.z) HSTEP(11, Bq2.w, Cq2.w)
    HSTEP(12, Bq3.x, Cq3.x) HSTEP(13, Bq3.y, Cq3.y)
    HSTEP(14, Bq3.z, Cq3.z) HSTEP(15, Bq3.w, Cq3.w)
    if (PHASE == 1) sdl += dc;
    if (PHASE == 3) {
      const float zc = bf2f(zs[j][tid]);
      float y = fmaf(uc, Dd, acc) * zc;
      uyb[(size_t)j * DN + tid] = f2bf(y);
    }
  }
  if (PHASE == 1) {
    unsigned short* hp = hendp + ((size_t)chunk * G2C + ch) * NS;
#pragma unroll
    for (int n = 0; n < NS; n++) hp[n] = f2bf(h[n]);
    sumdlp[(size_t)chunk * G2C + ch] = sdl;
  }
}
#undef HSTEP

// ---------------------------------------------------------------------------
// Phase 2 (both streams): grid (G2C/16, 2).
// ---------------------------------------------------------------------------
__global__ __launch_bounds__(256) void scan_combine_kernel(
    const float* __restrict__ A_log, const float* __restrict__ Ab_log,
    unsigned short* __restrict__ hend, const float* __restrict__ sumdl) {
  __shared__ float tile[8][256];
  __shared__ float sd[8][16];
  const int tid = threadIdx.x;
  const int str = blockIdx.y;
  const int ch0 = blockIdx.x * 16;
  const int chl = tid >> 4;
  const int n = tid & 15;
  const int ch = ch0 + chl;
  const bool rev = ch >= BB * DN;
  const int d = ch & (DN - 1);
  const float Av = -__expf((rev ? Ab_log : A_log)[d * NS + n]);
  unsigned short* hendp = hend + (size_t)str * HSZC;
  const float* sumdlp = sumdl + (size_t)str * NC2 * G2C;
  float H = 0.f;
  for (int cb = 0; cb < NC2 / 8; cb++) {
#pragma unroll
    for (int j = 0; j < 8; j++)
      tile[j][tid] = bf2f(hendp[((size_t)(cb * 8 + j) * G2C + ch0) * NS + tid]);
    if (tid < 128) {
      int j = tid >> 4, k = tid & 15;
      sd[j][k] = sumdlp[(size_t)(cb * 8 + j) * G2C + ch0 + k];
    }
    __syncthreads();
#pragma unroll
    for (int j = 0; j < 8; j++) {
      float tmp = tile[j][tid];
      tile[j][tid] = H;
      H = fmaf(__expf(Av * sd[j][chl]), H, tmp);
    }
    __syncthreads();
#pragma unroll
    for (int j = 0; j < 8; j++)
      hendp[((size_t)(cb * 8 + j) * G2C + ch0) * NS + tid] = f2bf(tile[j][tid]);
    __syncthreads();
  }
}

// ---------------------------------------------------------------------------
// out_proj (both streams): grid (32, 4, BB*2).
// ---------------------------------------------------------------------------
__global__ __launch_bounds__(256) void out_proj_mfma(
    const unsigned short* __restrict__ u,
    const float* __restrict__ ow_a, const float* __restrict__ ow_v,
    float* __restrict__ outp) {
  __shared__ unsigned short yt[64][40];
  __shared__ unsigned short wo[64][40];
  const int bz = blockIdx.z;
  const int b = bz & 3;
  const int str = bz >> 2;
  const float* ow = str ? ow_v : ow_a;
  const unsigned short* yf = u + (size_t)(str * 2) * SZC;
  const unsigned short* yr = u + (size_t)(str * 2 + 1) * SZC;
  float* outs = outp + (size_t)str * BB * LL * DM;
  const int m0 = blockIdx.y * 64;
  const int l0 = blockIdx.x * 64;
  const int tid = threadIdx.x;
  const int lane = tid & 63;
  const int wid = tid >> 6;
  const int wm = wid >> 1, wn = wid & 1;
  const int krow = (lane >> 4) * 8;
  const int rlo = lane & 15;

  f32x4 acc[2][2];
#pragma unroll
  for (int i = 0; i < 2; i++)
#pragma unroll
    for (int j = 0; j < 2; j++) acc[i][j] = (f32x4){0.f, 0.f, 0.f, 0.f};

  for (int dk = 0; dk < DN; dk += 32) {
    {
      int row = tid >> 2;
      int seg = (tid & 3) * 8;
      ushort8 a = *(const ushort8*)(yf + ((size_t)b * LL + l0 + row) * DN + dk + seg);
      ushort8 c = *(const ushort8*)(yr + ((size_t)b * LL + l0 + row) * DN + dk + seg);
      ushort8 yv;
#pragma unroll
      for (int k = 0; k < 8; k++) yv[k] = f2bf(0.5f * (bf2f(a[k]) + bf2f(c[k])));
      *(ushort8*)&yt[row][seg] = yv;
      const float* wp = ow + (size_t)(m0 + row) * DN + dk + seg;
      float4 w0 = *(const float4*)wp, w1 = *(const float4*)(wp + 4);
      ushort8 wv;
      wv[0] = f2bf(w0.x); wv[1] = f2bf(w0.y); wv[2] = f2bf(w0.z); wv[3] = f2bf(w0.w);
      wv[4] = f2bf(w1.x); wv[5] = f2bf(w1.y); wv[6] = f2bf(w1.z); wv[7] = f2bf(w1.w);
      *(ushort8*)&wo[row][seg] = wv;
    }
    __syncthreads();
    bf16x8 a0 = *(bf16x8*)&yt[wm * 32 + rlo][krow];
    bf16x8 a1 = *(bf16x8*)&yt[wm * 32 + 16 + rlo][krow];
    bf16x8 b0 = *(bf16x8*)&wo[wn * 32 + rlo][krow];
    bf16x8 b1 = *(bf16x8*)&wo[wn * 32 + 16 + rlo][krow];
    acc[0][0] = __builtin_amdgcn_mfma_f32_16x16x32_bf16(a0, b0, acc[0][0], 0, 0, 0);
    acc[0][1] = __builtin_amdgcn_mfma_f32_16x16x32_bf16(a0, b1, acc[0][1], 0, 0, 0);
    acc[1][0] = __builtin_amdgcn_mfma_f32_16x16x32_bf16(a1, b0, acc[1][0], 0, 0, 0);
    acc[1][1] = __builtin_amdgcn_mfma_f32_16x16x32_bf16(a1, b1, acc[1][1], 0, 0, 0);
    __syncthreads();
  }
#pragma unroll
  for (int mt = 0; mt < 2; mt++)
#pragma unroll
    for (int nt = 0; nt < 2; nt++)
#pragma unroll
      for (int r = 0; r < 4; r++) {
        int l = l0 + wm * 32 + mt * 16 + (lane >> 4) * 4 + r;
        int m = m0 + wn * 32 + nt * 16 + rlo;
        outs[((size_t)b * LL + l) * DM + m] = acc[mt][nt][r];
      }
}

// ---------------------------------------------------------------------------
extern "C" void kernel_launch(void* const* d_in, const int* in_sizes, int n_in,
                              void* d_out, int out_size, void* d_ws, size_t ws_size,
                              hipStream_t stream) {
  (void)in_sizes; (void)n_in; (void)out_size; (void)ws_size;
  const float* A_log = (const float*)d_in[2];
  const float* Ab_log = (const float*)d_in[3];
  // stream a params: d_in[4..17], stream v: d_in[18..31]
  const float* h_a = (const float*)d_in[0];
  const float* h_v = (const float*)d_in[1];
#define AP(i) ((const float*)d_in[4 + (i)])
#define VP(i) ((const float*)d_in[18 + (i)])

  float* ws = (float*)d_ws;
  float* dl = ws;                                   // 4*SZC fp32
  float* Bb = dl + 4 * SZC;                         // 4*NSZC
  float* Cb = Bb + 4 * NSZC;                        // 4*NSZC
  float* sumdl = Cb + 4 * NSZC;                     // 2*NC2*G2C
  float* dtv_g = sumdl + (size_t)2 * NC2 * G2C;     // 4*BB*NLT*256 = 524,288
  unsigned short* xwbf = (unsigned short*)(dtv_g + (size_t)4 * BB * NLT * 256);
  unsigned short* z_t = xwbf + 4 * XWSL;            // 2*SZC bf16
  unsigned short* u = z_t + 2 * SZC;                // 4*SZC bf16
  unsigned short* xz = u + 4 * SZC;                 // 2*SZC bf16
  unsigned short* hend = xz + 2 * SZC;              // 2*HSZC bf16

  hipLaunchKernelGGL(in_proj_mfma, dim3(LL / 64, EE / 128, BB * 2), dim3(256), 0,
                     stream, h_a, h_v, AP(0), VP(0), xz, z_t);
  hipLaunchKernelGGL(xw_prep_kernel, dim3(96), dim3(256), 0, stream,
                     AP(3), AP(9), VP(3), VP(9), xwbf);
  hipLaunchKernelGGL(conv_kernel, dim3((LL / 32) * 4, BB, 4), dim3(256), 0, stream,
                     xz, AP(1), AP(2), AP(7), AP(8), VP(1), VP(2), VP(7), VP(8), u);
  hipLaunchKernelGGL(xdbl_kernel, dim3(NLT, BB, 4), dim3(256), 0, stream,
                     u, xwbf, dtv_g, Bb, Cb);
  hipLaunchKernelGGL(delta_kernel, dim3(NLT, BB, 4), dim3(256), 0, stream,
                     dtv_g, AP(4), AP(5), AP(10), AP(11), VP(4), VP(5), VP(10),
                     VP(11), dl);
  hipLaunchKernelGGL(HIP_KERNEL_NAME(scan_kernel<1>), dim3(NC2 * 16, 2), dim3(256),
                     0, stream, u, dl, z_t, Bb, Cb, A_log, Ab_log, AP(6), AP(12),
                     VP(6), VP(12), hend, sumdl);
  hipLaunchKernelGGL(scan_combine_kernel, dim3(G2C / 16, 2), dim3(256), 0, stream,
                     A_log, Ab_log, hend, sumdl);
  hipLaunchKernelGGL(HIP_KERNEL_NAME(scan_kernel<3>), dim3(NC2 * 16, 2), dim3(256),
                     0, stream, u, dl, z_t, Bb, Cb, A_log, Ab_log, AP(6), AP(12),
                     VP(6), VP(12), hend, sumdl);
  hipLaunchKernelGGL(out_proj_mfma, dim3(LL / 64, DM / 64, BB * 2), dim3(256), 0,
                     stream, u, AP(13), VP(13), (float*)d_out);
#undef AP
#undef VP
}

// Round 20
// 246.939 us; speedup vs baseline: 1.4841x; 1.1613x over previous
//
#include <hip/hip_runtime.h>
#include <hip/hip_bf16.h>
#include <cstddef>

#define BB 4
#define LL 2048
#define DM 256
#define DN 512
#define EE 1024
#define NS 16
#define RK 16
#define NC2 128         // scan chunks
#define CL2 (LL / NC2)  // chunk length = 16
#define NLT (LL / 16)   // l-tiles for xdbl/delta = 128
#define G2C (2 * BB * DN)                       // 4096
#define SZC ((size_t)BB * LL * DN)              // 4,194,304
#define NSZC ((size_t)BB * LL * NS)             // 131,072
#define HSZC ((size_t)NC2 * G2C * NS)           // 8,388,608 (bf16 elems)
#define XWSL (48 * 512)                         // 24,576

typedef __attribute__((ext_vector_type(8))) short bf16x8;
typedef __attribute__((ext_vector_type(8))) unsigned short ushort8;
typedef __attribute__((ext_vector_type(4))) unsigned short ushort4v;
typedef __attribute__((ext_vector_type(2))) unsigned short ushort2v;
typedef __attribute__((ext_vector_type(4))) float f32x4;

__device__ __forceinline__ float fsilu(float x) { return x / (1.0f + __expf(-x)); }
__device__ __forceinline__ float fsoftplus(float x) { return x > 20.0f ? x : log1pf(__expf(x)); }
__device__ __forceinline__ float fsoftplus_fast(float x) {
  return x > 20.0f ? x : __logf(1.0f + __expf(x));
}
__device__ __forceinline__ unsigned short f2bf(float x) {  // RNE float->bf16
  union { float f; unsigned int u; } v; v.f = x;
  unsigned int r = v.u + 0x7fffu + ((v.u >> 16) & 1u);
  return (unsigned short)(r >> 16);
}
__device__ __forceinline__ float bf2f(unsigned short x) {
  union { unsigned int u; float f; } v; v.u = ((unsigned int)x) << 16;
  return v.f;
}

// ---------------------------------------------------------------------------
// in_proj (both streams). Tile 128e x 64l, grid (32, 8, BB*2).
// x-blocks: C[e][l] -> xz BF16 [str][b][e][l]. z-blocks: silu -> z_t [str][b][l][d].
// ---------------------------------------------------------------------------
__global__ __launch_bounds__(256) void in_proj_mfma(
    const float* __restrict__ h_a, const float* __restrict__ h_v,
    const float* __restrict__ w_a, const float* __restrict__ w_v,
    unsigned short* __restrict__ xz, unsigned short* __restrict__ z_t) {
  __shared__ unsigned short ht[64][40];   // [l][k] bf16
  __shared__ unsigned short wt[128][40];  // [e][k]
  const int bz = blockIdx.z;
  const int b = bz & 3;
  const int str = bz >> 2;
  const float* h = str ? h_v : h_a;
  const float* w = str ? w_v : w_a;
  unsigned short* xzs = xz + (size_t)str * SZC;
  unsigned short* zts = z_t + (size_t)str * SZC;
  const int e0 = blockIdx.y * 128;
  const int l0 = blockIdx.x * 64;
  const int tid = threadIdx.x;
  const int lane = tid & 63;
  const int wv = tid >> 6;
  const bool zblk = (e0 >= DN);
  const int krow = (lane >> 4) * 8;
  const int rlo = lane & 15;
  const int rbase = (lane >> 4) * 4;

  f32x4 acc[8];
#pragma unroll
  for (int i = 0; i < 8; i++) acc[i] = (f32x4){0.f, 0.f, 0.f, 0.f};

  for (int dk = 0; dk < DM; dk += 32) {
    {
      int row = tid >> 2;
      int seg = (tid & 3) * 8;
      const float* hp = h + ((size_t)b * LL + l0 + row) * DM + dk + seg;
      float4 ha = *(const float4*)hp, hb = *(const float4*)(hp + 4);
      ushort8 hv;
      hv[0] = f2bf(ha.x); hv[1] = f2bf(ha.y); hv[2] = f2bf(ha.z); hv[3] = f2bf(ha.w);
      hv[4] = f2bf(hb.x); hv[5] = f2bf(hb.y); hv[6] = f2bf(hb.z); hv[7] = f2bf(hb.w);
      *(ushort8*)&ht[row][seg] = hv;
    }
#pragma unroll
    for (int it = 0; it < 2; it++) {
      int idx = it * 256 + tid;
      int row = idx >> 2;
      int seg = (idx & 3) * 8;
      const float* wp = w + (size_t)(e0 + row) * DM + dk + seg;
      float4 wa = *(const float4*)wp, wb = *(const float4*)(wp + 4);
      ushort8 wv8;
      wv8[0] = f2bf(wa.x); wv8[1] = f2bf(wa.y); wv8[2] = f2bf(wa.z); wv8[3] = f2bf(wa.w);
      wv8[4] = f2bf(wb.x); wv8[5] = f2bf(wb.y); wv8[6] = f2bf(wb.z); wv8[7] = f2bf(wb.w);
      *(ushort8*)&wt[row][seg] = wv8;
    }
    __syncthreads();
    if (!zblk) {
      bf16x8 af0 = *(bf16x8*)&wt[wv * 32 + 0 * 16 + rlo][krow];
      bf16x8 af1 = *(bf16x8*)&wt[wv * 32 + 1 * 16 + rlo][krow];
      bf16x8 bf0 = *(bf16x8*)&ht[0 * 16 + rlo][krow];
      bf16x8 bf1 = *(bf16x8*)&ht[1 * 16 + rlo][krow];
      bf16x8 bf2 = *(bf16x8*)&ht[2 * 16 + rlo][krow];
      bf16x8 bf3 = *(bf16x8*)&ht[3 * 16 + rlo][krow];
      acc[0] = __builtin_amdgcn_mfma_f32_16x16x32_bf16(af0, bf0, acc[0], 0, 0, 0);
      acc[1] = __builtin_amdgcn_mfma_f32_16x16x32_bf16(af0, bf1, acc[1], 0, 0, 0);
      acc[2] = __builtin_amdgcn_mfma_f32_16x16x32_bf16(af0, bf2, acc[2], 0, 0, 0);
      acc[3] = __builtin_amdgcn_mfma_f32_16x16x32_bf16(af0, bf3, acc[3], 0, 0, 0);
      acc[4] = __builtin_amdgcn_mfma_f32_16x16x32_bf16(af1, bf0, acc[4], 0, 0, 0);
      acc[5] = __builtin_amdgcn_mfma_f32_16x16x32_bf16(af1, bf1, acc[5], 0, 0, 0);
      acc[6] = __builtin_amdgcn_mfma_f32_16x16x32_bf16(af1, bf2, acc[6], 0, 0, 0);
      acc[7] = __builtin_amdgcn_mfma_f32_16x16x32_bf16(af1, bf3, acc[7], 0, 0, 0);
    } else {
      bf16x8 af0 = *(bf16x8*)&ht[0 * 16 + rlo][krow];
      bf16x8 af1 = *(bf16x8*)&ht[1 * 16 + rlo][krow];
      bf16x8 af2 = *(bf16x8*)&ht[2 * 16 + rlo][krow];
      bf16x8 af3 = *(bf16x8*)&ht[3 * 16 + rlo][krow];
      bf16x8 bf0 = *(bf16x8*)&wt[wv * 32 + 0 * 16 + rlo][krow];
      bf16x8 bf1 = *(bf16x8*)&wt[wv * 32 + 1 * 16 + rlo][krow];
      acc[0] = __builtin_amdgcn_mfma_f32_16x16x32_bf16(af0, bf0, acc[0], 0, 0, 0);
      acc[1] = __builtin_amdgcn_mfma_f32_16x16x32_bf16(af0, bf1, acc[1], 0, 0, 0);
      acc[2] = __builtin_amdgcn_mfma_f32_16x16x32_bf16(af1, bf0, acc[2], 0, 0, 0);
      acc[3] = __builtin_amdgcn_mfma_f32_16x16x32_bf16(af1, bf1, acc[3], 0, 0, 0);
      acc[4] = __builtin_amdgcn_mfma_f32_16x16x32_bf16(af2, bf0, acc[4], 0, 0, 0);
      acc[5] = __builtin_amdgcn_mfma_f32_16x16x32_bf16(af2, bf1, acc[5], 0, 0, 0);
      acc[6] = __builtin_amdgcn_mfma_f32_16x16x32_bf16(af3, bf0, acc[6], 0, 0, 0);
      acc[7] = __builtin_amdgcn_mfma_f32_16x16x32_bf16(af3, bf1, acc[7], 0, 0, 0);
    }
    __syncthreads();
  }
  if (!zblk) {
#pragma unroll
    for (int m = 0; m < 2; m++)
#pragma unroll
      for (int n = 0; n < 4; n++)
#pragma unroll
        for (int r = 0; r < 4; r++) {
          int e = e0 + wv * 32 + m * 16 + rbase + r;
          int l = l0 + n * 16 + rlo;
          xzs[((size_t)b * DN + e) * LL + l] = f2bf(acc[m * 4 + n][r]);
        }
  } else {
#pragma unroll
    for (int m = 0; m < 4; m++)
#pragma unroll
      for (int n = 0; n < 2; n++)
#pragma unroll
        for (int r = 0; r < 4; r++) {
          int l = l0 + m * 16 + rbase + r;
          int d = (e0 - DN) + wv * 32 + n * 16 + rlo;
          zts[((size_t)b * LL + l) * DN + d] = f2bf(fsilu(acc[m * 2 + n][r]));
        }
  }
}

// ---------------------------------------------------------------------------
// conv (both streams): grid ((LL/32)*4, BB, 4): z = str*2 + rev.
// ---------------------------------------------------------------------------
__global__ __launch_bounds__(256) void conv_kernel(
    const unsigned short* __restrict__ xz,
    const float* __restrict__ cw_af, const float* __restrict__ cb_af,
    const float* __restrict__ cw_ar, const float* __restrict__ cb_ar,
    const float* __restrict__ cw_vf, const float* __restrict__ cb_vf,
    const float* __restrict__ cw_vr, const float* __restrict__ cb_vr,
    unsigned short* __restrict__ u) {
  __shared__ float xt[128][33];
  const int slab = blockIdx.z;      // str*2 + rev
  const int rev = slab & 1;
  const int str = slab >> 1;
  const int b = blockIdx.y;
  const int dc0 = (blockIdx.x & 3) * 128;
  const int l0 = (blockIdx.x >> 2) * 32;
  const int tid = threadIdx.x;
  const int lc = tid & 31;
  const int dg = tid >> 5;
  const int l = l0 + lc;
  const float* conv_w = str ? (rev ? cw_vr : cw_vf) : (rev ? cw_ar : cw_af);
  const float* conv_b = str ? (rev ? cb_vr : cb_vf) : (rev ? cb_ar : cb_af);
  const unsigned short* xzs = xz + (size_t)str * SZC;
  unsigned short* u_out = u + (size_t)slab * SZC;

#pragma unroll
  for (int i = 0; i < 16; i++) {
    int dloc = dg * 16 + i;
    int dd = dc0 + dloc;
    const unsigned short* base = xzs + ((size_t)b * DN + dd) * LL;
    float4 cw4 = *(const float4*)(conv_w + dd * 4);
    float a0 = conv_b[dd];
    if (rev) {
      a0 = fmaf(cw4.w, bf2f(base[l]), a0);
      if (l + 1 < LL) a0 = fmaf(cw4.z, bf2f(base[l + 1]), a0);
      if (l + 2 < LL) a0 = fmaf(cw4.y, bf2f(base[l + 2]), a0);
      if (l + 3 < LL) a0 = fmaf(cw4.x, bf2f(base[l + 3]), a0);
    } else {
      a0 = fmaf(cw4.w, bf2f(base[l]), a0);
      if (l - 1 >= 0) a0 = fmaf(cw4.z, bf2f(base[l - 1]), a0);
      if (l - 2 >= 0) a0 = fmaf(cw4.y, bf2f(base[l - 2]), a0);
      if (l - 3 >= 0) a0 = fmaf(cw4.x, bf2f(base[l - 3]), a0);
    }
    xt[dloc][lc] = fsilu(a0);
  }
  __syncthreads();
#pragma unroll
  for (int j = 0; j < 8; j++) {
    int idx = j * 256 + tid;
    int d2 = idx & 63;
    int l2 = idx >> 6;
    ushort2v v;
    v[0] = f2bf(xt[2 * d2][l2]);
    v[1] = f2bf(xt[2 * d2 + 1][l2]);
    *(ushort2v*)&u_out[((size_t)b * LL + l0 + l2) * DN + dc0 + 2 * d2] = v;
  }
}

// ---------------------------------------------------------------------------
// prep: convert all 4 x_w matrices to bf16 slabs.
// ---------------------------------------------------------------------------
__global__ __launch_bounds__(256) void xw_prep_kernel(
    const float* __restrict__ a_f, const float* __restrict__ a_r,
    const float* __restrict__ v_f, const float* __restrict__ v_r,
    unsigned short* __restrict__ o) {
  int i = blockIdx.x * 256 + threadIdx.x;
  if (i < XWSL) {
    o[i] = f2bf(a_f[i]);
    o[i + XWSL] = f2bf(a_r[i]);
    o[i + 2 * XWSL] = f2bf(v_f[i]);
    o[i + 3 * XWSL] = f2bf(v_r[i]);
  }
}

// ---------------------------------------------------------------------------
// xdbl (both streams): grid (NLT, BB, 4): z = str*2 + rev.
// ---------------------------------------------------------------------------
__global__ __launch_bounds__(256) void xdbl_kernel(
    const unsigned short* __restrict__ u, const unsigned short* __restrict__ xwbf,
    float* __restrict__ dtv_g, float* __restrict__ Bb, float* __restrict__ Cb) {
  __shared__ __align__(16) unsigned short ub[4][16][136];
  __shared__ float red[4][48][17];
  const int slab = blockIdx.z;
  const int b = blockIdx.y;
  const int lt = blockIdx.x;
  const int l0 = lt * 16;
  const int tid = threadIdx.x;
  const int lane = tid & 63;
  const int w = tid >> 6;
  const int rlo = lane & 15;
  const int hi4 = lane >> 4;
  const int kseg = hi4 * 8;

  const unsigned short* up = u + (size_t)slab * SZC + ((size_t)b * LL + l0) * DN;
  const unsigned short* xwb = xwbf + (size_t)slab * XWSL;
  float* B_out = Bb + (size_t)slab * NSZC;
  float* C_out = Cb + (size_t)slab * NSZC;

#pragma unroll
  for (int j = 0; j < 4; j++) {
    int idx = j * 256 + tid;
    int l2 = idx >> 6;
    int c8 = idx & 63;
    ushort8 v = *(const ushort8*)(up + (size_t)l2 * DN + c8 * 8);
    *(ushort8*)&ub[c8 >> 4][l2][(c8 & 15) * 8] = v;
  }
  __syncthreads();

  f32x4 am0 = (f32x4){0.f, 0.f, 0.f, 0.f};
  f32x4 am1 = (f32x4){0.f, 0.f, 0.f, 0.f};
  f32x4 am2 = (f32x4){0.f, 0.f, 0.f, 0.f};
#pragma unroll
  for (int ks = 0; ks < 4; ks++) {
    bf16x8 bfrag = *(bf16x8*)&ub[w][rlo][ks * 32 + kseg];
    const unsigned short* xp = xwb + (size_t)(w * 128 + ks * 32 + kseg);
    bf16x8 a0 = *(const bf16x8*)(xp + (size_t)(0 + rlo) * 512);
    bf16x8 a1 = *(const bf16x8*)(xp + (size_t)(16 + rlo) * 512);
    bf16x8 a2 = *(const bf16x8*)(xp + (size_t)(32 + rlo) * 512);
    am0 = __builtin_amdgcn_mfma_f32_16x16x32_bf16(a0, bfrag, am0, 0, 0, 0);
    am1 = __builtin_amdgcn_mfma_f32_16x16x32_bf16(a1, bfrag, am1, 0, 0, 0);
    am2 = __builtin_amdgcn_mfma_f32_16x16x32_bf16(a2, bfrag, am2, 0, 0, 0);
  }
  {
    const int rbase = hi4 * 4;
#pragma unroll
    for (int r = 0; r < 4; r++) red[w][0 + rbase + r][rlo] = am0[r];
#pragma unroll
    for (int r = 0; r < 4; r++) red[w][16 + rbase + r][rlo] = am1[r];
#pragma unroll
    for (int r = 0; r < 4; r++) red[w][32 + rbase + r][rlo] = am2[r];
  }
  __syncthreads();
  float* dtvp = dtv_g + (((size_t)slab * BB + b) * NLT + lt) * 256;
#pragma unroll
  for (int i = 0; i < 3; i++) {
    int o = i * 256 + tid;
    int row = o >> 4, col = o & 15;
    float s = (red[0][row][col] + red[1][row][col]) +
              (red[2][row][col] + red[3][row][col]);
    if (row < 16)
      dtvp[(size_t)row * 16 + col] = s;
    else if (row < 32)
      B_out[((size_t)b * LL + l0 + col) * NS + (row - 16)] = s;
    else
      C_out[((size_t)b * LL + l0 + col) * NS + (row - 32)] = s;
  }
}

// ---------------------------------------------------------------------------
// delta (both streams): grid (NLT, BB, 4). dtv transposed in LDS [l2][k] so
// each l2-step is 4 x ds_read_b128 (broadcast) shared by BOTH d-halves;
// 64 b128 reads/thread instead of 512 b32. softplus via hw log/exp.
// ---------------------------------------------------------------------------
__global__ __launch_bounds__(256) void delta_kernel(
    const float* __restrict__ dtv_g,
    const float* __restrict__ dtw_af, const float* __restrict__ dtb_af,
    const float* __restrict__ dtw_ar, const float* __restrict__ dtb_ar,
    const float* __restrict__ dtw_vf, const float* __restrict__ dtb_vf,
    const float* __restrict__ dtw_vr, const float* __restrict__ dtb_vr,
    float* __restrict__ dl) {
  __shared__ __align__(16) float dtvT[16][20];  // [l2][k], 16B-aligned rows
  const int slab = blockIdx.z;
  const int rev = slab & 1;
  const int str = slab >> 1;
  const int b = blockIdx.y;
  const int lt = blockIdx.x;
  const int l0 = lt * 16;
  const int tid = threadIdx.x;
  const float* dt_w = str ? (rev ? dtw_vr : dtw_vf) : (rev ? dtw_ar : dtw_af);
  const float* dt_b = str ? (rev ? dtb_vr : dtb_vf) : (rev ? dtb_ar : dtb_af);
  float* dl_out = dl + (size_t)slab * SZC;

  {  // dtv_g stored [k][l]; transpose into [l][k]
    const float* dtvp = dtv_g + (((size_t)slab * BB + b) * NLT + lt) * 256;
    float v = dtvp[tid];  // tid = k*16 + l
    dtvT[tid & 15][tid >> 4] = v;
  }
  __syncthreads();

  // both d-halves' weights in registers (8 float4 = 32 VGPR)
  const int dd0 = tid, dd1 = tid + 256;
  const float4* wr0 = (const float4*)(dt_w + (size_t)dd0 * RK);
  const float4* wr1 = (const float4*)(dt_w + (size_t)dd1 * RK);
  float4 a_0 = wr0[0], a_1 = wr0[1], a_2 = wr0[2], a_3 = wr0[3];
  float4 b_0 = wr1[0], b_1 = wr1[1], b_2 = wr1[2], b_3 = wr1[3];
  float bias0 = dt_b[dd0], bias1 = dt_b[dd1];

#pragma unroll
  for (int l2 = 0; l2 < 16; l2++) {
    float4 q0 = *(const float4*)&dtvT[l2][0];
    float4 q1 = *(const float4*)&dtvT[l2][4];
    float4 q2 = *(const float4*)&dtvT[l2][8];
    float4 q3 = *(const float4*)&dtvT[l2][12];
    float s0 = bias0, s1 = bias1;
    s0 = fmaf(a_0.x, q0.x, s0); s1 = fmaf(b_0.x, q0.x, s1);
    s0 = fmaf(a_0.y, q0.y, s0); s1 = fmaf(b_0.y, q0.y, s1);
    s0 = fmaf(a_0.z, q0.z, s0); s1 = fmaf(b_0.z, q0.z, s1);
    s0 = fmaf(a_0.w, q0.w, s0); s1 = fmaf(b_0.w, q0.w, s1);
    s0 = fmaf(a_1.x, q1.x, s0); s1 = fmaf(b_1.x, q1.x, s1);
    s0 = fmaf(a_1.y, q1.y, s0); s1 = fmaf(b_1.y, q1.y, s1);
    s0 = fmaf(a_1.z, q1.z, s0); s1 = fmaf(b_1.z, q1.z, s1);
    s0 = fmaf(a_1.w, q1.w, s0); s1 = fmaf(b_1.w, q1.w, s1);
    s0 = fmaf(a_2.x, q2.x, s0); s1 = fmaf(b_2.x, q2.x, s1);
    s0 = fmaf(a_2.y, q2.y, s0); s1 = fmaf(b_2.y, q2.y, s1);
    s0 = fmaf(a_2.z, q2.z, s0); s1 = fmaf(b_2.z, q2.z, s1);
    s0 = fmaf(a_2.w, q2.w, s0); s1 = fmaf(b_2.w, q2.w, s1);
    s0 = fmaf(a_3.x, q3.x, s0); s1 = fmaf(b_3.x, q3.x, s1);
    s0 = fmaf(a_3.y, q3.y, s0); s1 = fmaf(b_3.y, q3.y, s1);
    s0 = fmaf(a_3.z, q3.z, s0); s1 = fmaf(b_3.z, q3.z, s1);
    s0 = fmaf(a_3.w, q3.w, s0); s1 = fmaf(b_3.w, q3.w, s1);
    float* rowp = dl_out + ((size_t)b * LL + l0 + l2) * DN;
    rowp[dd0] = fsoftplus_fast(s0);
    rowp[dd1] = fsoftplus_fast(s1);
  }
}

// ---------------------------------------------------------------------------
// Scan (both streams, LDS-staged): grid (NC2*16, 2).
// ---------------------------------------------------------------------------
#define HSTEP(n, Bcomp, Ccomp)                      \
  {                                                 \
    float e_ = __expf(dc * Av[n]);                  \
    h[n] = fmaf(e_, h[n], dlu * (Bcomp));           \
    if (PHASE == 3) acc = fmaf(h[n], (Ccomp), acc); \
  }

template <int PHASE>
__global__ __launch_bounds__(256) void scan_kernel(
    unsigned short* __restrict__ u, const float* __restrict__ dl,
    const unsigned short* __restrict__ z_t, const float* __restrict__ Bb,
    const float* __restrict__ Cb, const float* __restrict__ A_log,
    const float* __restrict__ Ab_log,
    const float* __restrict__ D_af, const float* __restrict__ D_ar,
    const float* __restrict__ D_vf, const float* __restrict__ D_vr,
    unsigned short* __restrict__ hend, float* __restrict__ sumdl) {
  __shared__ unsigned short us[CL2][256];
  __shared__ unsigned short zs[CL2][256];
  __shared__ float dls[CL2][256];
  __shared__ float Bs[CL2][16];
  __shared__ float Cs[CL2][16];
  const int tid = threadIdx.x;
  const int str = blockIdx.y;
  const int ch0 = (blockIdx.x & 15) * 256;
  const int chunk = blockIdx.x >> 4;
  const int ch = ch0 + tid;
  const bool rev = ch0 >= BB * DN;
  const int slab = str * 2 + (rev ? 1 : 0);
  const int cid0 = rev ? ch0 - BB * DN : ch0;
  const int b = cid0 >> 9;
  const int d0 = cid0 & (DN - 1);
  const int d = d0 + tid;

  const float* Arow = (rev ? Ab_log : A_log) + d * NS;
  float Av[NS];
#pragma unroll
  for (int n = 0; n < NS; n++) Av[n] = -__expf(Arow[n]);
  const float* Dsel = str ? (rev ? D_vr : D_vf) : (rev ? D_ar : D_af);
  const float Dd = Dsel[d];

  const int tlo = rev ? (LL - CL2 * (chunk + 1)) : (CL2 * chunk);
  unsigned short* uyb = u + (size_t)slab * SZC + ((size_t)b * LL + tlo) * DN + d0;
  const float* dlb = dl + (size_t)slab * SZC + ((size_t)b * LL + tlo) * DN + d0;
  const unsigned short* zb = z_t + (size_t)str * SZC + ((size_t)b * LL + tlo) * DN + d0;
  const float* Bp = Bb + (size_t)slab * NSZC + ((size_t)b * LL + tlo) * NS;
  const float* Cp = Cb + (size_t)slab * NSZC + ((size_t)b * LL + tlo) * NS;
  unsigned short* hendp = hend + (size_t)str * HSZC;
  float* sumdlp = sumdl + (size_t)str * NC2 * G2C;

  // ---- stage the whole chunk tile ----
  {
    const int lane = tid & 63;
    const int w = tid >> 6;
#pragma unroll
    for (int j4 = 0; j4 < 4; j4++) {
      int row = w * 4 + j4;
      ushort4v uu = *(const ushort4v*)(uyb + (size_t)row * DN + lane * 4);
      *(ushort4v*)&us[row][lane * 4] = uu;
      float4 dd4 = *(const float4*)(dlb + (size_t)row * DN + lane * 4);
      *(float4*)&dls[row][lane * 4] = dd4;
      if (PHASE == 3) {
        ushort4v zz = *(const ushort4v*)(zb + (size_t)row * DN + lane * 4);
        *(ushort4v*)&zs[row][lane * 4] = zz;
      }
    }
    Bs[tid >> 4][tid & 15] = Bp[(size_t)(tid >> 4) * NS + (tid & 15)];
    if (PHASE == 3) Cs[tid >> 4][tid & 15] = Cp[(size_t)(tid >> 4) * NS + (tid & 15)];
  }

  float h[NS];
  if (PHASE == 3) {
    const unsigned short* hp = hendp + ((size_t)chunk * G2C + ch) * NS;
#pragma unroll
    for (int n = 0; n < NS; n++) h[n] = bf2f(hp[n]);
  } else {
#pragma unroll
    for (int n = 0; n < NS; n++) h[n] = 0.f;
  }
  __syncthreads();

  float sdl = 0.f;
#pragma unroll
  for (int jj = 0; jj < CL2; jj++) {
    const int j = rev ? (CL2 - 1 - jj) : jj;
    const float uc = bf2f(us[j][tid]);
    const float dc = dls[j][tid];
    const float4 Bq0 = *(const float4*)&Bs[j][0];
    const float4 Bq1 = *(const float4*)&Bs[j][4];
    const float4 Bq2 = *(const float4*)&Bs[j][8];
    const float4 Bq3 = *(const float4*)&Bs[j][12];
    float4 Cq0 = {0, 0, 0, 0}, Cq1 = {0, 0, 0, 0}, Cq2 = {0, 0, 0, 0},
           Cq3 = {0, 0, 0, 0};
    if (PHASE == 3) {
      Cq0 = *(const float4*)&Cs[j][0];
      Cq1 = *(const float4*)&Cs[j][4];
      Cq2 = *(const float4*)&Cs[j][8];
      Cq3 = *(const float4*)&Cs[j][12];
    }
    const float dlu = dc * uc;
    float acc = 0.f;
    HSTEP(0, Bq0.x, Cq0.x)  HSTEP(1, Bq0.y, Cq0.y)
    HSTEP(2, Bq0.z, Cq0.z)  HSTEP(3, Bq0.w, Cq0.w)
    HSTEP(4, Bq1.x, Cq1.x)  HSTEP(5, Bq1.y, Cq1.y)
    HSTEP(6, Bq1.z, Cq1.z)  HSTEP(7, Bq1.w, Cq1.w)
    HSTEP(8, Bq2.x, Cq2.x)  HSTEP(9, Bq2.y, Cq2.y)
    HSTEP(10, Bq2.z, Cq2.z) HSTEP(11, Bq2.w, Cq2.w)
    HSTEP(12, Bq3.x, Cq3.x) HSTEP(13, Bq3.y, Cq3.y)
    HSTEP(14, Bq3.z, Cq3.z) HSTEP(15, Bq3.w, Cq3.w)
    if (PHASE == 1) sdl += dc;
    if (PHASE == 3) {
      const float zc = bf2f(zs[j][tid]);
      float y = fmaf(uc, Dd, acc) * zc;
      uyb[(size_t)j * DN + tid] = f2bf(y);
    }
  }
  if (PHASE == 1) {
    unsigned short* hp = hendp + ((size_t)chunk * G2C + ch) * NS;
#pragma unroll
    for (int n = 0; n < NS; n++) hp[n] = f2bf(h[n]);
    sumdlp[(size_t)chunk * G2C + ch] = sdl;
  }
}
#undef HSTEP

// ---------------------------------------------------------------------------
// Phase 2 (both streams): grid (G2C/16, 2).
// ---------------------------------------------------------------------------
__global__ __launch_bounds__(256) void scan_combine_kernel(
    const float* __restrict__ A_log, const float* __restrict__ Ab_log,
    unsigned short* __restrict__ hend, const float* __restrict__ sumdl) {
  __shared__ float tile[8][256];
  __shared__ float sd[8][16];
  const int tid = threadIdx.x;
  const int str = blockIdx.y;
  const int ch0 = blockIdx.x * 16;
  const int chl = tid >> 4;
  const int n = tid & 15;
  const int ch = ch0 + chl;
  const bool rev = ch >= BB * DN;
  const int d = ch & (DN - 1);
  const float Av = -__expf((rev ? Ab_log : A_log)[d * NS + n]);
  unsigned short* hendp = hend + (size_t)str * HSZC;
  const float* sumdlp = sumdl + (size_t)str * NC2 * G2C;
  float H = 0.f;
  for (int cb = 0; cb < NC2 / 8; cb++) {
#pragma unroll
    for (int j = 0; j < 8; j++)
      tile[j][tid] = bf2f(hendp[((size_t)(cb * 8 + j) * G2C + ch0) * NS + tid]);
    if (tid < 128) {
      int j = tid >> 4, k = tid & 15;
      sd[j][k] = sumdlp[(size_t)(cb * 8 + j) * G2C + ch0 + k];
    }
    __syncthreads();
#pragma unroll
    for (int j = 0; j < 8; j++) {
      float tmp = tile[j][tid];
      tile[j][tid] = H;
      H = fmaf(__expf(Av * sd[j][chl]), H, tmp);
    }
    __syncthreads();
#pragma unroll
    for (int j = 0; j < 8; j++)
      hendp[((size_t)(cb * 8 + j) * G2C + ch0) * NS + tid] = f2bf(tile[j][tid]);
    __syncthreads();
  }
}

// ---------------------------------------------------------------------------
// out_proj (both streams): grid (32, 4, BB*2).
// ---------------------------------------------------------------------------
__global__ __launch_bounds__(256) void out_proj_mfma(
    const unsigned short* __restrict__ u,
    const float* __restrict__ ow_a, const float* __restrict__ ow_v,
    float* __restrict__ outp) {
  __shared__ unsigned short yt[64][40];
  __shared__ unsigned short wo[64][40];
  const int bz = blockIdx.z;
  const int b = bz & 3;
  const int str = bz >> 2;
  const float* ow = str ? ow_v : ow_a;
  const unsigned short* yf = u + (size_t)(str * 2) * SZC;
  const unsigned short* yr = u + (size_t)(str * 2 + 1) * SZC;
  float* outs = outp + (size_t)str * BB * LL * DM;
  const int m0 = blockIdx.y * 64;
  const int l0 = blockIdx.x * 64;
  const int tid = threadIdx.x;
  const int lane = tid & 63;
  const int wid = tid >> 6;
  const int wm = wid >> 1, wn = wid & 1;
  const int krow = (lane >> 4) * 8;
  const int rlo = lane & 15;

  f32x4 acc[2][2];
#pragma unroll
  for (int i = 0; i < 2; i++)
#pragma unroll
    for (int j = 0; j < 2; j++) acc[i][j] = (f32x4){0.f, 0.f, 0.f, 0.f};

  for (int dk = 0; dk < DN; dk += 32) {
    {
      int row = tid >> 2;
      int seg = (tid & 3) * 8;
      ushort8 a = *(const ushort8*)(yf + ((size_t)b * LL + l0 + row) * DN + dk + seg);
      ushort8 c = *(const ushort8*)(yr + ((size_t)b * LL + l0 + row) * DN + dk + seg);
      ushort8 yv;
#pragma unroll
      for (int k = 0; k < 8; k++) yv[k] = f2bf(0.5f * (bf2f(a[k]) + bf2f(c[k])));
      *(ushort8*)&yt[row][seg] = yv;
      const float* wp = ow + (size_t)(m0 + row) * DN + dk + seg;
      float4 w0 = *(const float4*)wp, w1 = *(const float4*)(wp + 4);
      ushort8 wv;
      wv[0] = f2bf(w0.x); wv[1] = f2bf(w0.y); wv[2] = f2bf(w0.z); wv[3] = f2bf(w0.w);
      wv[4] = f2bf(w1.x); wv[5] = f2bf(w1.y); wv[6] = f2bf(w1.z); wv[7] = f2bf(w1.w);
      *(ushort8*)&wo[row][seg] = wv;
    }
    __syncthreads();
    bf16x8 a0 = *(bf16x8*)&yt[wm * 32 + rlo][krow];
    bf16x8 a1 = *(bf16x8*)&yt[wm * 32 + 16 + rlo][krow];
    bf16x8 b0 = *(bf16x8*)&wo[wn * 32 + rlo][krow];
    bf16x8 b1 = *(bf16x8*)&wo[wn * 32 + 16 + rlo][krow];
    acc[0][0] = __builtin_amdgcn_mfma_f32_16x16x32_bf16(a0, b0, acc[0][0], 0, 0, 0);
    acc[0][1] = __builtin_amdgcn_mfma_f32_16x16x32_bf16(a0, b1, acc[0][1], 0, 0, 0);
    acc[1][0] = __builtin_amdgcn_mfma_f32_16x16x32_bf16(a1, b0, acc[1][0], 0, 0, 0);
    acc[1][1] = __builtin_amdgcn_mfma_f32_16x16x32_bf16(a1, b1, acc[1][1], 0, 0, 0);
    __syncthreads();
  }
#pragma unroll
  for (int mt = 0; mt < 2; mt++)
#pragma unroll
    for (int nt = 0; nt < 2; nt++)
#pragma unroll
      for (int r = 0; r < 4; r++) {
        int l = l0 + wm * 32 + mt * 16 + (lane >> 4) * 4 + r;
        int m = m0 + wn * 32 + nt * 16 + rlo;
        outs[((size_t)b * LL + l) * DM + m] = acc[mt][nt][r];
      }
}

// ---------------------------------------------------------------------------
extern "C" void kernel_launch(void* const* d_in, const int* in_sizes, int n_in,
                              void* d_out, int out_size, void* d_ws, size_t ws_size,
                              hipStream_t stream) {
  (void)in_sizes; (void)n_in; (void)out_size; (void)ws_size;
  const float* A_log = (const float*)d_in[2];
  const float* Ab_log = (const float*)d_in[3];
  const float* h_a = (const float*)d_in[0];
  const float* h_v = (const float*)d_in[1];
#define AP(i) ((const float*)d_in[4 + (i)])
#define VP(i) ((const float*)d_in[18 + (i)])

  float* ws = (float*)d_ws;
  float* dl = ws;                                   // 4*SZC fp32
  float* Bb = dl + 4 * SZC;                         // 4*NSZC
  float* Cb = Bb + 4 * NSZC;                        // 4*NSZC
  float* sumdl = Cb + 4 * NSZC;                     // 2*NC2*G2C
  float* dtv_g = sumdl + (size_t)2 * NC2 * G2C;     // 4*BB*NLT*256 = 524,288
  unsigned short* xwbf = (unsigned short*)(dtv_g + (size_t)4 * BB * NLT * 256);
  unsigned short* z_t = xwbf + 4 * XWSL;            // 2*SZC bf16
  unsigned short* u = z_t + 2 * SZC;                // 4*SZC bf16
  unsigned short* xz = u + 4 * SZC;                 // 2*SZC bf16
  unsigned short* hend = xz + 2 * SZC;              // 2*HSZC bf16

  hipLaunchKernelGGL(in_proj_mfma, dim3(LL / 64, EE / 128, BB * 2), dim3(256), 0,
                     stream, h_a, h_v, AP(0), VP(0), xz, z_t);
  hipLaunchKernelGGL(xw_prep_kernel, dim3(96), dim3(256), 0, stream,
                     AP(3), AP(9), VP(3), VP(9), xwbf);
  hipLaunchKernelGGL(conv_kernel, dim3((LL / 32) * 4, BB, 4), dim3(256), 0, stream,
                     xz, AP(1), AP(2), AP(7), AP(8), VP(1), VP(2), VP(7), VP(8), u);
  hipLaunchKernelGGL(xdbl_kernel, dim3(NLT, BB, 4), dim3(256), 0, stream,
                     u, xwbf, dtv_g, Bb, Cb);
  hipLaunchKernelGGL(delta_kernel, dim3(NLT, BB, 4), dim3(256), 0, stream,
                     dtv_g, AP(4), AP(5), AP(10), AP(11), VP(4), VP(5), VP(10),
                     VP(11), dl);
  hipLaunchKernelGGL(HIP_KERNEL_NAME(scan_kernel<1>), dim3(NC2 * 16, 2), dim3(256),
                     0, stream, u, dl, z_t, Bb, Cb, A_log, Ab_log, AP(6), AP(12),
                     VP(6), VP(12), hend, sumdl);
  hipLaunchKernelGGL(scan_combine_kernel, dim3(G2C / 16, 2), dim3(256), 0, stream,
                     A_log, Ab_log, hend, sumdl);
  hipLaunchKernelGGL(HIP_KERNEL_NAME(scan_kernel<3>), dim3(NC2 * 16, 2), dim3(256),
                     0, stream, u, dl, z_t, Bb, Cb, A_log, Ab_log, AP(6), AP(12),
                     VP(6), VP(12), hend, sumdl);
  hipLaunchKernelGGL(out_proj_mfma, dim3(LL / 64, DM / 64, BB * 2), dim3(256), 0,
                     stream, u, AP(13), VP(13), (float*)d_out);
#undef AP
#undef VP
}

// Round 21
// 226.668 us; speedup vs baseline: 1.6168x; 1.0894x over previous
//
#include <hip/hip_runtime.h>
#include <hip/hip_bf16.h>
#include <cstddef>

#define BB 4
#define LL 2048
#define DM 256
#define DN 512
#define EE 1024
#define NS 16
#define RK 16
#define NC2 128         // scan chunks
#define CL2 (LL / NC2)  // chunk length = 16
#define NLT (LL / 16)   // l-tiles for xdbl/delta = 128
#define G2C (2 * BB * DN)                       // 4096
#define SZC ((size_t)BB * LL * DN)              // 4,194,304
#define NSZC ((size_t)BB * LL * NS)             // 131,072
#define HSZC ((size_t)NC2 * G2C * NS)           // 8,388,608 (bf16 elems)
#define XWSL (48 * 512)                         // 24,576

typedef __attribute__((ext_vector_type(8))) short bf16x8;
typedef __attribute__((ext_vector_type(8))) unsigned short ushort8;
typedef __attribute__((ext_vector_type(4))) unsigned short ushort4v;
typedef __attribute__((ext_vector_type(2))) unsigned short ushort2v;
typedef __attribute__((ext_vector_type(4))) float f32x4;

__device__ __forceinline__ float fsilu(float x) { return x / (1.0f + __expf(-x)); }
__device__ __forceinline__ float fsoftplus_fast(float x) {
  return x > 20.0f ? x : __logf(1.0f + __expf(x));
}
__device__ __forceinline__ unsigned short f2bf(float x) {  // RNE float->bf16
  union { float f; unsigned int u; } v; v.f = x;
  unsigned int r = v.u + 0x7fffu + ((v.u >> 16) & 1u);
  return (unsigned short)(r >> 16);
}
__device__ __forceinline__ float bf2f(unsigned short x) {
  union { unsigned int u; float f; } v; v.u = ((unsigned int)x) << 16;
  return v.f;
}

// ---------------------------------------------------------------------------
// in_proj (both streams). Tile 128e x 64l, grid (32, 8, BB*2).
// ---------------------------------------------------------------------------
__global__ __launch_bounds__(256) void in_proj_mfma(
    const float* __restrict__ h_a, const float* __restrict__ h_v,
    const float* __restrict__ w_a, const float* __restrict__ w_v,
    unsigned short* __restrict__ xz, unsigned short* __restrict__ z_t) {
  __shared__ unsigned short ht[64][40];   // [l][k] bf16
  __shared__ unsigned short wt[128][40];  // [e][k]
  const int bz = blockIdx.z;
  const int b = bz & 3;
  const int str = bz >> 2;
  const float* h = str ? h_v : h_a;
  const float* w = str ? w_v : w_a;
  unsigned short* xzs = xz + (size_t)str * SZC;
  unsigned short* zts = z_t + (size_t)str * SZC;
  const int e0 = blockIdx.y * 128;
  const int l0 = blockIdx.x * 64;
  const int tid = threadIdx.x;
  const int lane = tid & 63;
  const int wv = tid >> 6;
  const bool zblk = (e0 >= DN);
  const int krow = (lane >> 4) * 8;
  const int rlo = lane & 15;
  const int rbase = (lane >> 4) * 4;

  f32x4 acc[8];
#pragma unroll
  for (int i = 0; i < 8; i++) acc[i] = (f32x4){0.f, 0.f, 0.f, 0.f};

  for (int dk = 0; dk < DM; dk += 32) {
    {
      int row = tid >> 2;
      int seg = (tid & 3) * 8;
      const float* hp = h + ((size_t)b * LL + l0 + row) * DM + dk + seg;
      float4 ha = *(const float4*)hp, hb = *(const float4*)(hp + 4);
      ushort8 hv;
      hv[0] = f2bf(ha.x); hv[1] = f2bf(ha.y); hv[2] = f2bf(ha.z); hv[3] = f2bf(ha.w);
      hv[4] = f2bf(hb.x); hv[5] = f2bf(hb.y); hv[6] = f2bf(hb.z); hv[7] = f2bf(hb.w);
      *(ushort8*)&ht[row][seg] = hv;
    }
#pragma unroll
    for (int it = 0; it < 2; it++) {
      int idx = it * 256 + tid;
      int row = idx >> 2;
      int seg = (idx & 3) * 8;
      const float* wp = w + (size_t)(e0 + row) * DM + dk + seg;
      float4 wa = *(const float4*)wp, wb = *(const float4*)(wp + 4);
      ushort8 wv8;
      wv8[0] = f2bf(wa.x); wv8[1] = f2bf(wa.y); wv8[2] = f2bf(wa.z); wv8[3] = f2bf(wa.w);
      wv8[4] = f2bf(wb.x); wv8[5] = f2bf(wb.y); wv8[6] = f2bf(wb.z); wv8[7] = f2bf(wb.w);
      *(ushort8*)&wt[row][seg] = wv8;
    }
    __syncthreads();
    if (!zblk) {
      bf16x8 af0 = *(bf16x8*)&wt[wv * 32 + 0 * 16 + rlo][krow];
      bf16x8 af1 = *(bf16x8*)&wt[wv * 32 + 1 * 16 + rlo][krow];
      bf16x8 bf0 = *(bf16x8*)&ht[0 * 16 + rlo][krow];
      bf16x8 bf1 = *(bf16x8*)&ht[1 * 16 + rlo][krow];
      bf16x8 bf2 = *(bf16x8*)&ht[2 * 16 + rlo][krow];
      bf16x8 bf3 = *(bf16x8*)&ht[3 * 16 + rlo][krow];
      acc[0] = __builtin_amdgcn_mfma_f32_16x16x32_bf16(af0, bf0, acc[0], 0, 0, 0);
      acc[1] = __builtin_amdgcn_mfma_f32_16x16x32_bf16(af0, bf1, acc[1], 0, 0, 0);
      acc[2] = __builtin_amdgcn_mfma_f32_16x16x32_bf16(af0, bf2, acc[2], 0, 0, 0);
      acc[3] = __builtin_amdgcn_mfma_f32_16x16x32_bf16(af0, bf3, acc[3], 0, 0, 0);
      acc[4] = __builtin_amdgcn_mfma_f32_16x16x32_bf16(af1, bf0, acc[4], 0, 0, 0);
      acc[5] = __builtin_amdgcn_mfma_f32_16x16x32_bf16(af1, bf1, acc[5], 0, 0, 0);
      acc[6] = __builtin_amdgcn_mfma_f32_16x16x32_bf16(af1, bf2, acc[6], 0, 0, 0);
      acc[7] = __builtin_amdgcn_mfma_f32_16x16x32_bf16(af1, bf3, acc[7], 0, 0, 0);
    } else {
      bf16x8 af0 = *(bf16x8*)&ht[0 * 16 + rlo][krow];
      bf16x8 af1 = *(bf16x8*)&ht[1 * 16 + rlo][krow];
      bf16x8 af2 = *(bf16x8*)&ht[2 * 16 + rlo][krow];
      bf16x8 af3 = *(bf16x8*)&ht[3 * 16 + rlo][krow];
      bf16x8 bf0 = *(bf16x8*)&wt[wv * 32 + 0 * 16 + rlo][krow];
      bf16x8 bf1 = *(bf16x8*)&wt[wv * 32 + 1 * 16 + rlo][krow];
      acc[0] = __builtin_amdgcn_mfma_f32_16x16x32_bf16(af0, bf0, acc[0], 0, 0, 0);
      acc[1] = __builtin_amdgcn_mfma_f32_16x16x32_bf16(af0, bf1, acc[1], 0, 0, 0);
      acc[2] = __builtin_amdgcn_mfma_f32_16x16x32_bf16(af1, bf0, acc[2], 0, 0, 0);
      acc[3] = __builtin_amdgcn_mfma_f32_16x16x32_bf16(af1, bf1, acc[3], 0, 0, 0);
      acc[4] = __builtin_amdgcn_mfma_f32_16x16x32_bf16(af2, bf0, acc[4], 0, 0, 0);
      acc[5] = __builtin_amdgcn_mfma_f32_16x16x32_bf16(af2, bf1, acc[5], 0, 0, 0);
      acc[6] = __builtin_amdgcn_mfma_f32_16x16x32_bf16(af3, bf0, acc[6], 0, 0, 0);
      acc[7] = __builtin_amdgcn_mfma_f32_16x16x32_bf16(af3, bf1, acc[7], 0, 0, 0);
    }
    __syncthreads();
  }
  if (!zblk) {
#pragma unroll
    for (int m = 0; m < 2; m++)
#pragma unroll
      for (int n = 0; n < 4; n++)
#pragma unroll
        for (int r = 0; r < 4; r++) {
          int e = e0 + wv * 32 + m * 16 + rbase + r;
          int l = l0 + n * 16 + rlo;
          xzs[((size_t)b * DN + e) * LL + l] = f2bf(acc[m * 4 + n][r]);
        }
  } else {
#pragma unroll
    for (int m = 0; m < 4; m++)
#pragma unroll
      for (int n = 0; n < 2; n++)
#pragma unroll
        for (int r = 0; r < 4; r++) {
          int l = l0 + m * 16 + rbase + r;
          int d = (e0 - DN) + wv * 32 + n * 16 + rlo;
          zts[((size_t)b * LL + l) * DN + d] = f2bf(fsilu(acc[m * 2 + n][r]));
        }
  }
}

// ---------------------------------------------------------------------------
// conv (both streams): grid ((LL/32)*4, BB, 4): z = str*2 + rev.
// ---------------------------------------------------------------------------
__global__ __launch_bounds__(256) void conv_kernel(
    const unsigned short* __restrict__ xz,
    const float* __restrict__ cw_af, const float* __restrict__ cb_af,
    const float* __restrict__ cw_ar, const float* __restrict__ cb_ar,
    const float* __restrict__ cw_vf, const float* __restrict__ cb_vf,
    const float* __restrict__ cw_vr, const float* __restrict__ cb_vr,
    unsigned short* __restrict__ u) {
  __shared__ float xt[128][33];
  const int slab = blockIdx.z;      // str*2 + rev
  const int rev = slab & 1;
  const int str = slab >> 1;
  const int b = blockIdx.y;
  const int dc0 = (blockIdx.x & 3) * 128;
  const int l0 = (blockIdx.x >> 2) * 32;
  const int tid = threadIdx.x;
  const int lc = tid & 31;
  const int dg = tid >> 5;
  const int l = l0 + lc;
  const float* conv_w = str ? (rev ? cw_vr : cw_vf) : (rev ? cw_ar : cw_af);
  const float* conv_b = str ? (rev ? cb_vr : cb_vf) : (rev ? cb_ar : cb_af);
  const unsigned short* xzs = xz + (size_t)str * SZC;
  unsigned short* u_out = u + (size_t)slab * SZC;

#pragma unroll
  for (int i = 0; i < 16; i++) {
    int dloc = dg * 16 + i;
    int dd = dc0 + dloc;
    const unsigned short* base = xzs + ((size_t)b * DN + dd) * LL;
    float4 cw4 = *(const float4*)(conv_w + dd * 4);
    float a0 = conv_b[dd];
    if (rev) {
      a0 = fmaf(cw4.w, bf2f(base[l]), a0);
      if (l + 1 < LL) a0 = fmaf(cw4.z, bf2f(base[l + 1]), a0);
      if (l + 2 < LL) a0 = fmaf(cw4.y, bf2f(base[l + 2]), a0);
      if (l + 3 < LL) a0 = fmaf(cw4.x, bf2f(base[l + 3]), a0);
    } else {
      a0 = fmaf(cw4.w, bf2f(base[l]), a0);
      if (l - 1 >= 0) a0 = fmaf(cw4.z, bf2f(base[l - 1]), a0);
      if (l - 2 >= 0) a0 = fmaf(cw4.y, bf2f(base[l - 2]), a0);
      if (l - 3 >= 0) a0 = fmaf(cw4.x, bf2f(base[l - 3]), a0);
    }
    xt[dloc][lc] = fsilu(a0);
  }
  __syncthreads();
#pragma unroll
  for (int j = 0; j < 8; j++) {
    int idx = j * 256 + tid;
    int d2 = idx & 63;
    int l2 = idx >> 6;
    ushort2v v;
    v[0] = f2bf(xt[2 * d2][l2]);
    v[1] = f2bf(xt[2 * d2 + 1][l2]);
    *(ushort2v*)&u_out[((size_t)b * LL + l0 + l2) * DN + dc0 + 2 * d2] = v;
  }
}

// ---------------------------------------------------------------------------
// prep: convert all 4 x_w matrices to bf16 slabs.
// ---------------------------------------------------------------------------
__global__ __launch_bounds__(256) void xw_prep_kernel(
    const float* __restrict__ a_f, const float* __restrict__ a_r,
    const float* __restrict__ v_f, const float* __restrict__ v_r,
    unsigned short* __restrict__ o) {
  int i = blockIdx.x * 256 + threadIdx.x;
  if (i < XWSL) {
    o[i] = f2bf(a_f[i]);
    o[i + XWSL] = f2bf(a_r[i]);
    o[i + 2 * XWSL] = f2bf(v_f[i]);
    o[i + 3 * XWSL] = f2bf(v_r[i]);
  }
}

// ---------------------------------------------------------------------------
// xdbl (both streams): grid (NLT, BB, 4): z = str*2 + rev.
// ---------------------------------------------------------------------------
__global__ __launch_bounds__(256) void xdbl_kernel(
    const unsigned short* __restrict__ u, const unsigned short* __restrict__ xwbf,
    float* __restrict__ dtv_g, float* __restrict__ Bb, float* __restrict__ Cb) {
  __shared__ __align__(16) unsigned short ub[4][16][136];
  __shared__ float red[4][48][17];
  const int slab = blockIdx.z;
  const int b = blockIdx.y;
  const int lt = blockIdx.x;
  const int l0 = lt * 16;
  const int tid = threadIdx.x;
  const int lane = tid & 63;
  const int w = tid >> 6;
  const int rlo = lane & 15;
  const int hi4 = lane >> 4;
  const int kseg = hi4 * 8;

  const unsigned short* up = u + (size_t)slab * SZC + ((size_t)b * LL + l0) * DN;
  const unsigned short* xwb = xwbf + (size_t)slab * XWSL;
  float* B_out = Bb + (size_t)slab * NSZC;
  float* C_out = Cb + (size_t)slab * NSZC;

#pragma unroll
  for (int j = 0; j < 4; j++) {
    int idx = j * 256 + tid;
    int l2 = idx >> 6;
    int c8 = idx & 63;
    ushort8 v = *(const ushort8*)(up + (size_t)l2 * DN + c8 * 8);
    *(ushort8*)&ub[c8 >> 4][l2][(c8 & 15) * 8] = v;
  }
  __syncthreads();

  f32x4 am0 = (f32x4){0.f, 0.f, 0.f, 0.f};
  f32x4 am1 = (f32x4){0.f, 0.f, 0.f, 0.f};
  f32x4 am2 = (f32x4){0.f, 0.f, 0.f, 0.f};
#pragma unroll
  for (int ks = 0; ks < 4; ks++) {
    bf16x8 bfrag = *(bf16x8*)&ub[w][rlo][ks * 32 + kseg];
    const unsigned short* xp = xwb + (size_t)(w * 128 + ks * 32 + kseg);
    bf16x8 a0 = *(const bf16x8*)(xp + (size_t)(0 + rlo) * 512);
    bf16x8 a1 = *(const bf16x8*)(xp + (size_t)(16 + rlo) * 512);
    bf16x8 a2 = *(const bf16x8*)(xp + (size_t)(32 + rlo) * 512);
    am0 = __builtin_amdgcn_mfma_f32_16x16x32_bf16(a0, bfrag, am0, 0, 0, 0);
    am1 = __builtin_amdgcn_mfma_f32_16x16x32_bf16(a1, bfrag, am1, 0, 0, 0);
    am2 = __builtin_amdgcn_mfma_f32_16x16x32_bf16(a2, bfrag, am2, 0, 0, 0);
  }
  {
    const int rbase = hi4 * 4;
#pragma unroll
    for (int r = 0; r < 4; r++) red[w][0 + rbase + r][rlo] = am0[r];
#pragma unroll
    for (int r = 0; r < 4; r++) red[w][16 + rbase + r][rlo] = am1[r];
#pragma unroll
    for (int r = 0; r < 4; r++) red[w][32 + rbase + r][rlo] = am2[r];
  }
  __syncthreads();
  float* dtvp = dtv_g + (((size_t)slab * BB + b) * NLT + lt) * 256;
#pragma unroll
  for (int i = 0; i < 3; i++) {
    int o = i * 256 + tid;
    int row = o >> 4, col = o & 15;
    float s = (red[0][row][col] + red[1][row][col]) +
              (red[2][row][col] + red[3][row][col]);
    if (row < 16)
      dtvp[(size_t)row * 16 + col] = s;
    else if (row < 32)
      B_out[((size_t)b * LL + l0 + col) * NS + (row - 16)] = s;
    else
      C_out[((size_t)b * LL + l0 + col) * NS + (row - 32)] = s;
  }
}

// ---------------------------------------------------------------------------
// delta (both streams): dtv transposed in LDS [l2][k]; b128 broadcast reads.
// ---------------------------------------------------------------------------
__global__ __launch_bounds__(256) void delta_kernel(
    const float* __restrict__ dtv_g,
    const float* __restrict__ dtw_af, const float* __restrict__ dtb_af,
    const float* __restrict__ dtw_ar, const float* __restrict__ dtb_ar,
    const float* __restrict__ dtw_vf, const float* __restrict__ dtb_vf,
    const float* __restrict__ dtw_vr, const float* __restrict__ dtb_vr,
    float* __restrict__ dl) {
  __shared__ __align__(16) float dtvT[16][20];
  const int slab = blockIdx.z;
  const int rev = slab & 1;
  const int str = slab >> 1;
  const int b = blockIdx.y;
  const int lt = blockIdx.x;
  const int l0 = lt * 16;
  const int tid = threadIdx.x;
  const float* dt_w = str ? (rev ? dtw_vr : dtw_vf) : (rev ? dtw_ar : dtw_af);
  const float* dt_b = str ? (rev ? dtb_vr : dtb_vf) : (rev ? dtb_ar : dtb_af);
  float* dl_out = dl + (size_t)slab * SZC;

  {
    const float* dtvp = dtv_g + (((size_t)slab * BB + b) * NLT + lt) * 256;
    float v = dtvp[tid];  // tid = k*16 + l
    dtvT[tid & 15][tid >> 4] = v;
  }
  __syncthreads();

  const int dd0 = tid, dd1 = tid + 256;
  const float4* wr0 = (const float4*)(dt_w + (size_t)dd0 * RK);
  const float4* wr1 = (const float4*)(dt_w + (size_t)dd1 * RK);
  float4 a_0 = wr0[0], a_1 = wr0[1], a_2 = wr0[2], a_3 = wr0[3];
  float4 b_0 = wr1[0], b_1 = wr1[1], b_2 = wr1[2], b_3 = wr1[3];
  float bias0 = dt_b[dd0], bias1 = dt_b[dd1];

#pragma unroll
  for (int l2 = 0; l2 < 16; l2++) {
    float4 q0 = *(const float4*)&dtvT[l2][0];
    float4 q1 = *(const float4*)&dtvT[l2][4];
    float4 q2 = *(const float4*)&dtvT[l2][8];
    float4 q3 = *(const float4*)&dtvT[l2][12];
    float s0 = bias0, s1 = bias1;
    s0 = fmaf(a_0.x, q0.x, s0); s1 = fmaf(b_0.x, q0.x, s1);
    s0 = fmaf(a_0.y, q0.y, s0); s1 = fmaf(b_0.y, q0.y, s1);
    s0 = fmaf(a_0.z, q0.z, s0); s1 = fmaf(b_0.z, q0.z, s1);
    s0 = fmaf(a_0.w, q0.w, s0); s1 = fmaf(b_0.w, q0.w, s1);
    s0 = fmaf(a_1.x, q1.x, s0); s1 = fmaf(b_1.x, q1.x, s1);
    s0 = fmaf(a_1.y, q1.y, s0); s1 = fmaf(b_1.y, q1.y, s1);
    s0 = fmaf(a_1.z, q1.z, s0); s1 = fmaf(b_1.z, q1.z, s1);
    s0 = fmaf(a_1.w, q1.w, s0); s1 = fmaf(b_1.w, q1.w, s1);
    s0 = fmaf(a_2.x, q2.x, s0); s1 = fmaf(b_2.x, q2.x, s1);
    s0 = fmaf(a_2.y, q2.y, s0); s1 = fmaf(b_2.y, q2.y, s1);
    s0 = fmaf(a_2.z, q2.z, s0); s1 = fmaf(b_2.z, q2.z, s1);
    s0 = fmaf(a_2.w, q2.w, s0); s1 = fmaf(b_2.w, q2.w, s1);
    s0 = fmaf(a_3.x, q3.x, s0); s1 = fmaf(b_3.x, q3.x, s1);
    s0 = fmaf(a_3.y, q3.y, s0); s1 = fmaf(b_3.y, q3.y, s1);
    s0 = fmaf(a_3.z, q3.z, s0); s1 = fmaf(b_3.z, q3.z, s1);
    s0 = fmaf(a_3.w, q3.w, s0); s1 = fmaf(b_3.w, q3.w, s1);
    float* rowp = dl_out + ((size_t)b * LL + l0 + l2) * DN;
    rowp[dd0] = fsoftplus_fast(s0);
    rowp[dd1] = fsoftplus_fast(s1);
  }
}

// ---------------------------------------------------------------------------
// Scan (both streams, LDS-staged). FAST PATH: the reference's A_log is
// log(arange(1..16)) broadcast, so Av[n] = -(n+1) exactly and
// exp(dl*Av[n]) = E^(n+1) with E = exp(-dl): 1 exp + 15 muls per step
// instead of 16 exps (quarter-rate trans). Guarded by a runtime check;
// falls back to the exact per-n exp path if the pattern doesn't hold.
// ---------------------------------------------------------------------------
#define HSTEP(n, Ecomp, Bcomp, Ccomp)               \
  {                                                 \
    h[n] = fmaf((Ecomp), h[n], dlu * (Bcomp));      \
    if (PHASE == 3) acc = fmaf(h[n], (Ccomp), acc); \
  }

template <int PHASE>
__global__ __launch_bounds__(256) void scan_kernel(
    unsigned short* __restrict__ u, const float* __restrict__ dl,
    const unsigned short* __restrict__ z_t, const float* __restrict__ Bb,
    const float* __restrict__ Cb, const float* __restrict__ A_log,
    const float* __restrict__ Ab_log,
    const float* __restrict__ D_af, const float* __restrict__ D_ar,
    const float* __restrict__ D_vf, const float* __restrict__ D_vr,
    unsigned short* __restrict__ hend, float* __restrict__ sumdl) {
  __shared__ unsigned short us[CL2][256];
  __shared__ unsigned short zs[CL2][256];
  __shared__ float dls[CL2][256];
  __shared__ float Bs[CL2][16];
  __shared__ float Cs[CL2][16];
  const int tid = threadIdx.x;
  const int str = blockIdx.y;
  const int ch0 = (blockIdx.x & 15) * 256;
  const int chunk = blockIdx.x >> 4;
  const int ch = ch0 + tid;
  const bool rev = ch0 >= BB * DN;
  const int slab = str * 2 + (rev ? 1 : 0);
  const int cid0 = rev ? ch0 - BB * DN : ch0;
  const int b = cid0 >> 9;
  const int d0 = cid0 & (DN - 1);
  const int d = d0 + tid;

  const float* Arow = (rev ? Ab_log : A_log) + d * NS;
  float Av[NS];
#pragma unroll
  for (int n = 0; n < NS; n++) Av[n] = -__expf(Arow[n]);
  bool fastA = true;
#pragma unroll
  for (int n = 0; n < NS; n++)
    if (fabsf(Av[n] + (float)(n + 1)) > 1e-4f * (float)(n + 1)) fastA = false;
  const float* Dsel = str ? (rev ? D_vr : D_vf) : (rev ? D_ar : D_af);
  const float Dd = Dsel[d];

  const int tlo = rev ? (LL - CL2 * (chunk + 1)) : (CL2 * chunk);
  unsigned short* uyb = u + (size_t)slab * SZC + ((size_t)b * LL + tlo) * DN + d0;
  const float* dlb = dl + (size_t)slab * SZC + ((size_t)b * LL + tlo) * DN + d0;
  const unsigned short* zb = z_t + (size_t)str * SZC + ((size_t)b * LL + tlo) * DN + d0;
  const float* Bp = Bb + (size_t)slab * NSZC + ((size_t)b * LL + tlo) * NS;
  const float* Cp = Cb + (size_t)slab * NSZC + ((size_t)b * LL + tlo) * NS;
  unsigned short* hendp = hend + (size_t)str * HSZC;
  float* sumdlp = sumdl + (size_t)str * NC2 * G2C;

  // ---- stage the whole chunk tile ----
  {
    const int lane = tid & 63;
    const int w = tid >> 6;
#pragma unroll
    for (int j4 = 0; j4 < 4; j4++) {
      int row = w * 4 + j4;
      ushort4v uu = *(const ushort4v*)(uyb + (size_t)row * DN + lane * 4);
      *(ushort4v*)&us[row][lane * 4] = uu;
      float4 dd4 = *(const float4*)(dlb + (size_t)row * DN + lane * 4);
      *(float4*)&dls[row][lane * 4] = dd4;
      if (PHASE == 3) {
        ushort4v zz = *(const ushort4v*)(zb + (size_t)row * DN + lane * 4);
        *(ushort4v*)&zs[row][lane * 4] = zz;
      }
    }
    Bs[tid >> 4][tid & 15] = Bp[(size_t)(tid >> 4) * NS + (tid & 15)];
    if (PHASE == 3) Cs[tid >> 4][tid & 15] = Cp[(size_t)(tid >> 4) * NS + (tid & 15)];
  }

  float h[NS];
  if (PHASE == 3) {
    const unsigned short* hp = hendp + ((size_t)chunk * G2C + ch) * NS;
#pragma unroll
    for (int n = 0; n < NS; n++) h[n] = bf2f(hp[n]);
  } else {
#pragma unroll
    for (int n = 0; n < NS; n++) h[n] = 0.f;
  }
  __syncthreads();

  float sdl = 0.f;
  if (fastA) {
#pragma unroll
    for (int jj = 0; jj < CL2; jj++) {
      const int j = rev ? (CL2 - 1 - jj) : jj;
      const float uc = bf2f(us[j][tid]);
      const float dc = dls[j][tid];
      const float4 Bq0 = *(const float4*)&Bs[j][0];
      const float4 Bq1 = *(const float4*)&Bs[j][4];
      const float4 Bq2 = *(const float4*)&Bs[j][8];
      const float4 Bq3 = *(const float4*)&Bs[j][12];
      float4 Cq0 = {0, 0, 0, 0}, Cq1 = {0, 0, 0, 0}, Cq2 = {0, 0, 0, 0},
             Cq3 = {0, 0, 0, 0};
      if (PHASE == 3) {
        Cq0 = *(const float4*)&Cs[j][0];
        Cq1 = *(const float4*)&Cs[j][4];
        Cq2 = *(const float4*)&Cs[j][8];
        Cq3 = *(const float4*)&Cs[j][12];
      }
      const float dlu = dc * uc;
      // powers of E = exp(-dc): e_n = E^(n+1), log-depth chain
      const float p1 = __expf(-dc);
      const float p2 = p1 * p1;
      const float p4 = p2 * p2;
      const float p8 = p4 * p4;
      const float p3 = p2 * p1;
      const float p5 = p4 * p1, p6 = p4 * p2, p7 = p4 * p3;
      const float p9 = p8 * p1, p10 = p8 * p2, p11 = p8 * p3, p12 = p8 * p4;
      const float p13 = p8 * p5, p14 = p8 * p6, p15 = p8 * p7, p16 = p8 * p8;
      float acc = 0.f;
      HSTEP(0, p1, Bq0.x, Cq0.x)   HSTEP(1, p2, Bq0.y, Cq0.y)
      HSTEP(2, p3, Bq0.z, Cq0.z)   HSTEP(3, p4, Bq0.w, Cq0.w)
      HSTEP(4, p5, Bq1.x, Cq1.x)   HSTEP(5, p6, Bq1.y, Cq1.y)
      HSTEP(6, p7, Bq1.z, Cq1.z)   HSTEP(7, p8, Bq1.w, Cq1.w)
      HSTEP(8, p9, Bq2.x, Cq2.x)   HSTEP(9, p10, Bq2.y, Cq2.y)
      HSTEP(10, p11, Bq2.z, Cq2.z) HSTEP(11, p12, Bq2.w, Cq2.w)
      HSTEP(12, p13, Bq3.x, Cq3.x) HSTEP(13, p14, Bq3.y, Cq3.y)
      HSTEP(14, p15, Bq3.z, Cq3.z) HSTEP(15, p16, Bq3.w, Cq3.w)
      if (PHASE == 1) sdl += dc;
      if (PHASE == 3) {
        const float zc = bf2f(zs[j][tid]);
        float y = fmaf(uc, Dd, acc) * zc;
        uyb[(size_t)j * DN + tid] = f2bf(y);
      }
    }
  } else {
#pragma unroll
    for (int jj = 0; jj < CL2; jj++) {
      const int j = rev ? (CL2 - 1 - jj) : jj;
      const float uc = bf2f(us[j][tid]);
      const float dc = dls[j][tid];
      const float4 Bq0 = *(const float4*)&Bs[j][0];
      const float4 Bq1 = *(const float4*)&Bs[j][4];
      const float4 Bq2 = *(const float4*)&Bs[j][8];
      const float4 Bq3 = *(const float4*)&Bs[j][12];
      float4 Cq0 = {0, 0, 0, 0}, Cq1 = {0, 0, 0, 0}, Cq2 = {0, 0, 0, 0},
             Cq3 = {0, 0, 0, 0};
      if (PHASE == 3) {
        Cq0 = *(const float4*)&Cs[j][0];
        Cq1 = *(const float4*)&Cs[j][4];
        Cq2 = *(const float4*)&Cs[j][8];
        Cq3 = *(const float4*)&Cs[j][12];
      }
      const float dlu = dc * uc;
      float acc = 0.f;
      HSTEP(0, __expf(dc * Av[0]), Bq0.x, Cq0.x)
      HSTEP(1, __expf(dc * Av[1]), Bq0.y, Cq0.y)
      HSTEP(2, __expf(dc * Av[2]), Bq0.z, Cq0.z)
      HSTEP(3, __expf(dc * Av[3]), Bq0.w, Cq0.w)
      HSTEP(4, __expf(dc * Av[4]), Bq1.x, Cq1.x)
      HSTEP(5, __expf(dc * Av[5]), Bq1.y, Cq1.y)
      HSTEP(6, __expf(dc * Av[6]), Bq1.z, Cq1.z)
      HSTEP(7, __expf(dc * Av[7]), Bq1.w, Cq1.w)
      HSTEP(8, __expf(dc * Av[8]), Bq2.x, Cq2.x)
      HSTEP(9, __expf(dc * Av[9]), Bq2.y, Cq2.y)
      HSTEP(10, __expf(dc * Av[10]), Bq2.z, Cq2.z)
      HSTEP(11, __expf(dc * Av[11]), Bq2.w, Cq2.w)
      HSTEP(12, __expf(dc * Av[12]), Bq3.x, Cq3.x)
      HSTEP(13, __expf(dc * Av[13]), Bq3.y, Cq3.y)
      HSTEP(14, __expf(dc * Av[14]), Bq3.z, Cq3.z)
      HSTEP(15, __expf(dc * Av[15]), Bq3.w, Cq3.w)
      if (PHASE == 1) sdl += dc;
      if (PHASE == 3) {
        const float zc = bf2f(zs[j][tid]);
        float y = fmaf(uc, Dd, acc) * zc;
        uyb[(size_t)j * DN + tid] = f2bf(y);
      }
    }
  }
  if (PHASE == 1) {
    unsigned short* hp = hendp + ((size_t)chunk * G2C + ch) * NS;
#pragma unroll
    for (int n = 0; n < NS; n++) hp[n] = f2bf(h[n]);
    sumdlp[(size_t)chunk * G2C + ch] = sdl;
  }
}
#undef HSTEP

// ---------------------------------------------------------------------------
// Phase 2 (both streams): grid (G2C/16, 2).
// ---------------------------------------------------------------------------
__global__ __launch_bounds__(256) void scan_combine_kernel(
    const float* __restrict__ A_log, const float* __restrict__ Ab_log,
    unsigned short* __restrict__ hend, const float* __restrict__ sumdl) {
  __shared__ float tile[8][256];
  __shared__ float sd[8][16];
  const int tid = threadIdx.x;
  const int str = blockIdx.y;
  const int ch0 = blockIdx.x * 16;
  const int chl = tid >> 4;
  const int n = tid & 15;
  const int ch = ch0 + chl;
  const bool rev = ch >= BB * DN;
  const int d = ch & (DN - 1);
  const float Av = -__expf((rev ? Ab_log : A_log)[d * NS + n]);
  unsigned short* hendp = hend + (size_t)str * HSZC;
  const float* sumdlp = sumdl + (size_t)str * NC2 * G2C;
  float H = 0.f;
  for (int cb = 0; cb < NC2 / 8; cb++) {
#pragma unroll
    for (int j = 0; j < 8; j++)
      tile[j][tid] = bf2f(hendp[((size_t)(cb * 8 + j) * G2C + ch0) * NS + tid]);
    if (tid < 128) {
      int j = tid >> 4, k = tid & 15;
      sd[j][k] = sumdlp[(size_t)(cb * 8 + j) * G2C + ch0 + k];
    }
    __syncthreads();
#pragma unroll
    for (int j = 0; j < 8; j++) {
      float tmp = tile[j][tid];
      tile[j][tid] = H;
      H = fmaf(__expf(Av * sd[j][chl]), H, tmp);
    }
    __syncthreads();
#pragma unroll
    for (int j = 0; j < 8; j++)
      hendp[((size_t)(cb * 8 + j) * G2C + ch0) * NS + tid] = f2bf(tile[j][tid]);
    __syncthreads();
  }
}

// ---------------------------------------------------------------------------
// out_proj (both streams): grid (32, 4, BB*2).
// ---------------------------------------------------------------------------
__global__ __launch_bounds__(256) void out_proj_mfma(
    const unsigned short* __restrict__ u,
    const float* __restrict__ ow_a, const float* __restrict__ ow_v,
    float* __restrict__ outp) {
  __shared__ unsigned short yt[64][40];
  __shared__ unsigned short wo[64][40];
  const int bz = blockIdx.z;
  const int b = bz & 3;
  const int str = bz >> 2;
  const float* ow = str ? ow_v : ow_a;
  const unsigned short* yf = u + (size_t)(str * 2) * SZC;
  const unsigned short* yr = u + (size_t)(str * 2 + 1) * SZC;
  float* outs = outp + (size_t)str * BB * LL * DM;
  const int m0 = blockIdx.y * 64;
  const int l0 = blockIdx.x * 64;
  const int tid = threadIdx.x;
  const int lane = tid & 63;
  const int wid = tid >> 6;
  const int wm = wid >> 1, wn = wid & 1;
  const int krow = (lane >> 4) * 8;
  const int rlo = lane & 15;

  f32x4 acc[2][2];
#pragma unroll
  for (int i = 0; i < 2; i++)
#pragma unroll
    for (int j = 0; j < 2; j++) acc[i][j] = (f32x4){0.f, 0.f, 0.f, 0.f};

  for (int dk = 0; dk < DN; dk += 32) {
    {
      int row = tid >> 2;
      int seg = (tid & 3) * 8;
      ushort8 a = *(const ushort8*)(yf + ((size_t)b * LL + l0 + row) * DN + dk + seg);
      ushort8 c = *(const ushort8*)(yr + ((size_t)b * LL + l0 + row) * DN + dk + seg);
      ushort8 yv;
#pragma unroll
      for (int k = 0; k < 8; k++) yv[k] = f2bf(0.5f * (bf2f(a[k]) + bf2f(c[k])));
      *(ushort8*)&yt[row][seg] = yv;
      const float* wp = ow + (size_t)(m0 + row) * DN + dk + seg;
      float4 w0 = *(const float4*)wp, w1 = *(const float4*)(wp + 4);
      ushort8 wv;
      wv[0] = f2bf(w0.x); wv[1] = f2bf(w0.y); wv[2] = f2bf(w0.z); wv[3] = f2bf(w0.w);
      wv[4] = f2bf(w1.x); wv[5] = f2bf(w1.y); wv[6] = f2bf(w1.z); wv[7] = f2bf(w1.w);
      *(ushort8*)&wo[row][seg] = wv;
    }
    __syncthreads();
    bf16x8 a0 = *(bf16x8*)&yt[wm * 32 + rlo][krow];
    bf16x8 a1 = *(bf16x8*)&yt[wm * 32 + 16 + rlo][krow];
    bf16x8 b0 = *(bf16x8*)&wo[wn * 32 + rlo][krow];
    bf16x8 b1 = *(bf16x8*)&wo[wn * 32 + 16 + rlo][krow];
    acc[0][0] = __builtin_amdgcn_mfma_f32_16x16x32_bf16(a0, b0, acc[0][0], 0, 0, 0);
    acc[0][1] = __builtin_amdgcn_mfma_f32_16x16x32_bf16(a0, b1, acc[0][1], 0, 0, 0);
    acc[1][0] = __builtin_amdgcn_mfma_f32_16x16x32_bf16(a1, b0, acc[1][0], 0, 0, 0);
    acc[1][1] = __builtin_amdgcn_mfma_f32_16x16x32_bf16(a1, b1, acc[1][1], 0, 0, 0);
    __syncthreads();
  }
#pragma unroll
  for (int mt = 0; mt < 2; mt++)
#pragma unroll
    for (int nt = 0; nt < 2; nt++)
#pragma unroll
      for (int r = 0; r < 4; r++) {
        int l = l0 + wm * 32 + mt * 16 + (lane >> 4) * 4 + r;
        int m = m0 + wn * 32 + nt * 16 + rlo;
        outs[((size_t)b * LL + l) * DM + m] = acc[mt][nt][r];
      }
}

// ---------------------------------------------------------------------------
extern "C" void kernel_launch(void* const* d_in, const int* in_sizes, int n_in,
                              void* d_out, int out_size, void* d_ws, size_t ws_size,
                              hipStream_t stream) {
  (void)in_sizes; (void)n_in; (void)out_size; (void)ws_size;
  const float* A_log = (const float*)d_in[2];
  const float* Ab_log = (const float*)d_in[3];
  const float* h_a = (const float*)d_in[0];
  const float* h_v = (const float*)d_in[1];
#define AP(i) ((const float*)d_in[4 + (i)])
#define VP(i) ((const float*)d_in[18 + (i)])

  float* ws = (float*)d_ws;
  float* dl = ws;                                   // 4*SZC fp32
  float* Bb = dl + 4 * SZC;                         // 4*NSZC
  float* Cb = Bb + 4 * NSZC;                        // 4*NSZC
  float* sumdl = Cb + 4 * NSZC;                     // 2*NC2*G2C
  float* dtv_g = sumdl + (size_t)2 * NC2 * G2C;     // 4*BB*NLT*256 = 524,288
  unsigned short* xwbf = (unsigned short*)(dtv_g + (size_t)4 * BB * NLT * 256);
  unsigned short* z_t = xwbf + 4 * XWSL;            // 2*SZC bf16
  unsigned short* u = z_t + 2 * SZC;                // 4*SZC bf16
  unsigned short* xz = u + 4 * SZC;                 // 2*SZC bf16
  unsigned short* hend = xz + 2 * SZC;              // 2*HSZC bf16

  hipLaunchKernelGGL(in_proj_mfma, dim3(LL / 64, EE / 128, BB * 2), dim3(256), 0,
                     stream, h_a, h_v, AP(0), VP(0), xz, z_t);
  hipLaunchKernelGGL(xw_prep_kernel, dim3(96), dim3(256), 0, stream,
                     AP(3), AP(9), VP(3), VP(9), xwbf);
  hipLaunchKernelGGL(conv_kernel, dim3((LL / 32) * 4, BB, 4), dim3(256), 0, stream,
                     xz, AP(1), AP(2), AP(7), AP(8), VP(1), VP(2), VP(7), VP(8), u);
  hipLaunchKernelGGL(xdbl_kernel, dim3(NLT, BB, 4), dim3(256), 0, stream,
                     u, xwbf, dtv_g, Bb, Cb);
  hipLaunchKernelGGL(delta_kernel, dim3(NLT, BB, 4), dim3(256), 0, stream,
                     dtv_g, AP(4), AP(5), AP(10), AP(11), VP(4), VP(5), VP(10),
                     VP(11), dl);
  hipLaunchKernelGGL(HIP_KERNEL_NAME(scan_kernel<1>), dim3(NC2 * 16, 2), dim3(256),
                     0, stream, u, dl, z_t, Bb, Cb, A_log, Ab_log, AP(6), AP(12),
                     VP(6), VP(12), hend, sumdl);
  hipLaunchKernelGGL(scan_combine_kernel, dim3(G2C / 16, 2), dim3(256), 0, stream,
                     A_log, Ab_log, hend, sumdl);
  hipLaunchKernelGGL(HIP_KERNEL_NAME(scan_kernel<3>), dim3(NC2 * 16, 2), dim3(256),
                     0, stream, u, dl, z_t, Bb, Cb, A_log, Ab_log, AP(6), AP(12),
                     VP(6), VP(12), hend, sumdl);
  hipLaunchKernelGGL(out_proj_mfma, dim3(LL / 64, DM / 64, BB * 2), dim3(256), 0,
                     stream, u, AP(13), VP(13), (float*)d_out);
#undef AP
#undef VP
}

// Round 22
// 224.568 us; speedup vs baseline: 1.6320x; 1.0094x over previous
//
#include <hip/hip_runtime.h>
#include <hip/hip_bf16.h>
#include <cstddef>

#define BB 4
#define LL 2048
#define DM 256
#define DN 512
#define EE 1024
#define NS 16
#define RK 16
#define NC2 128         // scan chunks
#define CL2 (LL / NC2)  // chunk length = 16
#define NLT (LL / 16)   // l-tiles for xdbl/delta = 128
#define G2C (2 * BB * DN)                       // 4096
#define SZC ((size_t)BB * LL * DN)              // 4,194,304
#define NSZC ((size_t)BB * LL * NS)             // 131,072
#define HSZC ((size_t)NC2 * G2C * NS)           // 8,388,608 (bf16 elems)
#define XWSL (48 * 512)                         // 24,576

typedef __attribute__((ext_vector_type(8))) short bf16x8;
typedef __attribute__((ext_vector_type(8))) unsigned short ushort8;
typedef __attribute__((ext_vector_type(4))) unsigned short ushort4v;
typedef __attribute__((ext_vector_type(2))) unsigned short ushort2v;
typedef __attribute__((ext_vector_type(4))) float f32x4;
typedef __attribute__((ext_vector_type(2))) float f32x2;

__device__ __forceinline__ float fsilu(float x) { return x / (1.0f + __expf(-x)); }
__device__ __forceinline__ float fsoftplus_fast(float x) {
  return x > 20.0f ? x : __logf(1.0f + __expf(x));
}
__device__ __forceinline__ unsigned short f2bf(float x) {  // RNE float->bf16
  union { float f; unsigned int u; } v; v.f = x;
  unsigned int r = v.u + 0x7fffu + ((v.u >> 16) & 1u);
  return (unsigned short)(r >> 16);
}
__device__ __forceinline__ float bf2f(unsigned short x) {
  union { unsigned int u; float f; } v; v.u = ((unsigned int)x) << 16;
  return v.f;
}

// ---------------------------------------------------------------------------
// in_proj (both streams). Tile 128e x 64l, grid (32, 8, BB*2).
// ---------------------------------------------------------------------------
__global__ __launch_bounds__(256) void in_proj_mfma(
    const float* __restrict__ h_a, const float* __restrict__ h_v,
    const float* __restrict__ w_a, const float* __restrict__ w_v,
    unsigned short* __restrict__ xz, unsigned short* __restrict__ z_t) {
  __shared__ unsigned short ht[64][40];   // [l][k] bf16
  __shared__ unsigned short wt[128][40];  // [e][k]
  const int bz = blockIdx.z;
  const int b = bz & 3;
  const int str = bz >> 2;
  const float* h = str ? h_v : h_a;
  const float* w = str ? w_v : w_a;
  unsigned short* xzs = xz + (size_t)str * SZC;
  unsigned short* zts = z_t + (size_t)str * SZC;
  const int e0 = blockIdx.y * 128;
  const int l0 = blockIdx.x * 64;
  const int tid = threadIdx.x;
  const int lane = tid & 63;
  const int wv = tid >> 6;
  const bool zblk = (e0 >= DN);
  const int krow = (lane >> 4) * 8;
  const int rlo = lane & 15;
  const int rbase = (lane >> 4) * 4;

  f32x4 acc[8];
#pragma unroll
  for (int i = 0; i < 8; i++) acc[i] = (f32x4){0.f, 0.f, 0.f, 0.f};

  for (int dk = 0; dk < DM; dk += 32) {
    {
      int row = tid >> 2;
      int seg = (tid & 3) * 8;
      const float* hp = h + ((size_t)b * LL + l0 + row) * DM + dk + seg;
      float4 ha = *(const float4*)hp, hb = *(const float4*)(hp + 4);
      ushort8 hv;
      hv[0] = f2bf(ha.x); hv[1] = f2bf(ha.y); hv[2] = f2bf(ha.z); hv[3] = f2bf(ha.w);
      hv[4] = f2bf(hb.x); hv[5] = f2bf(hb.y); hv[6] = f2bf(hb.z); hv[7] = f2bf(hb.w);
      *(ushort8*)&ht[row][seg] = hv;
    }
#pragma unroll
    for (int it = 0; it < 2; it++) {
      int idx = it * 256 + tid;
      int row = idx >> 2;
      int seg = (idx & 3) * 8;
      const float* wp = w + (size_t)(e0 + row) * DM + dk + seg;
      float4 wa = *(const float4*)wp, wb = *(const float4*)(wp + 4);
      ushort8 wv8;
      wv8[0] = f2bf(wa.x); wv8[1] = f2bf(wa.y); wv8[2] = f2bf(wa.z); wv8[3] = f2bf(wa.w);
      wv8[4] = f2bf(wb.x); wv8[5] = f2bf(wb.y); wv8[6] = f2bf(wb.z); wv8[7] = f2bf(wb.w);
      *(ushort8*)&wt[row][seg] = wv8;
    }
    __syncthreads();
    if (!zblk) {
      bf16x8 af0 = *(bf16x8*)&wt[wv * 32 + 0 * 16 + rlo][krow];
      bf16x8 af1 = *(bf16x8*)&wt[wv * 32 + 1 * 16 + rlo][krow];
      bf16x8 bf0 = *(bf16x8*)&ht[0 * 16 + rlo][krow];
      bf16x8 bf1 = *(bf16x8*)&ht[1 * 16 + rlo][krow];
      bf16x8 bf2 = *(bf16x8*)&ht[2 * 16 + rlo][krow];
      bf16x8 bf3 = *(bf16x8*)&ht[3 * 16 + rlo][krow];
      acc[0] = __builtin_amdgcn_mfma_f32_16x16x32_bf16(af0, bf0, acc[0], 0, 0, 0);
      acc[1] = __builtin_amdgcn_mfma_f32_16x16x32_bf16(af0, bf1, acc[1], 0, 0, 0);
      acc[2] = __builtin_amdgcn_mfma_f32_16x16x32_bf16(af0, bf2, acc[2], 0, 0, 0);
      acc[3] = __builtin_amdgcn_mfma_f32_16x16x32_bf16(af0, bf3, acc[3], 0, 0, 0);
      acc[4] = __builtin_amdgcn_mfma_f32_16x16x32_bf16(af1, bf0, acc[4], 0, 0, 0);
      acc[5] = __builtin_amdgcn_mfma_f32_16x16x32_bf16(af1, bf1, acc[5], 0, 0, 0);
      acc[6] = __builtin_amdgcn_mfma_f32_16x16x32_bf16(af1, bf2, acc[6], 0, 0, 0);
      acc[7] = __builtin_amdgcn_mfma_f32_16x16x32_bf16(af1, bf3, acc[7], 0, 0, 0);
    } else {
      bf16x8 af0 = *(bf16x8*)&ht[0 * 16 + rlo][krow];
      bf16x8 af1 = *(bf16x8*)&ht[1 * 16 + rlo][krow];
      bf16x8 af2 = *(bf16x8*)&ht[2 * 16 + rlo][krow];
      bf16x8 af3 = *(bf16x8*)&ht[3 * 16 + rlo][krow];
      bf16x8 bf0 = *(bf16x8*)&wt[wv * 32 + 0 * 16 + rlo][krow];
      bf16x8 bf1 = *(bf16x8*)&wt[wv * 32 + 1 * 16 + rlo][krow];
      acc[0] = __builtin_amdgcn_mfma_f32_16x16x32_bf16(af0, bf0, acc[0], 0, 0, 0);
      acc[1] = __builtin_amdgcn_mfma_f32_16x16x32_bf16(af0, bf1, acc[1], 0, 0, 0);
      acc[2] = __builtin_amdgcn_mfma_f32_16x16x32_bf16(af1, bf0, acc[2], 0, 0, 0);
      acc[3] = __builtin_amdgcn_mfma_f32_16x16x32_bf16(af1, bf1, acc[3], 0, 0, 0);
      acc[4] = __builtin_amdgcn_mfma_f32_16x16x32_bf16(af2, bf0, acc[4], 0, 0, 0);
      acc[5] = __builtin_amdgcn_mfma_f32_16x16x32_bf16(af2, bf1, acc[5], 0, 0, 0);
      acc[6] = __builtin_amdgcn_mfma_f32_16x16x32_bf16(af3, bf0, acc[6], 0, 0, 0);
      acc[7] = __builtin_amdgcn_mfma_f32_16x16x32_bf16(af3, bf1, acc[7], 0, 0, 0);
    }
    __syncthreads();
  }
  if (!zblk) {
#pragma unroll
    for (int m = 0; m < 2; m++)
#pragma unroll
      for (int n = 0; n < 4; n++)
#pragma unroll
        for (int r = 0; r < 4; r++) {
          int e = e0 + wv * 32 + m * 16 + rbase + r;
          int l = l0 + n * 16 + rlo;
          xzs[((size_t)b * DN + e) * LL + l] = f2bf(acc[m * 4 + n][r]);
        }
  } else {
#pragma unroll
    for (int m = 0; m < 4; m++)
#pragma unroll
      for (int n = 0; n < 2; n++)
#pragma unroll
        for (int r = 0; r < 4; r++) {
          int l = l0 + m * 16 + rbase + r;
          int d = (e0 - DN) + wv * 32 + n * 16 + rlo;
          zts[((size_t)b * LL + l) * DN + d] = f2bf(fsilu(acc[m * 2 + n][r]));
        }
  }
}

// ---------------------------------------------------------------------------
// conv (both streams): grid ((LL/32)*4, BB, 4): z = str*2 + rev.
// ---------------------------------------------------------------------------
__global__ __launch_bounds__(256) void conv_kernel(
    const unsigned short* __restrict__ xz,
    const float* __restrict__ cw_af, const float* __restrict__ cb_af,
    const float* __restrict__ cw_ar, const float* __restrict__ cb_ar,
    const float* __restrict__ cw_vf, const float* __restrict__ cb_vf,
    const float* __restrict__ cw_vr, const float* __restrict__ cb_vr,
    unsigned short* __restrict__ u) {
  __shared__ float xt[128][33];
  const int slab = blockIdx.z;      // str*2 + rev
  const int rev = slab & 1;
  const int str = slab >> 1;
  const int b = blockIdx.y;
  const int dc0 = (blockIdx.x & 3) * 128;
  const int l0 = (blockIdx.x >> 2) * 32;
  const int tid = threadIdx.x;
  const int lc = tid & 31;
  const int dg = tid >> 5;
  const int l = l0 + lc;
  const float* conv_w = str ? (rev ? cw_vr : cw_vf) : (rev ? cw_ar : cw_af);
  const float* conv_b = str ? (rev ? cb_vr : cb_vf) : (rev ? cb_ar : cb_af);
  const unsigned short* xzs = xz + (size_t)str * SZC;
  unsigned short* u_out = u + (size_t)slab * SZC;

#pragma unroll
  for (int i = 0; i < 16; i++) {
    int dloc = dg * 16 + i;
    int dd = dc0 + dloc;
    const unsigned short* base = xzs + ((size_t)b * DN + dd) * LL;
    float4 cw4 = *(const float4*)(conv_w + dd * 4);
    float a0 = conv_b[dd];
    if (rev) {
      a0 = fmaf(cw4.w, bf2f(base[l]), a0);
      if (l + 1 < LL) a0 = fmaf(cw4.z, bf2f(base[l + 1]), a0);
      if (l + 2 < LL) a0 = fmaf(cw4.y, bf2f(base[l + 2]), a0);
      if (l + 3 < LL) a0 = fmaf(cw4.x, bf2f(base[l + 3]), a0);
    } else {
      a0 = fmaf(cw4.w, bf2f(base[l]), a0);
      if (l - 1 >= 0) a0 = fmaf(cw4.z, bf2f(base[l - 1]), a0);
      if (l - 2 >= 0) a0 = fmaf(cw4.y, bf2f(base[l - 2]), a0);
      if (l - 3 >= 0) a0 = fmaf(cw4.x, bf2f(base[l - 3]), a0);
    }
    xt[dloc][lc] = fsilu(a0);
  }
  __syncthreads();
#pragma unroll
  for (int j = 0; j < 8; j++) {
    int idx = j * 256 + tid;
    int d2 = idx & 63;
    int l2 = idx >> 6;
    ushort2v v;
    v[0] = f2bf(xt[2 * d2][l2]);
    v[1] = f2bf(xt[2 * d2 + 1][l2]);
    *(ushort2v*)&u_out[((size_t)b * LL + l0 + l2) * DN + dc0 + 2 * d2] = v;
  }
}

// ---------------------------------------------------------------------------
// prep: convert all 4 x_w matrices to bf16 slabs.
// ---------------------------------------------------------------------------
__global__ __launch_bounds__(256) void xw_prep_kernel(
    const float* __restrict__ a_f, const float* __restrict__ a_r,
    const float* __restrict__ v_f, const float* __restrict__ v_r,
    unsigned short* __restrict__ o) {
  int i = blockIdx.x * 256 + threadIdx.x;
  if (i < XWSL) {
    o[i] = f2bf(a_f[i]);
    o[i + XWSL] = f2bf(a_r[i]);
    o[i + 2 * XWSL] = f2bf(v_f[i]);
    o[i + 3 * XWSL] = f2bf(v_r[i]);
  }
}

// ---------------------------------------------------------------------------
// xdbl (both streams): grid (NLT, BB, 4): z = str*2 + rev.
// ---------------------------------------------------------------------------
__global__ __launch_bounds__(256) void xdbl_kernel(
    const unsigned short* __restrict__ u, const unsigned short* __restrict__ xwbf,
    float* __restrict__ dtv_g, float* __restrict__ Bb, float* __restrict__ Cb) {
  __shared__ __align__(16) unsigned short ub[4][16][136];
  __shared__ float red[4][48][17];
  const int slab = blockIdx.z;
  const int b = blockIdx.y;
  const int lt = blockIdx.x;
  const int l0 = lt * 16;
  const int tid = threadIdx.x;
  const int lane = tid & 63;
  const int w = tid >> 6;
  const int rlo = lane & 15;
  const int hi4 = lane >> 4;
  const int kseg = hi4 * 8;

  const unsigned short* up = u + (size_t)slab * SZC + ((size_t)b * LL + l0) * DN;
  const unsigned short* xwb = xwbf + (size_t)slab * XWSL;
  float* B_out = Bb + (size_t)slab * NSZC;
  float* C_out = Cb + (size_t)slab * NSZC;

#pragma unroll
  for (int j = 0; j < 4; j++) {
    int idx = j * 256 + tid;
    int l2 = idx >> 6;
    int c8 = idx & 63;
    ushort8 v = *(const ushort8*)(up + (size_t)l2 * DN + c8 * 8);
    *(ushort8*)&ub[c8 >> 4][l2][(c8 & 15) * 8] = v;
  }
  __syncthreads();

  f32x4 am0 = (f32x4){0.f, 0.f, 0.f, 0.f};
  f32x4 am1 = (f32x4){0.f, 0.f, 0.f, 0.f};
  f32x4 am2 = (f32x4){0.f, 0.f, 0.f, 0.f};
#pragma unroll
  for (int ks = 0; ks < 4; ks++) {
    bf16x8 bfrag = *(bf16x8*)&ub[w][rlo][ks * 32 + kseg];
    const unsigned short* xp = xwb + (size_t)(w * 128 + ks * 32 + kseg);
    bf16x8 a0 = *(const bf16x8*)(xp + (size_t)(0 + rlo) * 512);
    bf16x8 a1 = *(const bf16x8*)(xp + (size_t)(16 + rlo) * 512);
    bf16x8 a2 = *(const bf16x8*)(xp + (size_t)(32 + rlo) * 512);
    am0 = __builtin_amdgcn_mfma_f32_16x16x32_bf16(a0, bfrag, am0, 0, 0, 0);
    am1 = __builtin_amdgcn_mfma_f32_16x16x32_bf16(a1, bfrag, am1, 0, 0, 0);
    am2 = __builtin_amdgcn_mfma_f32_16x16x32_bf16(a2, bfrag, am2, 0, 0, 0);
  }
  {
    const int rbase = hi4 * 4;
#pragma unroll
    for (int r = 0; r < 4; r++) red[w][0 + rbase + r][rlo] = am0[r];
#pragma unroll
    for (int r = 0; r < 4; r++) red[w][16 + rbase + r][rlo] = am1[r];
#pragma unroll
    for (int r = 0; r < 4; r++) red[w][32 + rbase + r][rlo] = am2[r];
  }
  __syncthreads();
  float* dtvp = dtv_g + (((size_t)slab * BB + b) * NLT + lt) * 256;
#pragma unroll
  for (int i = 0; i < 3; i++) {
    int o = i * 256 + tid;
    int row = o >> 4, col = o & 15;
    float s = (red[0][row][col] + red[1][row][col]) +
              (red[2][row][col] + red[3][row][col]);
    if (row < 16)
      dtvp[(size_t)row * 16 + col] = s;
    else if (row < 32)
      B_out[((size_t)b * LL + l0 + col) * NS + (row - 16)] = s;
    else
      C_out[((size_t)b * LL + l0 + col) * NS + (row - 32)] = s;
  }
}

// ---------------------------------------------------------------------------
// delta (both streams): dtv transposed in LDS [l2][k]; b128 broadcast reads.
// ---------------------------------------------------------------------------
__global__ __launch_bounds__(256) void delta_kernel(
    const float* __restrict__ dtv_g,
    const float* __restrict__ dtw_af, const float* __restrict__ dtb_af,
    const float* __restrict__ dtw_ar, const float* __restrict__ dtb_ar,
    const float* __restrict__ dtw_vf, const float* __restrict__ dtb_vf,
    const float* __restrict__ dtw_vr, const float* __restrict__ dtb_vr,
    float* __restrict__ dl) {
  __shared__ __align__(16) float dtvT[16][20];
  const int slab = blockIdx.z;
  const int rev = slab & 1;
  const int str = slab >> 1;
  const int b = blockIdx.y;
  const int lt = blockIdx.x;
  const int l0 = lt * 16;
  const int tid = threadIdx.x;
  const float* dt_w = str ? (rev ? dtw_vr : dtw_vf) : (rev ? dtw_ar : dtw_af);
  const float* dt_b = str ? (rev ? dtb_vr : dtb_vf) : (rev ? dtb_ar : dtb_af);
  float* dl_out = dl + (size_t)slab * SZC;

  {
    const float* dtvp = dtv_g + (((size_t)slab * BB + b) * NLT + lt) * 256;
    float v = dtvp[tid];  // tid = k*16 + l
    dtvT[tid & 15][tid >> 4] = v;
  }
  __syncthreads();

  const int dd0 = tid, dd1 = tid + 256;
  const float4* wr0 = (const float4*)(dt_w + (size_t)dd0 * RK);
  const float4* wr1 = (const float4*)(dt_w + (size_t)dd1 * RK);
  float4 a_0 = wr0[0], a_1 = wr0[1], a_2 = wr0[2], a_3 = wr0[3];
  float4 b_0 = wr1[0], b_1 = wr1[1], b_2 = wr1[2], b_3 = wr1[3];
  float bias0 = dt_b[dd0], bias1 = dt_b[dd1];

#pragma unroll
  for (int l2 = 0; l2 < 16; l2++) {
    float4 q0 = *(const float4*)&dtvT[l2][0];
    float4 q1 = *(const float4*)&dtvT[l2][4];
    float4 q2 = *(const float4*)&dtvT[l2][8];
    float4 q3 = *(const float4*)&dtvT[l2][12];
    float s0 = bias0, s1 = bias1;
    s0 = fmaf(a_0.x, q0.x, s0); s1 = fmaf(b_0.x, q0.x, s1);
    s0 = fmaf(a_0.y, q0.y, s0); s1 = fmaf(b_0.y, q0.y, s1);
    s0 = fmaf(a_0.z, q0.z, s0); s1 = fmaf(b_0.z, q0.z, s1);
    s0 = fmaf(a_0.w, q0.w, s0); s1 = fmaf(b_0.w, q0.w, s1);
    s0 = fmaf(a_1.x, q1.x, s0); s1 = fmaf(b_1.x, q1.x, s1);
    s0 = fmaf(a_1.y, q1.y, s0); s1 = fmaf(b_1.y, q1.y, s1);
    s0 = fmaf(a_1.z, q1.z, s0); s1 = fmaf(b_1.z, q1.z, s1);
    s0 = fmaf(a_1.w, q1.w, s0); s1 = fmaf(b_1.w, q1.w, s1);
    s0 = fmaf(a_2.x, q2.x, s0); s1 = fmaf(b_2.x, q2.x, s1);
    s0 = fmaf(a_2.y, q2.y, s0); s1 = fmaf(b_2.y, q2.y, s1);
    s0 = fmaf(a_2.z, q2.z, s0); s1 = fmaf(b_2.z, q2.z, s1);
    s0 = fmaf(a_2.w, q2.w, s0); s1 = fmaf(b_2.w, q2.w, s1);
    s0 = fmaf(a_3.x, q3.x, s0); s1 = fmaf(b_3.x, q3.x, s1);
    s0 = fmaf(a_3.y, q3.y, s0); s1 = fmaf(b_3.y, q3.y, s1);
    s0 = fmaf(a_3.z, q3.z, s0); s1 = fmaf(b_3.z, q3.z, s1);
    s0 = fmaf(a_3.w, q3.w, s0); s1 = fmaf(b_3.w, q3.w, s1);
    float* rowp = dl_out + ((size_t)b * LL + l0 + l2) * DN;
    rowp[dd0] = fsoftplus_fast(s0);
    rowp[dd1] = fsoftplus_fast(s1);
  }
}

// ---------------------------------------------------------------------------
// Scan (both streams, LDS-staged). Fast-A path (Av[n] = -(n+1)) now uses
// PACKED fp32 (v_pk_fma_f32): h-states as 8 f32x2 pairs, powers-of-E chain
// as 7 packed muls, 3 packed ops per 2 states. Fallback exact path kept.
// ---------------------------------------------------------------------------
template <int PHASE>
__global__ __launch_bounds__(256) void scan_kernel(
    unsigned short* __restrict__ u, const float* __restrict__ dl,
    const unsigned short* __restrict__ z_t, const float* __restrict__ Bb,
    const float* __restrict__ Cb, const float* __restrict__ A_log,
    const float* __restrict__ Ab_log,
    const float* __restrict__ D_af, const float* __restrict__ D_ar,
    const float* __restrict__ D_vf, const float* __restrict__ D_vr,
    unsigned short* __restrict__ hend, float* __restrict__ sumdl) {
  __shared__ unsigned short us[CL2][256];
  __shared__ unsigned short zs[CL2][256];
  __shared__ float dls[CL2][256];
  __shared__ __align__(16) float Bs[CL2][16];
  __shared__ __align__(16) float Cs[CL2][16];
  const int tid = threadIdx.x;
  const int str = blockIdx.y;
  const int ch0 = (blockIdx.x & 15) * 256;
  const int chunk = blockIdx.x >> 4;
  const int ch = ch0 + tid;
  const bool rev = ch0 >= BB * DN;
  const int slab = str * 2 + (rev ? 1 : 0);
  const int cid0 = rev ? ch0 - BB * DN : ch0;
  const int b = cid0 >> 9;
  const int d0 = cid0 & (DN - 1);
  const int d = d0 + tid;

  const float* Arow = (rev ? Ab_log : A_log) + d * NS;
  float Av[NS];
#pragma unroll
  for (int n = 0; n < NS; n++) Av[n] = -__expf(Arow[n]);
  bool fastA = true;
#pragma unroll
  for (int n = 0; n < NS; n++)
    if (fabsf(Av[n] + (float)(n + 1)) > 1e-4f * (float)(n + 1)) fastA = false;
  const float* Dsel = str ? (rev ? D_vr : D_vf) : (rev ? D_ar : D_af);
  const float Dd = Dsel[d];

  const int tlo = rev ? (LL - CL2 * (chunk + 1)) : (CL2 * chunk);
  unsigned short* uyb = u + (size_t)slab * SZC + ((size_t)b * LL + tlo) * DN + d0;
  const float* dlb = dl + (size_t)slab * SZC + ((size_t)b * LL + tlo) * DN + d0;
  const unsigned short* zb = z_t + (size_t)str * SZC + ((size_t)b * LL + tlo) * DN + d0;
  const float* Bp = Bb + (size_t)slab * NSZC + ((size_t)b * LL + tlo) * NS;
  const float* Cp = Cb + (size_t)slab * NSZC + ((size_t)b * LL + tlo) * NS;
  unsigned short* hendp = hend + (size_t)str * HSZC;
  float* sumdlp = sumdl + (size_t)str * NC2 * G2C;

  // ---- stage the whole chunk tile ----
  {
    const int lane = tid & 63;
    const int w = tid >> 6;
#pragma unroll
    for (int j4 = 0; j4 < 4; j4++) {
      int row = w * 4 + j4;
      ushort4v uu = *(const ushort4v*)(uyb + (size_t)row * DN + lane * 4);
      *(ushort4v*)&us[row][lane * 4] = uu;
      float4 dd4 = *(const float4*)(dlb + (size_t)row * DN + lane * 4);
      *(float4*)&dls[row][lane * 4] = dd4;
      if (PHASE == 3) {
        ushort4v zz = *(const ushort4v*)(zb + (size_t)row * DN + lane * 4);
        *(ushort4v*)&zs[row][lane * 4] = zz;
      }
    }
    Bs[tid >> 4][tid & 15] = Bp[(size_t)(tid >> 4) * NS + (tid & 15)];
    if (PHASE == 3) Cs[tid >> 4][tid & 15] = Cp[(size_t)(tid >> 4) * NS + (tid & 15)];
  }

  float h[NS];
  if (PHASE == 3) {
    const unsigned short* hp = hendp + ((size_t)chunk * G2C + ch) * NS;
#pragma unroll
    for (int n = 0; n < NS; n++) h[n] = bf2f(hp[n]);
  } else {
#pragma unroll
    for (int n = 0; n < NS; n++) h[n] = 0.f;
  }
  __syncthreads();

  float sdl = 0.f;
  if (fastA) {
    // packed state pairs
    f32x2 h2[8];
#pragma unroll
    for (int k = 0; k < 8; k++) h2[k] = (f32x2){h[2 * k], h[2 * k + 1]};
#pragma unroll
    for (int jj = 0; jj < CL2; jj++) {
      const int j = rev ? (CL2 - 1 - jj) : jj;
      const float uc = bf2f(us[j][tid]);
      const float dc = dls[j][tid];
      const f32x2* B2 = (const f32x2*)&Bs[j][0];
      const f32x2* C2 = (const f32x2*)&Cs[j][0];
      const float dlu = dc * uc;
      const f32x2 dlu2 = (f32x2){dlu, dlu};
      // powers of E = exp(-dc): P[k] = {E^(2k+1), E^(2k+2)}
      const float p1 = __expf(-dc);
      const float p2 = p1 * p1;
      const f32x2 p22 = (f32x2){p2, p2};
      f32x2 P[8];
      P[0] = (f32x2){p1, p2};
#pragma unroll
      for (int k = 1; k < 8; k++) P[k] = P[k - 1] * p22;
      f32x2 acc2 = (f32x2){0.f, 0.f};
#pragma unroll
      for (int k = 0; k < 8; k++) {
        f32x2 db = dlu2 * B2[k];
        h2[k] = __builtin_elementwise_fma(P[k], h2[k], db);
        if (PHASE == 3) acc2 = __builtin_elementwise_fma(h2[k], C2[k], acc2);
      }
      if (PHASE == 1) sdl += dc;
      if (PHASE == 3) {
        const float zc = bf2f(zs[j][tid]);
        float y = fmaf(uc, Dd, acc2.x + acc2.y) * zc;
        uyb[(size_t)j * DN + tid] = f2bf(y);
      }
    }
#pragma unroll
    for (int k = 0; k < 8; k++) { h[2 * k] = h2[k].x; h[2 * k + 1] = h2[k].y; }
  } else {
#pragma unroll
    for (int jj = 0; jj < CL2; jj++) {
      const int j = rev ? (CL2 - 1 - jj) : jj;
      const float uc = bf2f(us[j][tid]);
      const float dc = dls[j][tid];
      const float dlu = dc * uc;
      float acc = 0.f;
#pragma unroll
      for (int n = 0; n < NS; n++) {
        h[n] = fmaf(__expf(dc * Av[n]), h[n], dlu * Bs[j][n]);
        if (PHASE == 3) acc = fmaf(h[n], Cs[j][n], acc);
      }
      if (PHASE == 1) sdl += dc;
      if (PHASE == 3) {
        const float zc = bf2f(zs[j][tid]);
        float y = fmaf(uc, Dd, acc) * zc;
        uyb[(size_t)j * DN + tid] = f2bf(y);
      }
    }
  }
  if (PHASE == 1) {
    unsigned short* hp = hendp + ((size_t)chunk * G2C + ch) * NS;
#pragma unroll
    for (int n = 0; n < NS; n++) hp[n] = f2bf(h[n]);
    sumdlp[(size_t)chunk * G2C + ch] = sdl;
  }
}

// ---------------------------------------------------------------------------
// Phase 2 (both streams): grid (G2C/16, 2).
// ---------------------------------------------------------------------------
__global__ __launch_bounds__(256) void scan_combine_kernel(
    const float* __restrict__ A_log, const float* __restrict__ Ab_log,
    unsigned short* __restrict__ hend, const float* __restrict__ sumdl) {
  __shared__ float tile[8][256];
  __shared__ float sd[8][16];
  const int tid = threadIdx.x;
  const int str = blockIdx.y;
  const int ch0 = blockIdx.x * 16;
  const int chl = tid >> 4;
  const int n = tid & 15;
  const int ch = ch0 + chl;
  const bool rev = ch >= BB * DN;
  const int d = ch & (DN - 1);
  const float Av = -__expf((rev ? Ab_log : A_log)[d * NS + n]);
  unsigned short* hendp = hend + (size_t)str * HSZC;
  const float* sumdlp = sumdl + (size_t)str * NC2 * G2C;
  float H = 0.f;
  for (int cb = 0; cb < NC2 / 8; cb++) {
#pragma unroll
    for (int j = 0; j < 8; j++)
      tile[j][tid] = bf2f(hendp[((size_t)(cb * 8 + j) * G2C + ch0) * NS + tid]);
    if (tid < 128) {
      int j = tid >> 4, k = tid & 15;
      sd[j][k] = sumdlp[(size_t)(cb * 8 + j) * G2C + ch0 + k];
    }
    __syncthreads();
#pragma unroll
    for (int j = 0; j < 8; j++) {
      float tmp = tile[j][tid];
      tile[j][tid] = H;
      H = fmaf(__expf(Av * sd[j][chl]), H, tmp);
    }
    __syncthreads();
#pragma unroll
    for (int j = 0; j < 8; j++)
      hendp[((size_t)(cb * 8 + j) * G2C + ch0) * NS + tid] = f2bf(tile[j][tid]);
    __syncthreads();
  }
}

// ---------------------------------------------------------------------------
// out_proj (both streams): grid (32, 4, BB*2).
// ---------------------------------------------------------------------------
__global__ __launch_bounds__(256) void out_proj_mfma(
    const unsigned short* __restrict__ u,
    const float* __restrict__ ow_a, const float* __restrict__ ow_v,
    float* __restrict__ outp) {
  __shared__ unsigned short yt[64][40];
  __shared__ unsigned short wo[64][40];
  const int bz = blockIdx.z;
  const int b = bz & 3;
  const int str = bz >> 2;
  const float* ow = str ? ow_v : ow_a;
  const unsigned short* yf = u + (size_t)(str * 2) * SZC;
  const unsigned short* yr = u + (size_t)(str * 2 + 1) * SZC;
  float* outs = outp + (size_t)str * BB * LL * DM;
  const int m0 = blockIdx.y * 64;
  const int l0 = blockIdx.x * 64;
  const int tid = threadIdx.x;
  const int lane = tid & 63;
  const int wid = tid >> 6;
  const int wm = wid >> 1, wn = wid & 1;
  const int krow = (lane >> 4) * 8;
  const int rlo = lane & 15;

  f32x4 acc[2][2];
#pragma unroll
  for (int i = 0; i < 2; i++)
#pragma unroll
    for (int j = 0; j < 2; j++) acc[i][j] = (f32x4){0.f, 0.f, 0.f, 0.f};

  for (int dk = 0; dk < DN; dk += 32) {
    {
      int row = tid >> 2;
      int seg = (tid & 3) * 8;
      ushort8 a = *(const ushort8*)(yf + ((size_t)b * LL + l0 + row) * DN + dk + seg);
      ushort8 c = *(const ushort8*)(yr + ((size_t)b * LL + l0 + row) * DN + dk + seg);
      ushort8 yv;
#pragma unroll
      for (int k = 0; k < 8; k++) yv[k] = f2bf(0.5f * (bf2f(a[k]) + bf2f(c[k])));
      *(ushort8*)&yt[row][seg] = yv;
      const float* wp = ow + (size_t)(m0 + row) * DN + dk + seg;
      float4 w0 = *(const float4*)wp, w1 = *(const float4*)(wp + 4);
      ushort8 wv;
      wv[0] = f2bf(w0.x); wv[1] = f2bf(w0.y); wv[2] = f2bf(w0.z); wv[3] = f2bf(w0.w);
      wv[4] = f2bf(w1.x); wv[5] = f2bf(w1.y); wv[6] = f2bf(w1.z); wv[7] = f2bf(w1.w);
      *(ushort8*)&wo[row][seg] = wv;
    }
    __syncthreads();
    bf16x8 a0 = *(bf16x8*)&yt[wm * 32 + rlo][krow];
    bf16x8 a1 = *(bf16x8*)&yt[wm * 32 + 16 + rlo][krow];
    bf16x8 b0 = *(bf16x8*)&wo[wn * 32 + rlo][krow];
    bf16x8 b1 = *(bf16x8*)&wo[wn * 32 + 16 + rlo][krow];
    acc[0][0] = __builtin_amdgcn_mfma_f32_16x16x32_bf16(a0, b0, acc[0][0], 0, 0, 0);
    acc[0][1] = __builtin_amdgcn_mfma_f32_16x16x32_bf16(a0, b1, acc[0][1], 0, 0, 0);
    acc[1][0] = __builtin_amdgcn_mfma_f32_16x16x32_bf16(a1, b0, acc[1][0], 0, 0, 0);
    acc[1][1] = __builtin_amdgcn_mfma_f32_16x16x32_bf16(a1, b1, acc[1][1], 0, 0, 0);
    __syncthreads();
  }
#pragma unroll
  for (int mt = 0; mt < 2; mt++)
#pragma unroll
    for (int nt = 0; nt < 2; nt++)
#pragma unroll
      for (int r = 0; r < 4; r++) {
        int l = l0 + wm * 32 + mt * 16 + (lane >> 4) * 4 + r;
        int m = m0 + wn * 32 + nt * 16 + rlo;
        outs[((size_t)b * LL + l) * DM + m] = acc[mt][nt][r];
      }
}

// ---------------------------------------------------------------------------
extern "C" void kernel_launch(void* const* d_in, const int* in_sizes, int n_in,
                              void* d_out, int out_size, void* d_ws, size_t ws_size,
                              hipStream_t stream) {
  (void)in_sizes; (void)n_in; (void)out_size; (void)ws_size;
  const float* A_log = (const float*)d_in[2];
  const float* Ab_log = (const float*)d_in[3];
  const float* h_a = (const float*)d_in[0];
  const float* h_v = (const float*)d_in[1];
#define AP(i) ((const float*)d_in[4 + (i)])
#define VP(i) ((const float*)d_in[18 + (i)])

  float* ws = (float*)d_ws;
  float* dl = ws;                                   // 4*SZC fp32
  float* Bb = dl + 4 * SZC;                         // 4*NSZC
  float* Cb = Bb + 4 * NSZC;                        // 4*NSZC
  float* sumdl = Cb + 4 * NSZC;                     // 2*NC2*G2C
  float* dtv_g = sumdl + (size_t)2 * NC2 * G2C;     // 4*BB*NLT*256 = 524,288
  unsigned short* xwbf = (unsigned short*)(dtv_g + (size_t)4 * BB * NLT * 256);
  unsigned short* z_t = xwbf + 4 * XWSL;            // 2*SZC bf16
  unsigned short* u = z_t + 2 * SZC;                // 4*SZC bf16
  unsigned short* xz = u + 4 * SZC;                 // 2*SZC bf16
  unsigned short* hend = xz + 2 * SZC;              // 2*HSZC bf16

  hipLaunchKernelGGL(in_proj_mfma, dim3(LL / 64, EE / 128, BB * 2), dim3(256), 0,
                     stream, h_a, h_v, AP(0), VP(0), xz, z_t);
  hipLaunchKernelGGL(xw_prep_kernel, dim3(96), dim3(256), 0, stream,
                     AP(3), AP(9), VP(3), VP(9), xwbf);
  hipLaunchKernelGGL(conv_kernel, dim3((LL / 32) * 4, BB, 4), dim3(256), 0, stream,
                     xz, AP(1), AP(2), AP(7), AP(8), VP(1), VP(2), VP(7), VP(8), u);
  hipLaunchKernelGGL(xdbl_kernel, dim3(NLT, BB, 4), dim3(256), 0, stream,
                     u, xwbf, dtv_g, Bb, Cb);
  hipLaunchKernelGGL(delta_kernel, dim3(NLT, BB, 4), dim3(256), 0, stream,
                     dtv_g, AP(4), AP(5), AP(10), AP(11), VP(4), VP(5), VP(10),
                     VP(11), dl);
  hipLaunchKernelGGL(HIP_KERNEL_NAME(scan_kernel<1>), dim3(NC2 * 16, 2), dim3(256),
                     0, stream, u, dl, z_t, Bb, Cb, A_log, Ab_log, AP(6), AP(12),
                     VP(6), VP(12), hend, sumdl);
  hipLaunchKernelGGL(scan_combine_kernel, dim3(G2C / 16, 2), dim3(256), 0, stream,
                     A_log, Ab_log, hend, sumdl);
  hipLaunchKernelGGL(HIP_KERNEL_NAME(scan_kernel<3>), dim3(NC2 * 16, 2), dim3(256),
                     0, stream, u, dl, z_t, Bb, Cb, A_log, Ab_log, AP(6), AP(12),
                     VP(6), VP(12), hend, sumdl);
  hipLaunchKernelGGL(out_proj_mfma, dim3(LL / 64, DM / 64, BB * 2), dim3(256), 0,
                     stream, u, AP(13), VP(13), (float*)d_out);
#undef AP
#undef VP
}

// Round 23
// 220.940 us; speedup vs baseline: 1.6588x; 1.0164x over previous
//
#include <hip/hip_runtime.h>
#include <hip/hip_bf16.h>
#include <cstddef>

#define BB 4
#define LL 2048
#define DM 256
#define DN 512
#define EE 1024
#define NS 16
#define RK 16
#define NC2 128         // scan chunks
#define CL2 (LL / NC2)  // chunk length = 16
#define NLT (LL / 16)   // l-tiles for xdbl/delta = 128
#define G2C (2 * BB * DN)                       // 4096
#define SZC ((size_t)BB * LL * DN)              // 4,194,304
#define NSZC ((size_t)BB * LL * NS)             // 131,072
#define HSZC ((size_t)NC2 * G2C * NS)           // 8,388,608 (bf16 elems)
#define XWSL (48 * 512)                         // 24,576

typedef __attribute__((ext_vector_type(8))) short bf16x8;
typedef __attribute__((ext_vector_type(8))) unsigned short ushort8;
typedef __attribute__((ext_vector_type(4))) unsigned short ushort4v;
typedef __attribute__((ext_vector_type(2))) unsigned short ushort2v;
typedef __attribute__((ext_vector_type(4))) float f32x4;
typedef __attribute__((ext_vector_type(2))) float f32x2;

__device__ __forceinline__ float fsilu(float x) { return x / (1.0f + __expf(-x)); }
__device__ __forceinline__ float fsoftplus_fast(float x) {
  return x > 20.0f ? x : __logf(1.0f + __expf(x));
}
__device__ __forceinline__ unsigned short f2bf(float x) {  // RNE float->bf16
  union { float f; unsigned int u; } v; v.f = x;
  unsigned int r = v.u + 0x7fffu + ((v.u >> 16) & 1u);
  return (unsigned short)(r >> 16);
}
__device__ __forceinline__ float bf2f(unsigned short x) {
  union { unsigned int u; float f; } v; v.u = ((unsigned int)x) << 16;
  return v.f;
}

// ---------------------------------------------------------------------------
// in_proj (both streams). Tile 128e x 64l, grid (32, 8, BB*2).
// ---------------------------------------------------------------------------
__global__ __launch_bounds__(256) void in_proj_mfma(
    const float* __restrict__ h_a, const float* __restrict__ h_v,
    const float* __restrict__ w_a, const float* __restrict__ w_v,
    unsigned short* __restrict__ xz, unsigned short* __restrict__ z_t) {
  __shared__ unsigned short ht[64][40];   // [l][k] bf16
  __shared__ unsigned short wt[128][40];  // [e][k]
  const int bz = blockIdx.z;
  const int b = bz & 3;
  const int str = bz >> 2;
  const float* h = str ? h_v : h_a;
  const float* w = str ? w_v : w_a;
  unsigned short* xzs = xz + (size_t)str * SZC;
  unsigned short* zts = z_t + (size_t)str * SZC;
  const int e0 = blockIdx.y * 128;
  const int l0 = blockIdx.x * 64;
  const int tid = threadIdx.x;
  const int lane = tid & 63;
  const int wv = tid >> 6;
  const bool zblk = (e0 >= DN);
  const int krow = (lane >> 4) * 8;
  const int rlo = lane & 15;
  const int rbase = (lane >> 4) * 4;

  f32x4 acc[8];
#pragma unroll
  for (int i = 0; i < 8; i++) acc[i] = (f32x4){0.f, 0.f, 0.f, 0.f};

  for (int dk = 0; dk < DM; dk += 32) {
    {
      int row = tid >> 2;
      int seg = (tid & 3) * 8;
      const float* hp = h + ((size_t)b * LL + l0 + row) * DM + dk + seg;
      float4 ha = *(const float4*)hp, hb = *(const float4*)(hp + 4);
      ushort8 hv;
      hv[0] = f2bf(ha.x); hv[1] = f2bf(ha.y); hv[2] = f2bf(ha.z); hv[3] = f2bf(ha.w);
      hv[4] = f2bf(hb.x); hv[5] = f2bf(hb.y); hv[6] = f2bf(hb.z); hv[7] = f2bf(hb.w);
      *(ushort8*)&ht[row][seg] = hv;
    }
#pragma unroll
    for (int it = 0; it < 2; it++) {
      int idx = it * 256 + tid;
      int row = idx >> 2;
      int seg = (idx & 3) * 8;
      const float* wp = w + (size_t)(e0 + row) * DM + dk + seg;
      float4 wa = *(const float4*)wp, wb = *(const float4*)(wp + 4);
      ushort8 wv8;
      wv8[0] = f2bf(wa.x); wv8[1] = f2bf(wa.y); wv8[2] = f2bf(wa.z); wv8[3] = f2bf(wa.w);
      wv8[4] = f2bf(wb.x); wv8[5] = f2bf(wb.y); wv8[6] = f2bf(wb.z); wv8[7] = f2bf(wb.w);
      *(ushort8*)&wt[row][seg] = wv8;
    }
    __syncthreads();
    if (!zblk) {
      bf16x8 af0 = *(bf16x8*)&wt[wv * 32 + 0 * 16 + rlo][krow];
      bf16x8 af1 = *(bf16x8*)&wt[wv * 32 + 1 * 16 + rlo][krow];
      bf16x8 bf0 = *(bf16x8*)&ht[0 * 16 + rlo][krow];
      bf16x8 bf1 = *(bf16x8*)&ht[1 * 16 + rlo][krow];
      bf16x8 bf2 = *(bf16x8*)&ht[2 * 16 + rlo][krow];
      bf16x8 bf3 = *(bf16x8*)&ht[3 * 16 + rlo][krow];
      acc[0] = __builtin_amdgcn_mfma_f32_16x16x32_bf16(af0, bf0, acc[0], 0, 0, 0);
      acc[1] = __builtin_amdgcn_mfma_f32_16x16x32_bf16(af0, bf1, acc[1], 0, 0, 0);
      acc[2] = __builtin_amdgcn_mfma_f32_16x16x32_bf16(af0, bf2, acc[2], 0, 0, 0);
      acc[3] = __builtin_amdgcn_mfma_f32_16x16x32_bf16(af0, bf3, acc[3], 0, 0, 0);
      acc[4] = __builtin_amdgcn_mfma_f32_16x16x32_bf16(af1, bf0, acc[4], 0, 0, 0);
      acc[5] = __builtin_amdgcn_mfma_f32_16x16x32_bf16(af1, bf1, acc[5], 0, 0, 0);
      acc[6] = __builtin_amdgcn_mfma_f32_16x16x32_bf16(af1, bf2, acc[6], 0, 0, 0);
      acc[7] = __builtin_amdgcn_mfma_f32_16x16x32_bf16(af1, bf3, acc[7], 0, 0, 0);
    } else {
      bf16x8 af0 = *(bf16x8*)&ht[0 * 16 + rlo][krow];
      bf16x8 af1 = *(bf16x8*)&ht[1 * 16 + rlo][krow];
      bf16x8 af2 = *(bf16x8*)&ht[2 * 16 + rlo][krow];
      bf16x8 af3 = *(bf16x8*)&ht[3 * 16 + rlo][krow];
      bf16x8 bf0 = *(bf16x8*)&wt[wv * 32 + 0 * 16 + rlo][krow];
      bf16x8 bf1 = *(bf16x8*)&wt[wv * 32 + 1 * 16 + rlo][krow];
      acc[0] = __builtin_amdgcn_mfma_f32_16x16x32_bf16(af0, bf0, acc[0], 0, 0, 0);
      acc[1] = __builtin_amdgcn_mfma_f32_16x16x32_bf16(af0, bf1, acc[1], 0, 0, 0);
      acc[2] = __builtin_amdgcn_mfma_f32_16x16x32_bf16(af1, bf0, acc[2], 0, 0, 0);
      acc[3] = __builtin_amdgcn_mfma_f32_16x16x32_bf16(af1, bf1, acc[3], 0, 0, 0);
      acc[4] = __builtin_amdgcn_mfma_f32_16x16x32_bf16(af2, bf0, acc[4], 0, 0, 0);
      acc[5] = __builtin_amdgcn_mfma_f32_16x16x32_bf16(af2, bf1, acc[5], 0, 0, 0);
      acc[6] = __builtin_amdgcn_mfma_f32_16x16x32_bf16(af3, bf0, acc[6], 0, 0, 0);
      acc[7] = __builtin_amdgcn_mfma_f32_16x16x32_bf16(af3, bf1, acc[7], 0, 0, 0);
    }
    __syncthreads();
  }
  if (!zblk) {
#pragma unroll
    for (int m = 0; m < 2; m++)
#pragma unroll
      for (int n = 0; n < 4; n++)
#pragma unroll
        for (int r = 0; r < 4; r++) {
          int e = e0 + wv * 32 + m * 16 + rbase + r;
          int l = l0 + n * 16 + rlo;
          xzs[((size_t)b * DN + e) * LL + l] = f2bf(acc[m * 4 + n][r]);
        }
  } else {
#pragma unroll
    for (int m = 0; m < 4; m++)
#pragma unroll
      for (int n = 0; n < 2; n++)
#pragma unroll
        for (int r = 0; r < 4; r++) {
          int l = l0 + m * 16 + rbase + r;
          int d = (e0 - DN) + wv * 32 + n * 16 + rlo;
          zts[((size_t)b * LL + l) * DN + d] = f2bf(fsilu(acc[m * 2 + n][r]));
        }
  }
}

// ---------------------------------------------------------------------------
// conv (both streams): grid ((LL/32)*4, BB, 4): z = str*2 + rev.
// ---------------------------------------------------------------------------
__global__ __launch_bounds__(256) void conv_kernel(
    const unsigned short* __restrict__ xz,
    const float* __restrict__ cw_af, const float* __restrict__ cb_af,
    const float* __restrict__ cw_ar, const float* __restrict__ cb_ar,
    const float* __restrict__ cw_vf, const float* __restrict__ cb_vf,
    const float* __restrict__ cw_vr, const float* __restrict__ cb_vr,
    unsigned short* __restrict__ u) {
  __shared__ float xt[128][33];
  const int slab = blockIdx.z;      // str*2 + rev
  const int rev = slab & 1;
  const int str = slab >> 1;
  const int b = blockIdx.y;
  const int dc0 = (blockIdx.x & 3) * 128;
  const int l0 = (blockIdx.x >> 2) * 32;
  const int tid = threadIdx.x;
  const int lc = tid & 31;
  const int dg = tid >> 5;
  const int l = l0 + lc;
  const float* conv_w = str ? (rev ? cw_vr : cw_vf) : (rev ? cw_ar : cw_af);
  const float* conv_b = str ? (rev ? cb_vr : cb_vf) : (rev ? cb_ar : cb_af);
  const unsigned short* xzs = xz + (size_t)str * SZC;
  unsigned short* u_out = u + (size_t)slab * SZC;

#pragma unroll
  for (int i = 0; i < 16; i++) {
    int dloc = dg * 16 + i;
    int dd = dc0 + dloc;
    const unsigned short* base = xzs + ((size_t)b * DN + dd) * LL;
    float4 cw4 = *(const float4*)(conv_w + dd * 4);
    float a0 = conv_b[dd];
    if (rev) {
      a0 = fmaf(cw4.w, bf2f(base[l]), a0);
      if (l + 1 < LL) a0 = fmaf(cw4.z, bf2f(base[l + 1]), a0);
      if (l + 2 < LL) a0 = fmaf(cw4.y, bf2f(base[l + 2]), a0);
      if (l + 3 < LL) a0 = fmaf(cw4.x, bf2f(base[l + 3]), a0);
    } else {
      a0 = fmaf(cw4.w, bf2f(base[l]), a0);
      if (l - 1 >= 0) a0 = fmaf(cw4.z, bf2f(base[l - 1]), a0);
      if (l - 2 >= 0) a0 = fmaf(cw4.y, bf2f(base[l - 2]), a0);
      if (l - 3 >= 0) a0 = fmaf(cw4.x, bf2f(base[l - 3]), a0);
    }
    xt[dloc][lc] = fsilu(a0);
  }
  __syncthreads();
#pragma unroll
  for (int j = 0; j < 8; j++) {
    int idx = j * 256 + tid;
    int d2 = idx & 63;
    int l2 = idx >> 6;
    ushort2v v;
    v[0] = f2bf(xt[2 * d2][l2]);
    v[1] = f2bf(xt[2 * d2 + 1][l2]);
    *(ushort2v*)&u_out[((size_t)b * LL + l0 + l2) * DN + dc0 + 2 * d2] = v;
  }
}

// ---------------------------------------------------------------------------
// prep: convert all 4 x_w matrices to bf16 slabs.
// ---------------------------------------------------------------------------
__global__ __launch_bounds__(256) void xw_prep_kernel(
    const float* __restrict__ a_f, const float* __restrict__ a_r,
    const float* __restrict__ v_f, const float* __restrict__ v_r,
    unsigned short* __restrict__ o) {
  int i = blockIdx.x * 256 + threadIdx.x;
  if (i < XWSL) {
    o[i] = f2bf(a_f[i]);
    o[i + XWSL] = f2bf(a_r[i]);
    o[i + 2 * XWSL] = f2bf(v_f[i]);
    o[i + 3 * XWSL] = f2bf(v_r[i]);
  }
}

// ---------------------------------------------------------------------------
// xdbl (both streams): grid (NLT, BB, 4): z = str*2 + rev.
// ---------------------------------------------------------------------------
__global__ __launch_bounds__(256) void xdbl_kernel(
    const unsigned short* __restrict__ u, const unsigned short* __restrict__ xwbf,
    float* __restrict__ dtv_g, float* __restrict__ Bb, float* __restrict__ Cb) {
  __shared__ __align__(16) unsigned short ub[4][16][136];
  __shared__ float red[4][48][17];
  const int slab = blockIdx.z;
  const int b = blockIdx.y;
  const int lt = blockIdx.x;
  const int l0 = lt * 16;
  const int tid = threadIdx.x;
  const int lane = tid & 63;
  const int w = tid >> 6;
  const int rlo = lane & 15;
  const int hi4 = lane >> 4;
  const int kseg = hi4 * 8;

  const unsigned short* up = u + (size_t)slab * SZC + ((size_t)b * LL + l0) * DN;
  const unsigned short* xwb = xwbf + (size_t)slab * XWSL;
  float* B_out = Bb + (size_t)slab * NSZC;
  float* C_out = Cb + (size_t)slab * NSZC;

#pragma unroll
  for (int j = 0; j < 4; j++) {
    int idx = j * 256 + tid;
    int l2 = idx >> 6;
    int c8 = idx & 63;
    ushort8 v = *(const ushort8*)(up + (size_t)l2 * DN + c8 * 8);
    *(ushort8*)&ub[c8 >> 4][l2][(c8 & 15) * 8] = v;
  }
  __syncthreads();

  f32x4 am0 = (f32x4){0.f, 0.f, 0.f, 0.f};
  f32x4 am1 = (f32x4){0.f, 0.f, 0.f, 0.f};
  f32x4 am2 = (f32x4){0.f, 0.f, 0.f, 0.f};
#pragma unroll
  for (int ks = 0; ks < 4; ks++) {
    bf16x8 bfrag = *(bf16x8*)&ub[w][rlo][ks * 32 + kseg];
    const unsigned short* xp = xwb + (size_t)(w * 128 + ks * 32 + kseg);
    bf16x8 a0 = *(const bf16x8*)(xp + (size_t)(0 + rlo) * 512);
    bf16x8 a1 = *(const bf16x8*)(xp + (size_t)(16 + rlo) * 512);
    bf16x8 a2 = *(const bf16x8*)(xp + (size_t)(32 + rlo) * 512);
    am0 = __builtin_amdgcn_mfma_f32_16x16x32_bf16(a0, bfrag, am0, 0, 0, 0);
    am1 = __builtin_amdgcn_mfma_f32_16x16x32_bf16(a1, bfrag, am1, 0, 0, 0);
    am2 = __builtin_amdgcn_mfma_f32_16x16x32_bf16(a2, bfrag, am2, 0, 0, 0);
  }
  {
    const int rbase = hi4 * 4;
#pragma unroll
    for (int r = 0; r < 4; r++) red[w][0 + rbase + r][rlo] = am0[r];
#pragma unroll
    for (int r = 0; r < 4; r++) red[w][16 + rbase + r][rlo] = am1[r];
#pragma unroll
    for (int r = 0; r < 4; r++) red[w][32 + rbase + r][rlo] = am2[r];
  }
  __syncthreads();
  float* dtvp = dtv_g + (((size_t)slab * BB + b) * NLT + lt) * 256;
#pragma unroll
  for (int i = 0; i < 3; i++) {
    int o = i * 256 + tid;
    int row = o >> 4, col = o & 15;
    float s = (red[0][row][col] + red[1][row][col]) +
              (red[2][row][col] + red[3][row][col]);
    if (row < 16)
      dtvp[(size_t)row * 16 + col] = s;
    else if (row < 32)
      B_out[((size_t)b * LL + l0 + col) * NS + (row - 16)] = s;
    else
      C_out[((size_t)b * LL + l0 + col) * NS + (row - 32)] = s;
  }
}

// ---------------------------------------------------------------------------
// delta (both streams): dtv transposed in LDS; dl output now BF16.
// ---------------------------------------------------------------------------
__global__ __launch_bounds__(256) void delta_kernel(
    const float* __restrict__ dtv_g,
    const float* __restrict__ dtw_af, const float* __restrict__ dtb_af,
    const float* __restrict__ dtw_ar, const float* __restrict__ dtb_ar,
    const float* __restrict__ dtw_vf, const float* __restrict__ dtb_vf,
    const float* __restrict__ dtw_vr, const float* __restrict__ dtb_vr,
    unsigned short* __restrict__ dl) {
  __shared__ __align__(16) float dtvT[16][20];
  const int slab = blockIdx.z;
  const int rev = slab & 1;
  const int str = slab >> 1;
  const int b = blockIdx.y;
  const int lt = blockIdx.x;
  const int l0 = lt * 16;
  const int tid = threadIdx.x;
  const float* dt_w = str ? (rev ? dtw_vr : dtw_vf) : (rev ? dtw_ar : dtw_af);
  const float* dt_b = str ? (rev ? dtb_vr : dtb_vf) : (rev ? dtb_ar : dtb_af);
  unsigned short* dl_out = dl + (size_t)slab * SZC;

  {
    const float* dtvp = dtv_g + (((size_t)slab * BB + b) * NLT + lt) * 256;
    float v = dtvp[tid];  // tid = k*16 + l
    dtvT[tid & 15][tid >> 4] = v;
  }
  __syncthreads();

  const int dd0 = tid, dd1 = tid + 256;
  const float4* wr0 = (const float4*)(dt_w + (size_t)dd0 * RK);
  const float4* wr1 = (const float4*)(dt_w + (size_t)dd1 * RK);
  float4 a_0 = wr0[0], a_1 = wr0[1], a_2 = wr0[2], a_3 = wr0[3];
  float4 b_0 = wr1[0], b_1 = wr1[1], b_2 = wr1[2], b_3 = wr1[3];
  float bias0 = dt_b[dd0], bias1 = dt_b[dd1];

#pragma unroll
  for (int l2 = 0; l2 < 16; l2++) {
    float4 q0 = *(const float4*)&dtvT[l2][0];
    float4 q1 = *(const float4*)&dtvT[l2][4];
    float4 q2 = *(const float4*)&dtvT[l2][8];
    float4 q3 = *(const float4*)&dtvT[l2][12];
    float s0 = bias0, s1 = bias1;
    s0 = fmaf(a_0.x, q0.x, s0); s1 = fmaf(b_0.x, q0.x, s1);
    s0 = fmaf(a_0.y, q0.y, s0); s1 = fmaf(b_0.y, q0.y, s1);
    s0 = fmaf(a_0.z, q0.z, s0); s1 = fmaf(b_0.z, q0.z, s1);
    s0 = fmaf(a_0.w, q0.w, s0); s1 = fmaf(b_0.w, q0.w, s1);
    s0 = fmaf(a_1.x, q1.x, s0); s1 = fmaf(b_1.x, q1.x, s1);
    s0 = fmaf(a_1.y, q1.y, s0); s1 = fmaf(b_1.y, q1.y, s1);
    s0 = fmaf(a_1.z, q1.z, s0); s1 = fmaf(b_1.z, q1.z, s1);
    s0 = fmaf(a_1.w, q1.w, s0); s1 = fmaf(b_1.w, q1.w, s1);
    s0 = fmaf(a_2.x, q2.x, s0); s1 = fmaf(b_2.x, q2.x, s1);
    s0 = fmaf(a_2.y, q2.y, s0); s1 = fmaf(b_2.y, q2.y, s1);
    s0 = fmaf(a_2.z, q2.z, s0); s1 = fmaf(b_2.z, q2.z, s1);
    s0 = fmaf(a_2.w, q2.w, s0); s1 = fmaf(b_2.w, q2.w, s1);
    s0 = fmaf(a_3.x, q3.x, s0); s1 = fmaf(b_3.x, q3.x, s1);
    s0 = fmaf(a_3.y, q3.y, s0); s1 = fmaf(b_3.y, q3.y, s1);
    s0 = fmaf(a_3.z, q3.z, s0); s1 = fmaf(b_3.z, q3.z, s1);
    s0 = fmaf(a_3.w, q3.w, s0); s1 = fmaf(b_3.w, q3.w, s1);
    unsigned short* rowp = dl_out + ((size_t)b * LL + l0 + l2) * DN;
    rowp[dd0] = f2bf(fsoftplus_fast(s0));
    rowp[dd1] = f2bf(fsoftplus_fast(s1));
  }
}

// ---------------------------------------------------------------------------
// Scan (both streams, LDS-staged). dl now BF16 (halves the dominant read
// stream + LDS staging 16->8 KB -> 5 blocks/CU). Packed fast-A path kept.
// ---------------------------------------------------------------------------
template <int PHASE>
__global__ __launch_bounds__(256) void scan_kernel(
    unsigned short* __restrict__ u, const unsigned short* __restrict__ dl,
    const unsigned short* __restrict__ z_t, const float* __restrict__ Bb,
    const float* __restrict__ Cb, const float* __restrict__ A_log,
    const float* __restrict__ Ab_log,
    const float* __restrict__ D_af, const float* __restrict__ D_ar,
    const float* __restrict__ D_vf, const float* __restrict__ D_vr,
    unsigned short* __restrict__ hend, float* __restrict__ sumdl) {
  __shared__ unsigned short us[CL2][256];   // 8 KB
  __shared__ unsigned short zs[CL2][256];   // 8 KB
  __shared__ unsigned short dls[CL2][256];  // 8 KB (bf16 now)
  __shared__ __align__(16) float Bs[CL2][16];
  __shared__ __align__(16) float Cs[CL2][16];
  const int tid = threadIdx.x;
  const int str = blockIdx.y;
  const int ch0 = (blockIdx.x & 15) * 256;
  const int chunk = blockIdx.x >> 4;
  const int ch = ch0 + tid;
  const bool rev = ch0 >= BB * DN;
  const int slab = str * 2 + (rev ? 1 : 0);
  const int cid0 = rev ? ch0 - BB * DN : ch0;
  const int b = cid0 >> 9;
  const int d0 = cid0 & (DN - 1);
  const int d = d0 + tid;

  const float* Arow = (rev ? Ab_log : A_log) + d * NS;
  float Av[NS];
#pragma unroll
  for (int n = 0; n < NS; n++) Av[n] = -__expf(Arow[n]);
  bool fastA = true;
#pragma unroll
  for (int n = 0; n < NS; n++)
    if (fabsf(Av[n] + (float)(n + 1)) > 1e-4f * (float)(n + 1)) fastA = false;
  const float* Dsel = str ? (rev ? D_vr : D_vf) : (rev ? D_ar : D_af);
  const float Dd = Dsel[d];

  const int tlo = rev ? (LL - CL2 * (chunk + 1)) : (CL2 * chunk);
  unsigned short* uyb = u + (size_t)slab * SZC + ((size_t)b * LL + tlo) * DN + d0;
  const unsigned short* dlb = dl + (size_t)slab * SZC + ((size_t)b * LL + tlo) * DN + d0;
  const unsigned short* zb = z_t + (size_t)str * SZC + ((size_t)b * LL + tlo) * DN + d0;
  const float* Bp = Bb + (size_t)slab * NSZC + ((size_t)b * LL + tlo) * NS;
  const float* Cp = Cb + (size_t)slab * NSZC + ((size_t)b * LL + tlo) * NS;
  unsigned short* hendp = hend + (size_t)str * HSZC;
  float* sumdlp = sumdl + (size_t)str * NC2 * G2C;

  // ---- stage the whole chunk tile ----
  {
    const int lane = tid & 63;
    const int w = tid >> 6;
#pragma unroll
    for (int j4 = 0; j4 < 4; j4++) {
      int row = w * 4 + j4;
      ushort4v uu = *(const ushort4v*)(uyb + (size_t)row * DN + lane * 4);
      *(ushort4v*)&us[row][lane * 4] = uu;
      ushort4v dd4 = *(const ushort4v*)(dlb + (size_t)row * DN + lane * 4);
      *(ushort4v*)&dls[row][lane * 4] = dd4;
      if (PHASE == 3) {
        ushort4v zz = *(const ushort4v*)(zb + (size_t)row * DN + lane * 4);
        *(ushort4v*)&zs[row][lane * 4] = zz;
      }
    }
    Bs[tid >> 4][tid & 15] = Bp[(size_t)(tid >> 4) * NS + (tid & 15)];
    if (PHASE == 3) Cs[tid >> 4][tid & 15] = Cp[(size_t)(tid >> 4) * NS + (tid & 15)];
  }

  float h[NS];
  if (PHASE == 3) {
    const unsigned short* hp = hendp + ((size_t)chunk * G2C + ch) * NS;
#pragma unroll
    for (int n = 0; n < NS; n++) h[n] = bf2f(hp[n]);
  } else {
#pragma unroll
    for (int n = 0; n < NS; n++) h[n] = 0.f;
  }
  __syncthreads();

  float sdl = 0.f;
  if (fastA) {
    f32x2 h2[8];
#pragma unroll
    for (int k = 0; k < 8; k++) h2[k] = (f32x2){h[2 * k], h[2 * k + 1]};
#pragma unroll
    for (int jj = 0; jj < CL2; jj++) {
      const int j = rev ? (CL2 - 1 - jj) : jj;
      const float uc = bf2f(us[j][tid]);
      const float dc = bf2f(dls[j][tid]);
      const f32x2* B2 = (const f32x2*)&Bs[j][0];
      const f32x2* C2 = (const f32x2*)&Cs[j][0];
      const float dlu = dc * uc;
      const f32x2 dlu2 = (f32x2){dlu, dlu};
      const float p1 = __expf(-dc);
      const float p2 = p1 * p1;
      const f32x2 p22 = (f32x2){p2, p2};
      f32x2 P[8];
      P[0] = (f32x2){p1, p2};
#pragma unroll
      for (int k = 1; k < 8; k++) P[k] = P[k - 1] * p22;
      f32x2 acc2 = (f32x2){0.f, 0.f};
#pragma unroll
      for (int k = 0; k < 8; k++) {
        f32x2 db = dlu2 * B2[k];
        h2[k] = __builtin_elementwise_fma(P[k], h2[k], db);
        if (PHASE == 3) acc2 = __builtin_elementwise_fma(h2[k], C2[k], acc2);
      }
      if (PHASE == 1) sdl += dc;
      if (PHASE == 3) {
        const float zc = bf2f(zs[j][tid]);
        float y = fmaf(uc, Dd, acc2.x + acc2.y) * zc;
        uyb[(size_t)j * DN + tid] = f2bf(y);
      }
    }
#pragma unroll
    for (int k = 0; k < 8; k++) { h[2 * k] = h2[k].x; h[2 * k + 1] = h2[k].y; }
  } else {
#pragma unroll
    for (int jj = 0; jj < CL2; jj++) {
      const int j = rev ? (CL2 - 1 - jj) : jj;
      const float uc = bf2f(us[j][tid]);
      const float dc = bf2f(dls[j][tid]);
      const float dlu = dc * uc;
      float acc = 0.f;
#pragma unroll
      for (int n = 0; n < NS; n++) {
        h[n] = fmaf(__expf(dc * Av[n]), h[n], dlu * Bs[j][n]);
        if (PHASE == 3) acc = fmaf(h[n], Cs[j][n], acc);
      }
      if (PHASE == 1) sdl += dc;
      if (PHASE == 3) {
        const float zc = bf2f(zs[j][tid]);
        float y = fmaf(uc, Dd, acc) * zc;
        uyb[(size_t)j * DN + tid] = f2bf(y);
      }
    }
  }
  if (PHASE == 1) {
    unsigned short* hp = hendp + ((size_t)chunk * G2C + ch) * NS;
#pragma unroll
    for (int n = 0; n < NS; n++) hp[n] = f2bf(h[n]);
    sumdlp[(size_t)chunk * G2C + ch] = sdl;
  }
}

// ---------------------------------------------------------------------------
// Phase 2 (both streams): grid (G2C/16, 2).
// ---------------------------------------------------------------------------
__global__ __launch_bounds__(256) void scan_combine_kernel(
    const float* __restrict__ A_log, const float* __restrict__ Ab_log,
    unsigned short* __restrict__ hend, const float* __restrict__ sumdl) {
  __shared__ float tile[8][256];
  __shared__ float sd[8][16];
  const int tid = threadIdx.x;
  const int str = blockIdx.y;
  const int ch0 = blockIdx.x * 16;
  const int chl = tid >> 4;
  const int n = tid & 15;
  const int ch = ch0 + chl;
  const bool rev = ch >= BB * DN;
  const int d = ch & (DN - 1);
  const float Av = -__expf((rev ? Ab_log : A_log)[d * NS + n]);
  unsigned short* hendp = hend + (size_t)str * HSZC;
  const float* sumdlp = sumdl + (size_t)str * NC2 * G2C;
  float H = 0.f;
  for (int cb = 0; cb < NC2 / 8; cb++) {
#pragma unroll
    for (int j = 0; j < 8; j++)
      tile[j][tid] = bf2f(hendp[((size_t)(cb * 8 + j) * G2C + ch0) * NS + tid]);
    if (tid < 128) {
      int j = tid >> 4, k = tid & 15;
      sd[j][k] = sumdlp[(size_t)(cb * 8 + j) * G2C + ch0 + k];
    }
    __syncthreads();
#pragma unroll
    for (int j = 0; j < 8; j++) {
      float tmp = tile[j][tid];
      tile[j][tid] = H;
      H = fmaf(__expf(Av * sd[j][chl]), H, tmp);
    }
    __syncthreads();
#pragma unroll
    for (int j = 0; j < 8; j++)
      hendp[((size_t)(cb * 8 + j) * G2C + ch0) * NS + tid] = f2bf(tile[j][tid]);
    __syncthreads();
  }
}

// ---------------------------------------------------------------------------
// out_proj (both streams): grid (32, 4, BB*2).
// ---------------------------------------------------------------------------
__global__ __launch_bounds__(256) void out_proj_mfma(
    const unsigned short* __restrict__ u,
    const float* __restrict__ ow_a, const float* __restrict__ ow_v,
    float* __restrict__ outp) {
  __shared__ unsigned short yt[64][40];
  __shared__ unsigned short wo[64][40];
  const int bz = blockIdx.z;
  const int b = bz & 3;
  const int str = bz >> 2;
  const float* ow = str ? ow_v : ow_a;
  const unsigned short* yf = u + (size_t)(str * 2) * SZC;
  const unsigned short* yr = u + (size_t)(str * 2 + 1) * SZC;
  float* outs = outp + (size_t)str * BB * LL * DM;
  const int m0 = blockIdx.y * 64;
  const int l0 = blockIdx.x * 64;
  const int tid = threadIdx.x;
  const int lane = tid & 63;
  const int wid = tid >> 6;
  const int wm = wid >> 1, wn = wid & 1;
  const int krow = (lane >> 4) * 8;
  const int rlo = lane & 15;

  f32x4 acc[2][2];
#pragma unroll
  for (int i = 0; i < 2; i++)
#pragma unroll
    for (int j = 0; j < 2; j++) acc[i][j] = (f32x4){0.f, 0.f, 0.f, 0.f};

  for (int dk = 0; dk < DN; dk += 32) {
    {
      int row = tid >> 2;
      int seg = (tid & 3) * 8;
      ushort8 a = *(const ushort8*)(yf + ((size_t)b * LL + l0 + row) * DN + dk + seg);
      ushort8 c = *(const ushort8*)(yr + ((size_t)b * LL + l0 + row) * DN + dk + seg);
      ushort8 yv;
#pragma unroll
      for (int k = 0; k < 8; k++) yv[k] = f2bf(0.5f * (bf2f(a[k]) + bf2f(c[k])));
      *(ushort8*)&yt[row][seg] = yv;
      const float* wp = ow + (size_t)(m0 + row) * DN + dk + seg;
      float4 w0 = *(const float4*)wp, w1 = *(const float4*)(wp + 4);
      ushort8 wv;
      wv[0] = f2bf(w0.x); wv[1] = f2bf(w0.y); wv[2] = f2bf(w0.z); wv[3] = f2bf(w0.w);
      wv[4] = f2bf(w1.x); wv[5] = f2bf(w1.y); wv[6] = f2bf(w1.z); wv[7] = f2bf(w1.w);
      *(ushort8*)&wo[row][seg] = wv;
    }
    __syncthreads();
    bf16x8 a0 = *(bf16x8*)&yt[wm * 32 + rlo][krow];
    bf16x8 a1 = *(bf16x8*)&yt[wm * 32 + 16 + rlo][krow];
    bf16x8 b0 = *(bf16x8*)&wo[wn * 32 + rlo][krow];
    bf16x8 b1 = *(bf16x8*)&wo[wn * 32 + 16 + rlo][krow];
    acc[0][0] = __builtin_amdgcn_mfma_f32_16x16x32_bf16(a0, b0, acc[0][0], 0, 0, 0);
    acc[0][1] = __builtin_amdgcn_mfma_f32_16x16x32_bf16(a0, b1, acc[0][1], 0, 0, 0);
    acc[1][0] = __builtin_amdgcn_mfma_f32_16x16x32_bf16(a1, b0, acc[1][0], 0, 0, 0);
    acc[1][1] = __builtin_amdgcn_mfma_f32_16x16x32_bf16(a1, b1, acc[1][1], 0, 0, 0);
    __syncthreads();
  }
#pragma unroll
  for (int mt = 0; mt < 2; mt++)
#pragma unroll
    for (int nt = 0; nt < 2; nt++)
#pragma unroll
      for (int r = 0; r < 4; r++) {
        int l = l0 + wm * 32 + mt * 16 + (lane >> 4) * 4 + r;
        int m = m0 + wn * 32 + nt * 16 + rlo;
        outs[((size_t)b * LL + l) * DM + m] = acc[mt][nt][r];
      }
}

// ---------------------------------------------------------------------------
extern "C" void kernel_launch(void* const* d_in, const int* in_sizes, int n_in,
                              void* d_out, int out_size, void* d_ws, size_t ws_size,
                              hipStream_t stream) {
  (void)in_sizes; (void)n_in; (void)out_size; (void)ws_size;
  const float* A_log = (const float*)d_in[2];
  const float* Ab_log = (const float*)d_in[3];
  const float* h_a = (const float*)d_in[0];
  const float* h_v = (const float*)d_in[1];
#define AP(i) ((const float*)d_in[4 + (i)])
#define VP(i) ((const float*)d_in[18 + (i)])

  float* ws = (float*)d_ws;
  float* Bb = ws;                                   // 4*NSZC fp32
  float* Cb = Bb + 4 * NSZC;                        // 4*NSZC
  float* sumdl = Cb + 4 * NSZC;                     // 2*NC2*G2C
  float* dtv_g = sumdl + (size_t)2 * NC2 * G2C;     // 4*BB*NLT*256
  unsigned short* xwbf = (unsigned short*)(dtv_g + (size_t)4 * BB * NLT * 256);
  unsigned short* z_t = xwbf + 4 * XWSL;            // 2*SZC bf16
  unsigned short* u = z_t + 2 * SZC;                // 4*SZC bf16
  unsigned short* xz = u + 4 * SZC;                 // 2*SZC bf16
  unsigned short* hend = xz + 2 * SZC;              // 2*HSZC bf16
  unsigned short* dl = hend + 2 * HSZC;             // 4*SZC bf16

  hipLaunchKernelGGL(in_proj_mfma, dim3(LL / 64, EE / 128, BB * 2), dim3(256), 0,
                     stream, h_a, h_v, AP(0), VP(0), xz, z_t);
  hipLaunchKernelGGL(xw_prep_kernel, dim3(96), dim3(256), 0, stream,
                     AP(3), AP(9), VP(3), VP(9), xwbf);
  hipLaunchKernelGGL(conv_kernel, dim3((LL / 32) * 4, BB, 4), dim3(256), 0, stream,
                     xz, AP(1), AP(2), AP(7), AP(8), VP(1), VP(2), VP(7), VP(8), u);
  hipLaunchKernelGGL(xdbl_kernel, dim3(NLT, BB, 4), dim3(256), 0, stream,
                     u, xwbf, dtv_g, Bb, Cb);
  hipLaunchKernelGGL(delta_kernel, dim3(NLT, BB, 4), dim3(256), 0, stream,
                     dtv_g, AP(4), AP(5), AP(10), AP(11), VP(4), VP(5), VP(10),
                     VP(11), dl);
  hipLaunchKernelGGL(HIP_KERNEL_NAME(scan_kernel<1>), dim3(NC2 * 16, 2), dim3(256),
                     0, stream, u, dl, z_t, Bb, Cb, A_log, Ab_log, AP(6), AP(12),
                     VP(6), VP(12), hend, sumdl);
  hipLaunchKernelGGL(scan_combine_kernel, dim3(G2C / 16, 2), dim3(256), 0, stream,
                     A_log, Ab_log, hend, sumdl);
  hipLaunchKernelGGL(HIP_KERNEL_NAME(scan_kernel<3>), dim3(NC2 * 16, 2), dim3(256),
                     0, stream, u, dl, z_t, Bb, Cb, A_log, Ab_log, AP(6), AP(12),
                     VP(6), VP(12), hend, sumdl);
  hipLaunchKernelGGL(out_proj_mfma, dim3(LL / 64, DM / 64, BB * 2), dim3(256), 0,
                     stream, u, AP(13), VP(13), (float*)d_out);
#undef AP
#undef VP
}